// Round 7
// baseline (908.793 us; speedup 1.0000x reference)
//
#include <hip/hip_runtime.h>

typedef _Float16 f16;
typedef _Float16 f16x4 __attribute__((ext_vector_type(4)));
typedef _Float16 f16x8 __attribute__((ext_vector_type(8)));
typedef float    f32x4 __attribute__((ext_vector_type(4)));

#define MFMA16(a,b,c) __builtin_amdgcn_mfma_f32_16x16x32_f16((a),(b),(c),0,0,0)

static __device__ __forceinline__ float sigm(float x){ return 1.0f/(1.0f + __expf(-x)); }

// ---------------- workspace layout (bytes) ----------------
static constexpr size_t OFF_WSE_P  = 0;                                  // 4 MB
static constexpr size_t OFF_WSD_P  = OFF_WSE_P  + (size_t)8192*256*2;    // 4 MB
static constexpr size_t OFF_WIHE_P = OFF_WSD_P  + (size_t)8192*256*2;    // 512 KB
static constexpr size_t OFF_WIHD_P = OFF_WIHE_P + (size_t)256*1024*2;
static constexpr size_t OFF_WHHE_P = OFF_WIHD_P + (size_t)256*1024*2;
static constexpr size_t OFF_WHHD_P = OFF_WHHE_P + (size_t)256*1024*2;
static constexpr size_t OFF_W3E    = OFF_WHHD_P + (size_t)256*1024*2;
static constexpr size_t OFF_W3D    = OFF_W3E   + (size_t)3*1024*4;
static constexpr size_t OFF_W2WO   = OFF_W3D   + (size_t)3*1024*4;
static constexpr size_t OFF_BIASE  = OFF_W2WO  + (size_t)256*3*4;
static constexpr size_t OFF_BIASD  = OFF_BIASE + (size_t)1024*4;
static constexpr size_t OFF_B2WO   = OFF_BIASD + (size_t)1024*4;
static constexpr size_t OFF_PREGE  = OFF_B2WO  + 256;                    // 10.5 MB
static constexpr size_t OFF_PREGD  = OFF_PREGE + (size_t)5120*1024*2;    // 52.4 MB
static constexpr size_t OFF_END    = OFF_PREGD + (size_t)25600*1024*2;

// ================= prep: pack weights (blocks 0-2559) + small folds (2560-2569)
// pack layout [kfg][ctg][lane][8]; element (k,n): k = kfg*32+(l>>4)*8+i, n = ctg*16+(l&15)
__global__ __launch_bounds__(256) void k_prep(
    const float* __restrict__ Wse, const float* __restrict__ Wsd,
    const float* __restrict__ Wih_e, const float* __restrict__ Wih_d,
    const float* __restrict__ Whh_e, const float* __restrict__ Whh_d,
    f16* pWse, f16* pWsd, f16* pWih_e, f16* pWih_d, f16* pWhh_e, f16* pWhh_d,
    const float* __restrict__ Wpe, const float* __restrict__ bpe,
    const float* __restrict__ bih_e, const float* __restrict__ bhh_e,
    const float* __restrict__ Wpd, const float* __restrict__ bpd,
    const float* __restrict__ bih_d, const float* __restrict__ bhh_d,
    const float* __restrict__ W2, const float* __restrict__ b2,
    const float* __restrict__ Wo, const float* __restrict__ bo,
    float* W3e, float* W3d, float* biasE, float* biasD, float* W2Wo, float* b2Wo)
{
  int blk = blockIdx.x;
  if (blk < 2560) {
    const float* W; f16* o; int N, base;
    if      (blk < 1024) { W=Wse;   o=pWse;   N=256;  base=0; }
    else if (blk < 2048) { W=Wsd;   o=pWsd;   N=256;  base=1024; }
    else if (blk < 2176) { W=Wih_e; o=pWih_e; N=1024; base=2048; }  // k rows 0..255 (sal part)
    else if (blk < 2304) { W=Wih_d; o=pWih_d; N=1024; base=2176; }
    else if (blk < 2432) { W=Whh_e; o=pWhh_e; N=1024; base=2304; }
    else                 { W=Whh_d; o=pWhh_d; N=1024; base=2432; }
    int tid = (blk - base)*256 + threadIdx.x;
    int l = tid & 63;
    int nct = N >> 4;
    int ctg = (tid >> 6) % nct;
    int kfg = (tid >> 6) / nct;
    int k0  = kfg*32 + ((l>>4)<<3);
    int col = ctg*16 + (l&15);
    f16x8 v;
#pragma unroll
    for (int i=0;i<8;++i) v[i] = (f16)W[(size_t)(k0+i)*N + col];
    *(f16x8*)(o + (size_t)tid*8) = v;
    return;
  }
  int bid = blk - 2560, tid = threadIdx.x;
  if (bid < 4) {
    int j = bid*256 + tid;
    float s0=0,s1=0,s2=0,sb=0;
    for (int m=0;m<256;++m) {
      float wv = Wih_e[(size_t)(256+m)*1024 + j];
      s0 += Wpe[m]*wv; s1 += Wpe[256+m]*wv; s2 += Wpe[512+m]*wv; sb += bpe[m]*wv;
    }
    W3e[j]=s0; W3e[1024+j]=s1; W3e[2048+j]=s2;
    biasE[j] = bih_e[j] + bhh_e[j] + sb;
  } else if (bid < 8) {
    int j = (bid-4)*256 + tid;
    float s0=0,s1=0,s2=0,sb=0;
    for (int m=0;m<256;++m) {
      float wv = Wih_d[(size_t)(256+m)*1024 + j];
      s0 += Wpd[m]*wv; s1 += Wpd[256+m]*wv; s2 += Wpd[512+m]*wv; sb += bpd[m]*wv;
    }
    W3d[j]=s0; W3d[1024+j]=s1; W3d[2048+j]=s2;
    biasD[j] = bih_d[j] + bhh_d[j] + sb;
  } else if (bid == 8) {
    int c = tid;
    float s0=0,s1=0,s2=0;
    for (int m=0;m<256;++m) {
      float wv = W2[(size_t)c*256+m];
      s0 += wv*Wo[m*3+0]; s1 += wv*Wo[m*3+1]; s2 += wv*Wo[m*3+2];
    }
    W2Wo[c*3+0]=s0; W2Wo[c*3+1]=s1; W2Wo[c*3+2]=s2;
  } else {
    if (tid < 192) {
      int j = tid >> 6, lane = tid & 63;
      float s = 0.f;
      for (int m=lane;m<256;m+=64) s += b2[m]*Wo[m*3+j];
#pragma unroll
      for (int msk=1;msk<64;msk<<=1) s += __shfl_xor(s, msk);
      if (lane==0) b2Wo[j] = s + bo[j];
    }
  }
}

// ======== fused GEMM: preg = (A(f32,K=8192)@Ws + bs) @ Wih + bias [+ pos@W3] =
// t-major row permutation: tile rows r' = t*1024+b (64 consecutive b, fixed t);
// A-source row = b*T + t. Stage-1 sal tile stays in LDS; stage-2 writes
// fragment-order preg. For the ENCODER job, pos@W3e is folded in here too
// (enc pos is non-recurrent), so k_rnn's encoder gate math is acc-only.
__global__ __launch_bounds__(256) void k_gemm_fused(
    const float* __restrict__ A0, const f16* __restrict__ W0,
    const float* __restrict__ bs0, const f16* __restrict__ Wih0,
    const float* __restrict__ bias0, f16* __restrict__ P0, int nb0, int T0,
    const float* __restrict__ pos0, const float* __restrict__ W3f0,
    const float* __restrict__ A1, const f16* __restrict__ W1,
    const float* __restrict__ bs1, const f16* __restrict__ Wih1,
    const float* __restrict__ bias1, f16* __restrict__ P1, int T1)
{
  __shared__ f16 aLDS[2][64*64];   // 16 KB: stage-1 A tiles, 16B-slot ^= row&7
  __shared__ f16 sLDS[64*256];     // 32 KB: sal tile, 16B-slot ^= row&7
  const int tid = threadIdx.x, l = tid & 63, w = tid >> 6;
  const int li = l & 15, hi = l >> 4;
  const int bx = blockIdx.x;
  const float *Ap, *bs, *bias, *posf, *W3f; const f16 *Wp, *Wih; f16* P; int rblk, T;
  if (bx < nb0) { Ap=A0; Wp=W0; bs=bs0; Wih=Wih0; bias=bias0; P=P0; rblk=bx*64;       T=T0; posf=pos0; W3f=W3f0; }
  else          { Ap=A1; Wp=W1; bs=bs1; Wih=Wih1; bias=bias1; P=P1; rblk=(bx-nb0)*64; T=T1; posf=nullptr; W3f=nullptr; }
  const int t = rblk >> 10, b0 = rblk & 1023;

  f32x4 acc[4][4];
#pragma unroll
  for (int a=0;a<4;++a)
#pragma unroll
    for (int b=0;b<4;++b) acc[a][b] = (f32x4){0.f,0.f,0.f,0.f};

  const int srow = tid >> 2, kseg = tid & 3;   // 64 rows x 4 k-segs
  const float* Arow = Ap + ((size_t)(b0 + srow)*T + t)*8192 + kseg*16;

  float4 f0,f1,f2,f3;
#define LOADA(ti_) { const float* Aq = Arow + (ti_)*64;                       \
    f0 = *(const float4*)Aq;     f1 = *(const float4*)(Aq+4);                 \
    f2 = *(const float4*)(Aq+8); f3 = *(const float4*)(Aq+12); }

  LOADA(0);
  for (int ti = 0; ti < 128; ++ti) {
    const int buf = ti & 1;
    f16x8 w0, w1;
    w0[0]=(f16)f0.x; w0[1]=(f16)f0.y; w0[2]=(f16)f0.z; w0[3]=(f16)f0.w;
    w0[4]=(f16)f1.x; w0[5]=(f16)f1.y; w0[6]=(f16)f1.z; w0[7]=(f16)f1.w;
    w1[0]=(f16)f2.x; w1[1]=(f16)f2.y; w1[2]=(f16)f2.z; w1[3]=(f16)f2.w;
    w1[4]=(f16)f3.x; w1[5]=(f16)f3.y; w1[6]=(f16)f3.z; w1[7]=(f16)f3.w;
    __syncthreads();     // readers of this buf (iter ti-2) done
    *(f16x8*)&aLDS[buf][srow*64 + ((kseg*2    ) ^ (srow&7))*8] = w0;
    *(f16x8*)&aLDS[buf][srow*64 + ((kseg*2 + 1) ^ (srow&7))*8] = w1;
    if (ti + 1 < 128) LOADA(ti+1);    // prefetch flies under MFMA phase
    __syncthreads();
    const int kfg0 = ti*2;
#pragma unroll
    for (int kf = 0; kf < 2; ++kf) {
      f16x8 afr[4], bfr[4];
#pragma unroll
      for (int rt=0; rt<4; ++rt) {
        int row = rt*16 + li;
        afr[rt] = *(f16x8*)&aLDS[buf][row*64 + (((kf*4) + hi) ^ (row&7))*8];
      }
#pragma unroll
      for (int ct=0; ct<4; ++ct) {
        int ctg = w*4 + ct;
        bfr[ct] = *(const f16x8*)(Wp + ((size_t)((kfg0+kf)*16 + ctg)*64 + l)*8);
      }
#pragma unroll
      for (int rt=0; rt<4; ++rt)
#pragma unroll
        for (int ct=0; ct<4; ++ct)
          acc[rt][ct] = MFMA16(afr[rt], bfr[ct], acc[rt][ct]);
    }
  }
#undef LOADA
  // stage-1 epilogue: sal tile (+bs) -> LDS, swizzled row-major [64][256]
#pragma unroll
  for (int ct=0; ct<4; ++ct) {
    int col = (w*4 + ct)*16 + li;
    float bv = bs[col];
    int slot = col >> 3;
#pragma unroll
    for (int rt=0; rt<4; ++rt)
#pragma unroll
      for (int i=0;i<4;++i) {
        int row = rt*16 + hi*4 + i;
        sLDS[row*256 + ((slot ^ (row&7))<<3) + (col&7)] = (f16)(acc[rt][ct][i] + bv);
      }
  }
  // enc job: load per-row pos once (reused across all output cols)
  float pe[4][4][3];
  if (posf) {
#pragma unroll
    for (int rt=0; rt<4; ++rt)
#pragma unroll
      for (int i=0;i<4;++i) {
        int brow = b0 + rt*16 + hi*4 + i;
        const float* pq = posf + ((size_t)brow*T + t)*3;
        pe[rt][i][0]=pq[0]; pe[rt][i][1]=pq[1]; pe[rt][i][2]=pq[2];
      }
  }
  __syncthreads();
  // stage-2: sal(64x256) @ Wih(256x1024), 4 col-chunks of 256
  const int bblk0 = b0 >> 4;
#pragma unroll
  for (int cg=0; cg<4; ++cg) {
    f32x4 a2[4][4];
#pragma unroll
    for (int a=0;a<4;++a)
#pragma unroll
      for (int b=0;b<4;++b) a2[a][b] = (f32x4){0.f,0.f,0.f,0.f};
#pragma unroll
    for (int kfg=0; kfg<8; ++kfg) {
      f16x8 afr[4], bfr[4];
#pragma unroll
      for (int rt=0; rt<4; ++rt) {
        int row = rt*16 + li;
        afr[rt] = *(f16x8*)&sLDS[row*256 + (((kfg*4 + hi) ^ (row&7))<<3)];
      }
#pragma unroll
      for (int ct=0; ct<4; ++ct) {
        int ctg2 = cg*16 + w*4 + ct;
        bfr[ct] = *(const f16x8*)(Wih + ((size_t)(kfg*64 + ctg2)*64 + l)*8);
      }
#pragma unroll
      for (int rt=0; rt<4; ++rt)
#pragma unroll
        for (int ct=0; ct<4; ++ct)
          a2[rt][ct] = MFMA16(afr[rt], bfr[ct], a2[rt][ct]);
    }
    // fragment-order store (identity with k_rnn's C-init loads); bias (+pos@W3) folded
#pragma unroll
    for (int ct=0; ct<4; ++ct) {
      const int ctg2 = cg*16 + w*4 + ct;
      const float bv = bias[ctg2*16 + li];
      float w30=0.f, w31=0.f, w32=0.f;
      if (posf) { int gc = ctg2*16 + li; w30=W3f[gc]; w31=W3f[1024+gc]; w32=W3f[2048+gc]; }
#pragma unroll
      for (int rt=0; rt<4; ++rt) {
        f16x4 o;
#pragma unroll
        for (int i=0;i<4;++i) {
          float v = a2[rt][ct][i] + bv;
          if (posf) v += pe[rt][i][0]*w30 + pe[rt][i][1]*w31 + pe[rt][i][2]*w32;
          o[i] = (f16)v;
        }
        *(f16x4*)(P + ((size_t)((bblk0 + rt)*T + t)*64 + ctg2)*256 + l*4) = o;
      }
    }
  }
}

// ================= fused recurrent kernel: encoder(5) then decoder(25) ======
// 64 blocks x 16 rows, 512 threads (8 waves). wave w owns h-cols [w*32,+32):
// ctg = q*16 + w*2 + j -> gate quadruples lane-local.
// Whh kf0-1 held in registers for all steps; kf2-7 streamed from L2.
// h double-buffered in LDS -> ONE barrier per step. Decoder pos carried
// redundantly in registers; cross-wave delta via LDS atomicAdd into a
// per-step dpart slot (no re-zeroing, no extra barrier).
__global__ __launch_bounds__(512) void k_rnn(
    const f16* __restrict__ pregE,   // [b_blk][5][64][64][4]  (pos+bias folded)
    const f16* __restrict__ pregD,   // [b_blk][25][64][64][4] (bias folded)
    const f16* __restrict__ Whh_e_p, const f16* __restrict__ Whh_d_p,
    const float* __restrict__ W3d, const float* __restrict__ dec_pos,
    const float* __restrict__ W2Wo, const float* __restrict__ b2Wo,
    float* __restrict__ out)         // (B,25,3)
{
  __shared__ f16 hBuf[2][16*256];    // swizzled (16B slot ^= row&7)
  __shared__ float dpart[25][16][3]; // per-step delta accumulators
  const int tid = threadIdx.x, l = tid & 63, w = tid >> 6;
  const int li = l & 15, hi = l >> 4;
  const int bblk = blockIdx.x, rb = bblk*16;

  for (int i=tid; i<25*16*3; i+=512) ((float*)dpart)[i] = 0.f;

  float c_st[2][4];
#pragma unroll
  for (int j=0;j<2;++j)
#pragma unroll
    for (int i=0;i<4;++i) c_st[j][i]=0.f;

  // held Whh fragments for kf = 0..1 (this wave's 8 ctg)
  f16x8 bhh[2][4][2];
#define LOAD_HELD(WP)                                                         \
  _Pragma("unroll")                                                           \
  for (int kf2=0;kf2<2;++kf2)                                                 \
    _Pragma("unroll")                                                         \
    for (int q=0;q<4;++q)                                                     \
      _Pragma("unroll")                                                       \
      for (int j=0;j<2;++j)                                                   \
        bhh[kf2][q][j] = *(const f16x8*)((WP) + ((size_t)(kf2*64 + q*16+w*2+j)*64 + l)*8);

#define LOADPV(dst, base, t_)                                                 \
  _Pragma("unroll")                                                           \
  for (int q=0;q<4;++q)                                                       \
    _Pragma("unroll")                                                         \
    for (int j=0;j<2;++j)                                                     \
      dst[q][j] = *(const f16x4*)((base) + ((size_t)(t_)*16384 + (size_t)(q*16 + w*2 + j)*256 + l*4));

#define COPYPV()                                                              \
  _Pragma("unroll")                                                           \
  for (int q=0;q<4;++q)                                                       \
    _Pragma("unroll")                                                         \
    for (int j=0;j<2;++j) pvA[q][j] = pvB[q][j];

#define ACCINIT()                                                             \
  f32x4 acc[4][2];                                                            \
  _Pragma("unroll")                                                           \
  for (int q=0;q<4;++q)                                                       \
    _Pragma("unroll")                                                         \
    for (int j=0;j<2;++j)                                                     \
      acc[q][j] = (f32x4){(float)pvA[q][j][0],(float)pvA[q][j][1],(float)pvA[q][j][2],(float)pvA[q][j][3]};

#define MFMA_STEP(hB, WP)                                                     \
  _Pragma("unroll")                                                           \
  for (int kf2=0;kf2<2;++kf2) {                                               \
    f16x8 ah = *(f16x8*)&(hB)[li*256 + (((kf2*4)+hi) ^ (li&7))*8];            \
    _Pragma("unroll")                                                         \
    for (int q=0;q<4;++q)                                                     \
      _Pragma("unroll")                                                       \
      for (int j=0;j<2;++j) acc[q][j] = MFMA16(ah, bhh[kf2][q][j], acc[q][j]);\
  }                                                                           \
  _Pragma("unroll")                                                           \
  for (int kf=2;kf<8;++kf) {                                                  \
    f16x8 ah = *(f16x8*)&(hB)[li*256 + (((kf*4)+hi) ^ (li&7))*8];             \
    _Pragma("unroll")                                                         \
    for (int q=0;q<4;++q)                                                     \
      _Pragma("unroll")                                                       \
      for (int j=0;j<2;++j) {                                                 \
        f16x8 b = *(const f16x8*)((WP) + ((size_t)(kf*64 + q*16+w*2+j)*64 + l)*8); \
        acc[q][j] = MFMA16(ah, b, acc[q][j]);                                 \
      }                                                                       \
  }

  LOAD_HELD(Whh_e_p)

  // ---------------- encoder (gate = acc only: bias+pos pre-folded) ---------
  const f16* prE = pregE + (size_t)bblk*5*16384;
  f16x4 pvA[4][2], pvB[4][2];
  LOADPV(pvA, prE, 0)
  __syncthreads();                 // dpart zero-init visible (decoder)
  for (int t=0;t<5;++t) {
    if (t+1 < 5) LOADPV(pvB, prE, t+1)
    ACCINIT()
    if (t > 0) { MFMA_STEP(hBuf[(t-1)&1], Whh_e_p) }
#pragma unroll
    for (int i=0;i<4;++i) {
      int r = hi*4 + i;
#pragma unroll
      for (int j=0;j<2;++j) {
        int hc = w*32 + j*16 + li;
        float cn = sigm(acc[1][j][i])*c_st[j][i] + sigm(acc[0][j][i])*tanhf(acc[2][j][i]);
        c_st[j][i] = cn;
        float h = sigm(acc[3][j][i])*tanhf(cn);
        hBuf[t&1][r*256 + (((hc>>3) ^ (r&7))<<3) + (hc&7)] = (f16)h;
      }
    }
    if (t+1 < 5) { COPYPV() }
    __syncthreads();               // h[t] visible for t+1
  }

  // ---------------- decoder constants ----------------
  LOAD_HELD(Whh_d_p)
  float w3r[2][4][3];
#pragma unroll
  for (int j=0;j<2;++j)
#pragma unroll
    for (int q=0;q<4;++q) {
      int gc = q*256 + w*32 + j*16 + li;
      w3r[j][q][0]=W3d[gc]; w3r[j][q][1]=W3d[1024+gc]; w3r[j][q][2]=W3d[2048+gc];
    }
  float w2r[2][3];
#pragma unroll
  for (int j=0;j<2;++j) {
    int hc = w*32 + j*16 + li;
    w2r[j][0]=W2Wo[hc*3+0]; w2r[j][1]=W2Wo[hc*3+1]; w2r[j][2]=W2Wo[hc*3+2];
  }
  const float b2w0 = b2Wo[0], b2w1 = b2Wo[1], b2w2 = b2Wo[2];
  float pp[4][3];
#pragma unroll
  for (int i=0;i<4;++i) {
    int r = rb + hi*4 + i;
    pp[i][0]=dec_pos[r*3+0]; pp[i][1]=dec_pos[r*3+1]; pp[i][2]=dec_pos[r*3+2];
  }

  // ---------------- decoder (1 barrier/step) ----------------
  // enc t=4 wrote hBuf[0]; dec step t reads hBuf[t&1], writes hBuf[(t+1)&1].
  const f16* prD = pregD + (size_t)bblk*25*16384;
  LOADPV(pvA, prD, 0)
  for (int t=0;t<25;++t) {
    if (t+1 < 25) LOADPV(pvB, prD, t+1)
    ACCINIT()
    MFMA_STEP(hBuf[t&1], Whh_d_p)
    float dpar[4][3];
#pragma unroll
    for (int i=0;i<4;++i){ dpar[i][0]=0.f; dpar[i][1]=0.f; dpar[i][2]=0.f; }
#pragma unroll
    for (int i=0;i<4;++i) {
      int r = hi*4 + i;
#pragma unroll
      for (int j=0;j<2;++j) {
        int hc = w*32 + j*16 + li;
        float gq[4];
#pragma unroll
        for (int q=0;q<4;++q)
          gq[q] = acc[q][j][i] + pp[i][0]*w3r[j][q][0] + pp[i][1]*w3r[j][q][1] + pp[i][2]*w3r[j][q][2];
        float cn = sigm(gq[1])*c_st[j][i] + sigm(gq[0])*tanhf(gq[2]);
        c_st[j][i] = cn;
        float h = sigm(gq[3])*tanhf(cn);
        hBuf[(t+1)&1][r*256 + (((hc>>3) ^ (r&7))<<3) + (hc&7)] = (f16)h;
        dpar[i][0] += h*w2r[j][0];
        dpar[i][1] += h*w2r[j][1];
        dpar[i][2] += h*w2r[j][2];
      }
    }
#pragma unroll
    for (int m=1;m<16;m<<=1)
#pragma unroll
      for (int i=0;i<4;++i) {
        dpar[i][0] += __shfl_xor(dpar[i][0], m);
        dpar[i][1] += __shfl_xor(dpar[i][1], m);
        dpar[i][2] += __shfl_xor(dpar[i][2], m);
      }
    if (li==0) {
#pragma unroll
      for (int i=0;i<4;++i) {
        int r = hi*4 + i;
        atomicAdd(&dpart[t][r][0], dpar[i][0]);
        atomicAdd(&dpart[t][r][1], dpar[i][1]);
        atomicAdd(&dpart[t][r][2], dpar[i][2]);
      }
    }
    if (t+1 < 25) { COPYPV() }
    __syncthreads();               // h[t+1] + dpart[t] visible
    // pos update (redundant per 16-lane group, identical FP ops -> identical)
#pragma unroll
    for (int i=0;i<4;++i) {
      int r = hi*4 + i;
      float p0 = pp[i][0] + b2w0 + dpart[t][r][0];
      float p1 = pp[i][1] + b2w1 + dpart[t][r][1];
      float p2 = pp[i][2] + b2w2 + dpart[t][r][2];
      float inv = 1.0f/sqrtf(p0*p0+p1*p1+p2*p2);
      pp[i][0]=p0*inv; pp[i][1]=p1*inv; pp[i][2]=p2*inv;
      if (w==0 && li==0) {
        float* o = out + (size_t)(rb+r)*75 + t*3;
        o[0]=pp[i][0]; o[1]=pp[i][1]; o[2]=pp[i][2];
      }
    }
  }
#undef LOAD_HELD
#undef LOADPV
#undef COPYPV
#undef ACCINIT
#undef MFMA_STEP
}

// ================= launch =================
extern "C" void kernel_launch(void* const* d_in, const int* in_sizes, int n_in,
                              void* d_out, int out_size, void* d_ws, size_t ws_size,
                              hipStream_t stream)
{
  const float* enc_pos = (const float*)d_in[0];
  const float* enc_sal = (const float*)d_in[1];
  const float* dec_pos = (const float*)d_in[2];
  const float* dec_sal = (const float*)d_in[3];
  const float* Wpe  = (const float*)d_in[4];
  const float* bpe  = (const float*)d_in[5];
  const float* Wse  = (const float*)d_in[6];
  const float* bse  = (const float*)d_in[7];
  const float* Wih_e= (const float*)d_in[8];
  const float* Whh_e= (const float*)d_in[9];
  const float* bih_e= (const float*)d_in[10];
  const float* bhh_e= (const float*)d_in[11];
  const float* Wih_d= (const float*)d_in[12];
  const float* Whh_d= (const float*)d_in[13];
  const float* bih_d= (const float*)d_in[14];
  const float* bhh_d= (const float*)d_in[15];
  const float* Wpd  = (const float*)d_in[16];
  const float* bpd  = (const float*)d_in[17];
  const float* Wsd  = (const float*)d_in[18];
  const float* bsd  = (const float*)d_in[19];
  const float* W2   = (const float*)d_in[20];
  const float* b2   = (const float*)d_in[21];
  const float* Wo   = (const float*)d_in[22];
  const float* bo   = (const float*)d_in[23];

  char* ws = (char*)d_ws;
  f16* pWse   = (f16*)(ws + OFF_WSE_P);
  f16* pWsd   = (f16*)(ws + OFF_WSD_P);
  f16* pWih_e = (f16*)(ws + OFF_WIHE_P);
  f16* pWih_d = (f16*)(ws + OFF_WIHD_P);
  f16* pWhh_e = (f16*)(ws + OFF_WHHE_P);
  f16* pWhh_d = (f16*)(ws + OFF_WHHD_P);
  float* W3e  = (float*)(ws + OFF_W3E);
  float* W3d  = (float*)(ws + OFF_W3D);
  float* W2WoP= (float*)(ws + OFF_W2WO);
  float* biasE= (float*)(ws + OFF_BIASE);
  float* biasD= (float*)(ws + OFF_BIASD);
  float* b2WoP= (float*)(ws + OFF_B2WO);
  f16* pregE  = (f16*)(ws + OFF_PREGE);
  f16* pregD  = (f16*)(ws + OFF_PREGD);
  float* out  = (float*)d_out;

  hipLaunchKernelGGL(k_prep, dim3(2570), dim3(256), 0, stream,
                     Wse, Wsd, Wih_e, Wih_d, Whh_e, Whh_d,
                     pWse, pWsd, pWih_e, pWih_d, pWhh_e, pWhh_d,
                     Wpe, bpe, bih_e, bhh_e, Wpd, bpd, bih_d, bhh_d,
                     W2, b2, Wo, bo,
                     W3e, W3d, biasE, biasD, W2WoP, b2WoP);
  // fused sal-projection + pre-gate GEMM: enc tiles [0,80) (pos folded), dec [80,480)
  hipLaunchKernelGGL(k_gemm_fused, dim3(480), dim3(256), 0, stream,
                     enc_sal, pWse, bse, pWih_e, biasE, pregE, 80, 5, enc_pos, W3e,
                     dec_sal, pWsd, bsd, pWih_d, biasD, pregD, 25);
  // fused encoder+decoder recurrence
  hipLaunchKernelGGL(k_rnn, dim3(64), dim3(512), 0, stream,
                     pregE, pregD, pWhh_e, pWhh_d,
                     W3d, dec_pos, W2WoP, b2WoP, out);
}

// Round 8
// 817.565 us; speedup vs baseline: 1.1116x; 1.1116x over previous
//
#include <hip/hip_runtime.h>

typedef _Float16 f16;
typedef _Float16 f16x4 __attribute__((ext_vector_type(4)));
typedef _Float16 f16x8 __attribute__((ext_vector_type(8)));
typedef float    f32x4 __attribute__((ext_vector_type(4)));

#define MFMA16(a,b,c) __builtin_amdgcn_mfma_f32_16x16x32_f16((a),(b),(c),0,0,0)

static __device__ __forceinline__ float frcp(float x){ float r; asm("v_rcp_f32 %0, %1" : "=v"(r) : "v"(x)); return r; }
static __device__ __forceinline__ float sigm(float x){ return frcp(1.0f + __expf(-x)); }
static __device__ __forceinline__ float tanh_(float x){ return 1.0f - 2.0f*frcp(1.0f + __expf(2.0f*x)); }

// ---------------- workspace layout (bytes) ----------------
static constexpr size_t OFF_WSE_P  = 0;                                  // 4 MB
static constexpr size_t OFF_WSD_P  = OFF_WSE_P  + (size_t)8192*256*2;    // 4 MB
static constexpr size_t OFF_WIHE_P = OFF_WSD_P  + (size_t)8192*256*2;    // 512 KB
static constexpr size_t OFF_WIHD_P = OFF_WIHE_P + (size_t)256*1024*2;
static constexpr size_t OFF_WHHE_P = OFF_WIHD_P + (size_t)256*1024*2;
static constexpr size_t OFF_WHHD_P = OFF_WHHE_P + (size_t)256*1024*2;
static constexpr size_t OFF_W3E    = OFF_WHHD_P + (size_t)256*1024*2;
static constexpr size_t OFF_W3D    = OFF_W3E   + (size_t)3*1024*4;
static constexpr size_t OFF_W2WO   = OFF_W3D   + (size_t)3*1024*4;
static constexpr size_t OFF_BIASE  = OFF_W2WO  + (size_t)256*3*4;
static constexpr size_t OFF_BIASD  = OFF_BIASE + (size_t)1024*4;
static constexpr size_t OFF_B2WO   = OFF_BIASD + (size_t)1024*4;
static constexpr size_t OFF_PREGE  = OFF_B2WO  + 256;                    // 10.5 MB
static constexpr size_t OFF_PREGD  = OFF_PREGE + (size_t)5120*1024*2;    // 52.4 MB
static constexpr size_t OFF_END    = OFF_PREGD + (size_t)25600*1024*2;

// ================= prep: pack weights (blocks 0-2559) + small folds (2560-2569)
// pack layout [kfg][ctg][lane][8]; element (k,n): k = kfg*32+(l>>4)*8+i, n = ctg*16+(l&15)
__global__ __launch_bounds__(256) void k_prep(
    const float* __restrict__ Wse, const float* __restrict__ Wsd,
    const float* __restrict__ Wih_e, const float* __restrict__ Wih_d,
    const float* __restrict__ Whh_e, const float* __restrict__ Whh_d,
    f16* pWse, f16* pWsd, f16* pWih_e, f16* pWih_d, f16* pWhh_e, f16* pWhh_d,
    const float* __restrict__ Wpe, const float* __restrict__ bpe,
    const float* __restrict__ bih_e, const float* __restrict__ bhh_e,
    const float* __restrict__ Wpd, const float* __restrict__ bpd,
    const float* __restrict__ bih_d, const float* __restrict__ bhh_d,
    const float* __restrict__ W2, const float* __restrict__ b2,
    const float* __restrict__ Wo, const float* __restrict__ bo,
    float* W3e, float* W3d, float* biasE, float* biasD, float* W2Wo, float* b2Wo)
{
  int blk = blockIdx.x;
  if (blk < 2560) {
    const float* W; f16* o; int N, base;
    if      (blk < 1024) { W=Wse;   o=pWse;   N=256;  base=0; }
    else if (blk < 2048) { W=Wsd;   o=pWsd;   N=256;  base=1024; }
    else if (blk < 2176) { W=Wih_e; o=pWih_e; N=1024; base=2048; }  // k rows 0..255 (sal part)
    else if (blk < 2304) { W=Wih_d; o=pWih_d; N=1024; base=2176; }
    else if (blk < 2432) { W=Whh_e; o=pWhh_e; N=1024; base=2304; }
    else                 { W=Whh_d; o=pWhh_d; N=1024; base=2432; }
    int tid = (blk - base)*256 + threadIdx.x;
    int l = tid & 63;
    int nct = N >> 4;
    int ctg = (tid >> 6) % nct;
    int kfg = (tid >> 6) / nct;
    int k0  = kfg*32 + ((l>>4)<<3);
    int col = ctg*16 + (l&15);
    f16x8 v;
#pragma unroll
    for (int i=0;i<8;++i) v[i] = (f16)W[(size_t)(k0+i)*N + col];
    *(f16x8*)(o + (size_t)tid*8) = v;
    return;
  }
  int bid = blk - 2560, tid = threadIdx.x;
  if (bid < 4) {
    int j = bid*256 + tid;
    float s0=0,s1=0,s2=0,sb=0;
    for (int m=0;m<256;++m) {
      float wv = Wih_e[(size_t)(256+m)*1024 + j];
      s0 += Wpe[m]*wv; s1 += Wpe[256+m]*wv; s2 += Wpe[512+m]*wv; sb += bpe[m]*wv;
    }
    W3e[j]=s0; W3e[1024+j]=s1; W3e[2048+j]=s2;
    biasE[j] = bih_e[j] + bhh_e[j] + sb;
  } else if (bid < 8) {
    int j = (bid-4)*256 + tid;
    float s0=0,s1=0,s2=0,sb=0;
    for (int m=0;m<256;++m) {
      float wv = Wih_d[(size_t)(256+m)*1024 + j];
      s0 += Wpd[m]*wv; s1 += Wpd[256+m]*wv; s2 += Wpd[512+m]*wv; sb += bpd[m]*wv;
    }
    W3d[j]=s0; W3d[1024+j]=s1; W3d[2048+j]=s2;
    biasD[j] = bih_d[j] + bhh_d[j] + sb;
  } else if (bid == 8) {
    int c = tid;
    float s0=0,s1=0,s2=0;
    for (int m=0;m<256;++m) {
      float wv = W2[(size_t)c*256+m];
      s0 += wv*Wo[m*3+0]; s1 += wv*Wo[m*3+1]; s2 += wv*Wo[m*3+2];
    }
    W2Wo[c*3+0]=s0; W2Wo[c*3+1]=s1; W2Wo[c*3+2]=s2;
  } else {
    if (tid < 192) {
      int j = tid >> 6, lane = tid & 63;
      float s = 0.f;
      for (int m=lane;m<256;m+=64) s += b2[m]*Wo[m*3+j];
#pragma unroll
      for (int msk=1;msk<64;msk<<=1) s += __shfl_xor(s, msk);
      if (lane==0) b2Wo[j] = s + bo[j];
    }
  }
}

// ======== fused GEMM: preg = (A(f32,K=8192)@Ws + bs) @ Wih + bias [+ pos@W3] =
__global__ __launch_bounds__(256) void k_gemm_fused(
    const float* __restrict__ A0, const f16* __restrict__ W0,
    const float* __restrict__ bs0, const f16* __restrict__ Wih0,
    const float* __restrict__ bias0, f16* __restrict__ P0, int nb0, int T0,
    const float* __restrict__ pos0, const float* __restrict__ W3f0,
    const float* __restrict__ A1, const f16* __restrict__ W1,
    const float* __restrict__ bs1, const f16* __restrict__ Wih1,
    const float* __restrict__ bias1, f16* __restrict__ P1, int T1)
{
  __shared__ f16 aLDS[2][64*64];   // 16 KB: stage-1 A tiles, 16B-slot ^= row&7
  __shared__ f16 sLDS[64*256];     // 32 KB: sal tile, 16B-slot ^= row&7
  const int tid = threadIdx.x, l = tid & 63, w = tid >> 6;
  const int li = l & 15, hi = l >> 4;
  const int bx = blockIdx.x;
  const float *Ap, *bs, *bias, *posf, *W3f; const f16 *Wp, *Wih; f16* P; int rblk, T;
  if (bx < nb0) { Ap=A0; Wp=W0; bs=bs0; Wih=Wih0; bias=bias0; P=P0; rblk=bx*64;       T=T0; posf=pos0; W3f=W3f0; }
  else          { Ap=A1; Wp=W1; bs=bs1; Wih=Wih1; bias=bias1; P=P1; rblk=(bx-nb0)*64; T=T1; posf=nullptr; W3f=nullptr; }
  const int t = rblk >> 10, b0 = rblk & 1023;

  f32x4 acc[4][4];
#pragma unroll
  for (int a=0;a<4;++a)
#pragma unroll
    for (int b=0;b<4;++b) acc[a][b] = (f32x4){0.f,0.f,0.f,0.f};

  const int srow = tid >> 2, kseg = tid & 3;   // 64 rows x 4 k-segs
  const float* Arow = Ap + ((size_t)(b0 + srow)*T + t)*8192 + kseg*16;

  float4 f0,f1,f2,f3;
#define LOADA(ti_) { const float* Aq = Arow + (ti_)*64;                       \
    f0 = *(const float4*)Aq;     f1 = *(const float4*)(Aq+4);                 \
    f2 = *(const float4*)(Aq+8); f3 = *(const float4*)(Aq+12); }

  LOADA(0);
  for (int ti = 0; ti < 128; ++ti) {
    const int buf = ti & 1;
    f16x8 w0, w1;
    w0[0]=(f16)f0.x; w0[1]=(f16)f0.y; w0[2]=(f16)f0.z; w0[3]=(f16)f0.w;
    w0[4]=(f16)f1.x; w0[5]=(f16)f1.y; w0[6]=(f16)f1.z; w0[7]=(f16)f1.w;
    w1[0]=(f16)f2.x; w1[1]=(f16)f2.y; w1[2]=(f16)f2.z; w1[3]=(f16)f2.w;
    w1[4]=(f16)f3.x; w1[5]=(f16)f3.y; w1[6]=(f16)f3.z; w1[7]=(f16)f3.w;
    __syncthreads();     // readers of this buf (iter ti-2) done
    *(f16x8*)&aLDS[buf][srow*64 + ((kseg*2    ) ^ (srow&7))*8] = w0;
    *(f16x8*)&aLDS[buf][srow*64 + ((kseg*2 + 1) ^ (srow&7))*8] = w1;
    if (ti + 1 < 128) LOADA(ti+1);    // prefetch flies under MFMA phase
    __syncthreads();
    const int kfg0 = ti*2;
#pragma unroll
    for (int kf = 0; kf < 2; ++kf) {
      f16x8 afr[4], bfr[4];
#pragma unroll
      for (int rt=0; rt<4; ++rt) {
        int row = rt*16 + li;
        afr[rt] = *(f16x8*)&aLDS[buf][row*64 + (((kf*4) + hi) ^ (row&7))*8];
      }
#pragma unroll
      for (int ct=0; ct<4; ++ct) {
        int ctg = w*4 + ct;
        bfr[ct] = *(const f16x8*)(Wp + ((size_t)((kfg0+kf)*16 + ctg)*64 + l)*8);
      }
#pragma unroll
      for (int rt=0; rt<4; ++rt)
#pragma unroll
        for (int ct=0; ct<4; ++ct)
          acc[rt][ct] = MFMA16(afr[rt], bfr[ct], acc[rt][ct]);
    }
  }
#undef LOADA
  // stage-1 epilogue: sal tile (+bs) -> LDS, swizzled row-major [64][256]
#pragma unroll
  for (int ct=0; ct<4; ++ct) {
    int col = (w*4 + ct)*16 + li;
    float bv = bs[col];
    int slot = col >> 3;
#pragma unroll
    for (int rt=0; rt<4; ++rt)
#pragma unroll
      for (int i=0;i<4;++i) {
        int row = rt*16 + hi*4 + i;
        sLDS[row*256 + ((slot ^ (row&7))<<3) + (col&7)] = (f16)(acc[rt][ct][i] + bv);
      }
  }
  // enc job: load per-row pos once (reused across all output cols)
  float pe[4][4][3];
  if (posf) {
#pragma unroll
    for (int rt=0; rt<4; ++rt)
#pragma unroll
      for (int i=0;i<4;++i) {
        int brow = b0 + rt*16 + hi*4 + i;
        const float* pq = posf + ((size_t)brow*T + t)*3;
        pe[rt][i][0]=pq[0]; pe[rt][i][1]=pq[1]; pe[rt][i][2]=pq[2];
      }
  }
  __syncthreads();
  // stage-2: sal(64x256) @ Wih(256x1024), 4 col-chunks of 256
  const int bblk0 = b0 >> 4;
#pragma unroll
  for (int cg=0; cg<4; ++cg) {
    f32x4 a2[4][4];
#pragma unroll
    for (int a=0;a<4;++a)
#pragma unroll
      for (int b=0;b<4;++b) a2[a][b] = (f32x4){0.f,0.f,0.f,0.f};
#pragma unroll
    for (int kfg=0; kfg<8; ++kfg) {
      f16x8 afr[4], bfr[4];
#pragma unroll
      for (int rt=0; rt<4; ++rt) {
        int row = rt*16 + li;
        afr[rt] = *(f16x8*)&sLDS[row*256 + (((kfg*4 + hi) ^ (row&7))<<3)];
      }
#pragma unroll
      for (int ct=0; ct<4; ++ct) {
        int ctg2 = cg*16 + w*4 + ct;
        bfr[ct] = *(const f16x8*)(Wih + ((size_t)(kfg*64 + ctg2)*64 + l)*8);
      }
#pragma unroll
      for (int rt=0; rt<4; ++rt)
#pragma unroll
        for (int ct=0; ct<4; ++ct)
          a2[rt][ct] = MFMA16(afr[rt], bfr[ct], a2[rt][ct]);
    }
    // fragment-order store (identity with k_rnn's C-init loads); bias (+pos@W3) folded
#pragma unroll
    for (int ct=0; ct<4; ++ct) {
      const int ctg2 = cg*16 + w*4 + ct;
      const float bv = bias[ctg2*16 + li];
      float w30=0.f, w31=0.f, w32=0.f;
      if (posf) { int gc = ctg2*16 + li; w30=W3f[gc]; w31=W3f[1024+gc]; w32=W3f[2048+gc]; }
#pragma unroll
      for (int rt=0; rt<4; ++rt) {
        f16x4 o;
#pragma unroll
        for (int i=0;i<4;++i) {
          float v = a2[rt][ct][i] + bv;
          if (posf) v += pe[rt][i][0]*w30 + pe[rt][i][1]*w31 + pe[rt][i][2]*w32;
          o[i] = (f16)v;
        }
        *(f16x4*)(P + ((size_t)((bblk0 + rt)*T + t)*64 + ctg2)*256 + l*4) = o;
      }
    }
  }
}

// ================= fused recurrent kernel: encoder(5) then decoder(25) ======
// 64 blocks x 16 rows, 512 threads (8 waves), __launch_bounds__(512,2) -> 256 VGPR.
// wave w owns h-cols [w*32,+32): ctg = q*16 + w*2 + j (gate quadruples lane-local).
// Whh streamed per step as 4 rolling batches of 2 kf (16 frags, 64 VGPR) —
// batch n+2 issues while batch n's MFMAs run. Fast sigm/tanh (v_exp + v_rcp).
__global__ __launch_bounds__(512, 2) void k_rnn(
    const f16* __restrict__ pregE,   // [b_blk][5][64][64][4]  (pos+bias folded)
    const f16* __restrict__ pregD,   // [b_blk][25][64][64][4] (bias folded)
    const f16* __restrict__ Whh_e_p, const f16* __restrict__ Whh_d_p,
    const float* __restrict__ W3d, const float* __restrict__ dec_pos,
    const float* __restrict__ W2Wo, const float* __restrict__ b2Wo,
    float* __restrict__ out)         // (B,25,3)
{
  __shared__ f16 hBuf[2][16*256];    // swizzled (16B slot ^= row&7)
  __shared__ float W3s[3*1024];
  __shared__ float dpart[25][16][3]; // per-step delta accumulators
  const int tid = threadIdx.x, l = tid & 63, w = tid >> 6;
  const int li = l & 15, hi = l >> 4;
  const int bblk = blockIdx.x, rb = bblk*16;

  for (int i=tid;i<3072;i+=512) W3s[i]=W3d[i];
  for (int i=tid; i<25*16*3; i+=512) ((float*)dpart)[i] = 0.f;

  float c_st[2][4];
#pragma unroll
  for (int j=0;j<2;++j)
#pragma unroll
    for (int i=0;i<4;++i) c_st[j][i]=0.f;

#define WLOAD(dst, WP, kfb)                                                   \
  _Pragma("unroll") for (int kk=0;kk<2;++kk)                                  \
  _Pragma("unroll") for (int q=0;q<4;++q)                                     \
  _Pragma("unroll") for (int j=0;j<2;++j)                                     \
    dst[kk][q][j] = *(const f16x8*)((WP) + ((size_t)(((kfb)+kk)*64 + q*16 + w*2 + j)*64 + l)*8);

#define AH2(dst, hB, kfb)                                                     \
  _Pragma("unroll") for (int kk=0;kk<2;++kk)                                  \
    dst[kk] = *(f16x8*)&(hB)[li*256 + (((((kfb)+kk)*4)+hi) ^ (li&7))*8];

#define MFMA_B2(WSET, AHS)                                                    \
  _Pragma("unroll") for (int kk=0;kk<2;++kk)                                  \
  _Pragma("unroll") for (int q=0;q<4;++q)                                     \
  _Pragma("unroll") for (int j=0;j<2;++j)                                     \
    acc[q][j] = MFMA16(AHS[kk], WSET[kk][q][j], acc[q][j]);

#define MFMA_STEP(hB, WP) {                                                   \
  f16x8 wa[2][4][2], wb[2][4][2];                                             \
  f16x8 aha[2], ahb[2];                                                       \
  WLOAD(wa, WP, 0) WLOAD(wb, WP, 2)                                           \
  AH2(aha, hB, 0) AH2(ahb, hB, 2)                                             \
  MFMA_B2(wa, aha)                                                            \
  WLOAD(wa, WP, 4) AH2(aha, hB, 4)                                            \
  MFMA_B2(wb, ahb)                                                            \
  WLOAD(wb, WP, 6) AH2(ahb, hB, 6)                                            \
  MFMA_B2(wa, aha)                                                            \
  MFMA_B2(wb, ahb) }

#define LOADPV(dst, base, t_)                                                 \
  _Pragma("unroll")                                                           \
  for (int q=0;q<4;++q)                                                       \
    _Pragma("unroll")                                                         \
    for (int j=0;j<2;++j)                                                     \
      dst[q][j] = *(const f16x4*)((base) + ((size_t)(t_)*16384 + (size_t)(q*16 + w*2 + j)*256 + l*4));

#define COPYPV()                                                              \
  _Pragma("unroll")                                                           \
  for (int q=0;q<4;++q)                                                       \
    _Pragma("unroll")                                                         \
    for (int j=0;j<2;++j) pvA[q][j] = pvB[q][j];

#define ACCINIT()                                                             \
  f32x4 acc[4][2];                                                            \
  _Pragma("unroll")                                                           \
  for (int q=0;q<4;++q)                                                       \
    _Pragma("unroll")                                                         \
    for (int j=0;j<2;++j)                                                     \
      acc[q][j] = (f32x4){(float)pvA[q][j][0],(float)pvA[q][j][1],(float)pvA[q][j][2],(float)pvA[q][j][3]};

  // ---------------- encoder (gate = acc only: bias+pos pre-folded) ---------
  const f16* prE = pregE + (size_t)bblk*5*16384;
  f16x4 pvA[4][2], pvB[4][2];
  LOADPV(pvA, prE, 0)
  __syncthreads();                 // W3s + dpart init visible
  for (int t=0;t<5;++t) {
    if (t+1 < 5) LOADPV(pvB, prE, t+1)
    ACCINIT()
    if (t > 0) MFMA_STEP(hBuf[(t-1)&1], Whh_e_p)
#pragma unroll
    for (int i=0;i<4;++i) {
      int r = hi*4 + i;
#pragma unroll
      for (int j=0;j<2;++j) {
        int hc = w*32 + j*16 + li;
        float cn = sigm(acc[1][j][i])*c_st[j][i] + sigm(acc[0][j][i])*tanh_(acc[2][j][i]);
        c_st[j][i] = cn;
        float h = sigm(acc[3][j][i])*tanh_(cn);
        hBuf[t&1][r*256 + (((hc>>3) ^ (r&7))<<3) + (hc&7)] = (f16)h;
      }
    }
    if (t+1 < 5) { COPYPV() }
    __syncthreads();               // h[t] visible for t+1
  }

  // ---------------- decoder constants ----------------
  float w2r[2][3];
#pragma unroll
  for (int j=0;j<2;++j) {
    int hc = w*32 + j*16 + li;
    w2r[j][0]=W2Wo[hc*3+0]; w2r[j][1]=W2Wo[hc*3+1]; w2r[j][2]=W2Wo[hc*3+2];
  }
  const float b2w0 = b2Wo[0], b2w1 = b2Wo[1], b2w2 = b2Wo[2];
  float pp[4][3];
#pragma unroll
  for (int i=0;i<4;++i) {
    int r = rb + hi*4 + i;
    pp[i][0]=dec_pos[r*3+0]; pp[i][1]=dec_pos[r*3+1]; pp[i][2]=dec_pos[r*3+2];
  }

  // ---------------- decoder (1 barrier/step) ----------------
  // enc t=4 wrote hBuf[0]; dec step t reads hBuf[t&1], writes hBuf[(t+1)&1].
  const f16* prD = pregD + (size_t)bblk*25*16384;
  LOADPV(pvA, prD, 0)
  for (int t=0;t<25;++t) {
    if (t+1 < 25) LOADPV(pvB, prD, t+1)
    ACCINIT()
    MFMA_STEP(hBuf[t&1], Whh_d_p)
    float dpar[4][3];
#pragma unroll
    for (int i=0;i<4;++i){ dpar[i][0]=0.f; dpar[i][1]=0.f; dpar[i][2]=0.f; }
#pragma unroll
    for (int i=0;i<4;++i) {
      int r = hi*4 + i;
#pragma unroll
      for (int j=0;j<2;++j) {
        int hc = w*32 + j*16 + li;
        float gq[4];
#pragma unroll
        for (int q=0;q<4;++q) {
          int gc = q*256 + hc;
          gq[q] = acc[q][j][i] + pp[i][0]*W3s[gc] + pp[i][1]*W3s[1024+gc] + pp[i][2]*W3s[2048+gc];
        }
        float cn = sigm(gq[1])*c_st[j][i] + sigm(gq[0])*tanh_(gq[2]);
        c_st[j][i] = cn;
        float h = sigm(gq[3])*tanh_(cn);
        hBuf[(t+1)&1][r*256 + (((hc>>3) ^ (r&7))<<3) + (hc&7)] = (f16)h;
        dpar[i][0] += h*w2r[j][0];
        dpar[i][1] += h*w2r[j][1];
        dpar[i][2] += h*w2r[j][2];
      }
    }
#pragma unroll
    for (int m=1;m<16;m<<=1)
#pragma unroll
      for (int i=0;i<4;++i) {
        dpar[i][0] += __shfl_xor(dpar[i][0], m);
        dpar[i][1] += __shfl_xor(dpar[i][1], m);
        dpar[i][2] += __shfl_xor(dpar[i][2], m);
      }
    if (li==0) {
#pragma unroll
      for (int i=0;i<4;++i) {
        int r = hi*4 + i;
        atomicAdd(&dpart[t][r][0], dpar[i][0]);
        atomicAdd(&dpart[t][r][1], dpar[i][1]);
        atomicAdd(&dpart[t][r][2], dpar[i][2]);
      }
    }
    if (t+1 < 25) { COPYPV() }
    __syncthreads();               // h[t+1] + dpart[t] visible
    // pos update (redundant per 16-lane group, identical FP ops -> identical)
#pragma unroll
    for (int i=0;i<4;++i) {
      int r = hi*4 + i;
      float p0 = pp[i][0] + b2w0 + dpart[t][r][0];
      float p1 = pp[i][1] + b2w1 + dpart[t][r][1];
      float p2 = pp[i][2] + b2w2 + dpart[t][r][2];
      float inv = 1.0f/sqrtf(p0*p0+p1*p1+p2*p2);
      pp[i][0]=p0*inv; pp[i][1]=p1*inv; pp[i][2]=p2*inv;
      if (w==0 && li==0) {
        float* o = out + (size_t)(rb+r)*75 + t*3;
        o[0]=pp[i][0]; o[1]=pp[i][1]; o[2]=pp[i][2];
      }
    }
  }
#undef WLOAD
#undef AH2
#undef MFMA_B2
#undef MFMA_STEP
#undef LOADPV
#undef COPYPV
#undef ACCINIT
}

// ================= launch =================
extern "C" void kernel_launch(void* const* d_in, const int* in_sizes, int n_in,
                              void* d_out, int out_size, void* d_ws, size_t ws_size,
                              hipStream_t stream)
{
  const float* enc_pos = (const float*)d_in[0];
  const float* enc_sal = (const float*)d_in[1];
  const float* dec_pos = (const float*)d_in[2];
  const float* dec_sal = (const float*)d_in[3];
  const float* Wpe  = (const float*)d_in[4];
  const float* bpe  = (const float*)d_in[5];
  const float* Wse  = (const float*)d_in[6];
  const float* bse  = (const float*)d_in[7];
  const float* Wih_e= (const float*)d_in[8];
  const float* Whh_e= (const float*)d_in[9];
  const float* bih_e= (const float*)d_in[10];
  const float* bhh_e= (const float*)d_in[11];
  const float* Wih_d= (const float*)d_in[12];
  const float* Whh_d= (const float*)d_in[13];
  const float* bih_d= (const float*)d_in[14];
  const float* bhh_d= (const float*)d_in[15];
  const float* Wpd  = (const float*)d_in[16];
  const float* bpd  = (const float*)d_in[17];
  const float* Wsd  = (const float*)d_in[18];
  const float* bsd  = (const float*)d_in[19];
  const float* W2   = (const float*)d_in[20];
  const float* b2   = (const float*)d_in[21];
  const float* Wo   = (const float*)d_in[22];
  const float* bo   = (const float*)d_in[23];

  char* ws = (char*)d_ws;
  f16* pWse   = (f16*)(ws + OFF_WSE_P);
  f16* pWsd   = (f16*)(ws + OFF_WSD_P);
  f16* pWih_e = (f16*)(ws + OFF_WIHE_P);
  f16* pWih_d = (f16*)(ws + OFF_WIHD_P);
  f16* pWhh_e = (f16*)(ws + OFF_WHHE_P);
  f16* pWhh_d = (f16*)(ws + OFF_WHHD_P);
  float* W3e  = (float*)(ws + OFF_W3E);
  float* W3d  = (float*)(ws + OFF_W3D);
  float* W2WoP= (float*)(ws + OFF_W2WO);
  float* biasE= (float*)(ws + OFF_BIASE);
  float* biasD= (float*)(ws + OFF_BIASD);
  float* b2WoP= (float*)(ws + OFF_B2WO);
  f16* pregE  = (f16*)(ws + OFF_PREGE);
  f16* pregD  = (f16*)(ws + OFF_PREGD);
  float* out  = (float*)d_out;

  hipLaunchKernelGGL(k_prep, dim3(2570), dim3(256), 0, stream,
                     Wse, Wsd, Wih_e, Wih_d, Whh_e, Whh_d,
                     pWse, pWsd, pWih_e, pWih_d, pWhh_e, pWhh_d,
                     Wpe, bpe, bih_e, bhh_e, Wpd, bpd, bih_d, bhh_d,
                     W2, b2, Wo, bo,
                     W3e, W3d, biasE, biasD, W2WoP, b2WoP);
  // fused sal-projection + pre-gate GEMM: enc tiles [0,80) (pos folded), dec [80,480)
  hipLaunchKernelGGL(k_gemm_fused, dim3(480), dim3(256), 0, stream,
                     enc_sal, pWse, bse, pWih_e, biasE, pregE, 80, 5, enc_pos, W3e,
                     dec_sal, pWsd, bsd, pWih_d, biasD, pregD, 25);
  // fused encoder+decoder recurrence
  hipLaunchKernelGGL(k_rnn, dim3(64), dim3(512), 0, stream,
                     pregE, pregD, pWhh_e, pWhh_d,
                     W3d, dec_pos, W2WoP, b2WoP, out);
}

// Round 9
// 809.254 us; speedup vs baseline: 1.1230x; 1.0103x over previous
//
#include <hip/hip_runtime.h>

typedef _Float16 f16;
typedef _Float16 f16x4 __attribute__((ext_vector_type(4)));
typedef _Float16 f16x8 __attribute__((ext_vector_type(8)));
typedef float    f32x4 __attribute__((ext_vector_type(4)));

#define MFMA16(a,b,c) __builtin_amdgcn_mfma_f32_16x16x32_f16((a),(b),(c),0,0,0)

static __device__ __forceinline__ float frcp(float x){ float r; asm("v_rcp_f32 %0, %1" : "=v"(r) : "v"(x)); return r; }
static __device__ __forceinline__ float sigm(float x){ return frcp(1.0f + __expf(-x)); }
static __device__ __forceinline__ float tanh_(float x){ return 1.0f - 2.0f*frcp(1.0f + __expf(2.0f*x)); }

// barrier with LDS-visibility only: ds ops drained, global loads STAY IN FLIGHT
// (__syncthreads would emit s_waitcnt vmcnt(0) and expose HBM/L2 latency)
static __device__ __forceinline__ void bar_lgkm(){
  asm volatile("s_waitcnt lgkmcnt(0)" ::: "memory");
  __builtin_amdgcn_s_barrier();
  asm volatile("" ::: "memory");
}
static __device__ __forceinline__ void bar_plain(){
  asm volatile("" ::: "memory");
  __builtin_amdgcn_s_barrier();
  asm volatile("" ::: "memory");
}

// ---------------- workspace layout (bytes) ----------------
static constexpr size_t OFF_WSE_P  = 0;                                  // 4 MB
static constexpr size_t OFF_WSD_P  = OFF_WSE_P  + (size_t)8192*256*2;    // 4 MB
static constexpr size_t OFF_WIHE_P = OFF_WSD_P  + (size_t)8192*256*2;    // 512 KB
static constexpr size_t OFF_WIHD_P = OFF_WIHE_P + (size_t)256*1024*2;
static constexpr size_t OFF_WHHE_P = OFF_WIHD_P + (size_t)256*1024*2;
static constexpr size_t OFF_WHHD_P = OFF_WHHE_P + (size_t)256*1024*2;
static constexpr size_t OFF_W3E    = OFF_WHHD_P + (size_t)256*1024*2;
static constexpr size_t OFF_W3D    = OFF_W3E   + (size_t)3*1024*4;
static constexpr size_t OFF_W2WO   = OFF_W3D   + (size_t)3*1024*4;
static constexpr size_t OFF_BIASE  = OFF_W2WO  + (size_t)256*3*4;
static constexpr size_t OFF_BIASD  = OFF_BIASE + (size_t)1024*4;
static constexpr size_t OFF_B2WO   = OFF_BIASD + (size_t)1024*4;
static constexpr size_t OFF_PREGE  = OFF_B2WO  + 256;                    // 10.5 MB
static constexpr size_t OFF_PREGD  = OFF_PREGE + (size_t)5120*1024*2;    // 52.4 MB
static constexpr size_t OFF_END    = OFF_PREGD + (size_t)25600*1024*2;

// ================= prep: pack weights (blocks 0-2559) + small folds (2560-2569)
// pack layout [kfg][ctg][lane][8]; element (k,n): k = kfg*32+(l>>4)*8+i, n = ctg*16+(l&15)
__global__ __launch_bounds__(256) void k_prep(
    const float* __restrict__ Wse, const float* __restrict__ Wsd,
    const float* __restrict__ Wih_e, const float* __restrict__ Wih_d,
    const float* __restrict__ Whh_e, const float* __restrict__ Whh_d,
    f16* pWse, f16* pWsd, f16* pWih_e, f16* pWih_d, f16* pWhh_e, f16* pWhh_d,
    const float* __restrict__ Wpe, const float* __restrict__ bpe,
    const float* __restrict__ bih_e, const float* __restrict__ bhh_e,
    const float* __restrict__ Wpd, const float* __restrict__ bpd,
    const float* __restrict__ bih_d, const float* __restrict__ bhh_d,
    const float* __restrict__ W2, const float* __restrict__ b2,
    const float* __restrict__ Wo, const float* __restrict__ bo,
    float* W3e, float* W3d, float* biasE, float* biasD, float* W2Wo, float* b2Wo)
{
  int blk = blockIdx.x;
  if (blk < 2560) {
    const float* W; f16* o; int N, base;
    if      (blk < 1024) { W=Wse;   o=pWse;   N=256;  base=0; }
    else if (blk < 2048) { W=Wsd;   o=pWsd;   N=256;  base=1024; }
    else if (blk < 2176) { W=Wih_e; o=pWih_e; N=1024; base=2048; }  // k rows 0..255 (sal part)
    else if (blk < 2304) { W=Wih_d; o=pWih_d; N=1024; base=2176; }
    else if (blk < 2432) { W=Whh_e; o=pWhh_e; N=1024; base=2304; }
    else                 { W=Whh_d; o=pWhh_d; N=1024; base=2432; }
    int tid = (blk - base)*256 + threadIdx.x;
    int l = tid & 63;
    int nct = N >> 4;
    int ctg = (tid >> 6) % nct;
    int kfg = (tid >> 6) / nct;
    int k0  = kfg*32 + ((l>>4)<<3);
    int col = ctg*16 + (l&15);
    f16x8 v;
#pragma unroll
    for (int i=0;i<8;++i) v[i] = (f16)W[(size_t)(k0+i)*N + col];
    *(f16x8*)(o + (size_t)tid*8) = v;
    return;
  }
  int bid = blk - 2560, tid = threadIdx.x;
  if (bid < 4) {
    int j = bid*256 + tid;
    float s0=0,s1=0,s2=0,sb=0;
    for (int m=0;m<256;++m) {
      float wv = Wih_e[(size_t)(256+m)*1024 + j];
      s0 += Wpe[m]*wv; s1 += Wpe[256+m]*wv; s2 += Wpe[512+m]*wv; sb += bpe[m]*wv;
    }
    W3e[j]=s0; W3e[1024+j]=s1; W3e[2048+j]=s2;
    biasE[j] = bih_e[j] + bhh_e[j] + sb;
  } else if (bid < 8) {
    int j = (bid-4)*256 + tid;
    float s0=0,s1=0,s2=0,sb=0;
    for (int m=0;m<256;++m) {
      float wv = Wih_d[(size_t)(256+m)*1024 + j];
      s0 += Wpd[m]*wv; s1 += Wpd[256+m]*wv; s2 += Wpd[512+m]*wv; sb += bpd[m]*wv;
    }
    W3d[j]=s0; W3d[1024+j]=s1; W3d[2048+j]=s2;
    biasD[j] = bih_d[j] + bhh_d[j] + sb;
  } else if (bid == 8) {
    int c = tid;
    float s0=0,s1=0,s2=0;
    for (int m=0;m<256;++m) {
      float wv = W2[(size_t)c*256+m];
      s0 += wv*Wo[m*3+0]; s1 += wv*Wo[m*3+1]; s2 += wv*Wo[m*3+2];
    }
    W2Wo[c*3+0]=s0; W2Wo[c*3+1]=s1; W2Wo[c*3+2]=s2;
  } else {
    if (tid < 192) {
      int j = tid >> 6, lane = tid & 63;
      float s = 0.f;
      for (int m=lane;m<256;m+=64) s += b2[m]*Wo[m*3+j];
#pragma unroll
      for (int msk=1;msk<64;msk<<=1) s += __shfl_xor(s, msk);
      if (lane==0) b2Wo[j] = s + bo[j];
    }
  }
}

// ======== fused GEMM: preg = (A(f32,K=8192)@Ws + bs) @ Wih + bias [+ pos@W3] =
// Stage-1 pipeline: 2 named A-register sets, prefetch distance 2, raw barriers
// (no vmcnt drain) -> HBM latency amortizes over 2 iterations + block TLP.
__global__ __launch_bounds__(256) void k_gemm_fused(
    const float* __restrict__ A0, const f16* __restrict__ W0,
    const float* __restrict__ bs0, const f16* __restrict__ Wih0,
    const float* __restrict__ bias0, f16* __restrict__ P0, int nb0, int T0,
    const float* __restrict__ pos0, const float* __restrict__ W3f0,
    const float* __restrict__ A1, const f16* __restrict__ W1,
    const float* __restrict__ bs1, const f16* __restrict__ Wih1,
    const float* __restrict__ bias1, f16* __restrict__ P1, int T1)
{
  __shared__ f16 aLDS[2][64*64];   // 16 KB: stage-1 A tiles, 16B-slot ^= row&7
  __shared__ f16 sLDS[64*256];     // 32 KB: sal tile, 16B-slot ^= row&7
  const int tid = threadIdx.x, l = tid & 63, w = tid >> 6;
  const int li = l & 15, hi = l >> 4;
  const int bx = blockIdx.x;
  const float *Ap, *bs, *bias, *posf, *W3f; const f16 *Wp, *Wih; f16* P; int rblk, T;
  if (bx < nb0) { Ap=A0; Wp=W0; bs=bs0; Wih=Wih0; bias=bias0; P=P0; rblk=bx*64;       T=T0; posf=pos0; W3f=W3f0; }
  else          { Ap=A1; Wp=W1; bs=bs1; Wih=Wih1; bias=bias1; P=P1; rblk=(bx-nb0)*64; T=T1; posf=nullptr; W3f=nullptr; }
  const int t = rblk >> 10, b0 = rblk & 1023;

  f32x4 acc[4][4];
#pragma unroll
  for (int a=0;a<4;++a)
#pragma unroll
    for (int b=0;b<4;++b) acc[a][b] = (f32x4){0.f,0.f,0.f,0.f};

  const int srow = tid >> 2, kseg = tid & 3;   // 64 rows x 4 k-segs
  const float* Arow = Ap + ((size_t)(b0 + srow)*T + t)*8192 + kseg*16;

  float4 fA0,fA1,fA2,fA3, fB0,fB1,fB2,fB3;
#define LOADA_A(ti_) { const float* Aq = Arow + (ti_)*64;                      \
    fA0 = *(const float4*)Aq;     fA1 = *(const float4*)(Aq+4);                \
    fA2 = *(const float4*)(Aq+8); fA3 = *(const float4*)(Aq+12); }
#define LOADA_B(ti_) { const float* Aq = Arow + (ti_)*64;                      \
    fB0 = *(const float4*)Aq;     fB1 = *(const float4*)(Aq+4);                \
    fB2 = *(const float4*)(Aq+8); fB3 = *(const float4*)(Aq+12); }
#define MFMA_TILE(buf_, kfg0_)                                                 \
  _Pragma("unroll")                                                            \
  for (int kf = 0; kf < 2; ++kf) {                                             \
    f16x8 afr[4], bfr[4];                                                      \
    _Pragma("unroll")                                                          \
    for (int rt=0; rt<4; ++rt) {                                               \
      int row = rt*16 + li;                                                    \
      afr[rt] = *(f16x8*)&aLDS[buf_][row*64 + (((kf*4) + hi) ^ (row&7))*8];    \
    }                                                                          \
    _Pragma("unroll")                                                          \
    for (int ct=0; ct<4; ++ct) {                                               \
      int ctg = w*4 + ct;                                                      \
      bfr[ct] = *(const f16x8*)(Wp + ((size_t)(((kfg0_)+kf)*16 + ctg)*64 + l)*8); \
    }                                                                          \
    _Pragma("unroll")                                                          \
    for (int rt=0; rt<4; ++rt)                                                 \
      _Pragma("unroll")                                                        \
      for (int ct=0; ct<4; ++ct)                                               \
        acc[rt][ct] = MFMA16(afr[rt], bfr[ct], acc[rt][ct]);                   \
  }
#define STAGE1_STEP(F0,F1,F2,F3, RELOAD, buf_, ti_) {                          \
    f16x8 w0, w1;  /* consume: load was issued 2 iterations ago */             \
    w0[0]=(f16)F0.x; w0[1]=(f16)F0.y; w0[2]=(f16)F0.z; w0[3]=(f16)F0.w;        \
    w0[4]=(f16)F1.x; w0[5]=(f16)F1.y; w0[6]=(f16)F1.z; w0[7]=(f16)F1.w;        \
    w1[0]=(f16)F2.x; w1[1]=(f16)F2.y; w1[2]=(f16)F2.z; w1[3]=(f16)F2.w;        \
    w1[4]=(f16)F3.x; w1[5]=(f16)F3.y; w1[6]=(f16)F3.z; w1[7]=(f16)F3.w;        \
    bar_plain();          /* readers of this buf (iter ti-2) done */           \
    *(f16x8*)&aLDS[buf_][srow*64 + ((kseg*2    ) ^ (srow&7))*8] = w0;          \
    *(f16x8*)&aLDS[buf_][srow*64 + ((kseg*2 + 1) ^ (srow&7))*8] = w1;          \
    { int tn = ((ti_)+2 < 128) ? (ti_)+2 : 127; RELOAD(tn); }                  \
    bar_lgkm();           /* LDS visible; A-loads stay in flight */            \
    MFMA_TILE(buf_, (ti_)*2)                                                   \
  }

  LOADA_A(0); LOADA_B(1);
  for (int ti = 0; ti < 128; ti += 2) {
    STAGE1_STEP(fA0,fA1,fA2,fA3, LOADA_A, 0, ti)
    STAGE1_STEP(fB0,fB1,fB2,fB3, LOADA_B, 1, ti+1)
  }
#undef LOADA_A
#undef LOADA_B
#undef MFMA_TILE
#undef STAGE1_STEP
  // stage-1 epilogue: sal tile (+bs) -> LDS, swizzled row-major [64][256]
  bar_plain();             // last MFMA readers done before sLDS... (aLDS distinct; barrier for uniformity)
#pragma unroll
  for (int ct=0; ct<4; ++ct) {
    int col = (w*4 + ct)*16 + li;
    float bv = bs[col];
    int slot = col >> 3;
#pragma unroll
    for (int rt=0; rt<4; ++rt)
#pragma unroll
      for (int i=0;i<4;++i) {
        int row = rt*16 + hi*4 + i;
        sLDS[row*256 + ((slot ^ (row&7))<<3) + (col&7)] = (f16)(acc[rt][ct][i] + bv);
      }
  }
  // enc job: load per-row pos once (reused across all output cols)
  float pe[4][4][3];
  if (posf) {
#pragma unroll
    for (int rt=0; rt<4; ++rt)
#pragma unroll
      for (int i=0;i<4;++i) {
        int brow = b0 + rt*16 + hi*4 + i;
        const float* pq = posf + ((size_t)brow*T + t)*3;
        pe[rt][i][0]=pq[0]; pe[rt][i][1]=pq[1]; pe[rt][i][2]=pq[2];
      }
  }
  __syncthreads();
  // stage-2: sal(64x256) @ Wih(256x1024), 4 col-chunks of 256
  const int bblk0 = b0 >> 4;
#pragma unroll
  for (int cg=0; cg<4; ++cg) {
    f32x4 a2[4][4];
#pragma unroll
    for (int a=0;a<4;++a)
#pragma unroll
      for (int b=0;b<4;++b) a2[a][b] = (f32x4){0.f,0.f,0.f,0.f};
#pragma unroll
    for (int kfg=0; kfg<8; ++kfg) {
      f16x8 afr[4], bfr[4];
#pragma unroll
      for (int rt=0; rt<4; ++rt) {
        int row = rt*16 + li;
        afr[rt] = *(f16x8*)&sLDS[row*256 + (((kfg*4 + hi) ^ (row&7))<<3)];
      }
#pragma unroll
      for (int ct=0; ct<4; ++ct) {
        int ctg2 = cg*16 + w*4 + ct;
        bfr[ct] = *(const f16x8*)(Wih + ((size_t)(kfg*64 + ctg2)*64 + l)*8);
      }
#pragma unroll
      for (int rt=0; rt<4; ++rt)
#pragma unroll
        for (int ct=0; ct<4; ++ct)
          a2[rt][ct] = MFMA16(afr[rt], bfr[ct], a2[rt][ct]);
    }
    // fragment-order store (identity with k_rnn's C-init loads); bias (+pos@W3) folded
#pragma unroll
    for (int ct=0; ct<4; ++ct) {
      const int ctg2 = cg*16 + w*4 + ct;
      const float bv = bias[ctg2*16 + li];
      float w30=0.f, w31=0.f, w32=0.f;
      if (posf) { int gc = ctg2*16 + li; w30=W3f[gc]; w31=W3f[1024+gc]; w32=W3f[2048+gc]; }
#pragma unroll
      for (int rt=0; rt<4; ++rt) {
        f16x4 o;
#pragma unroll
        for (int i=0;i<4;++i) {
          float v = a2[rt][ct][i] + bv;
          if (posf) v += pe[rt][i][0]*w30 + pe[rt][i][1]*w31 + pe[rt][i][2]*w32;
          o[i] = (f16)v;
        }
        *(f16x4*)(P + ((size_t)((bblk0 + rt)*T + t)*64 + ctg2)*256 + l*4) = o;
      }
    }
  }
}

// ================= fused recurrent kernel: encoder(5) then decoder(25) ======
// 64 blocks x 16 rows, 512 threads (8 waves), __launch_bounds__(512,2) -> 256 VGPR.
// Per-step barrier is lgkmcnt-only: preg prefetch + trailing Whh loads stay
// in flight across step boundaries.
__global__ __launch_bounds__(512, 2) void k_rnn(
    const f16* __restrict__ pregE,   // [b_blk][5][64][64][4]  (pos+bias folded)
    const f16* __restrict__ pregD,   // [b_blk][25][64][64][4] (bias folded)
    const f16* __restrict__ Whh_e_p, const f16* __restrict__ Whh_d_p,
    const float* __restrict__ W3d, const float* __restrict__ dec_pos,
    const float* __restrict__ W2Wo, const float* __restrict__ b2Wo,
    float* __restrict__ out)         // (B,25,3)
{
  __shared__ f16 hBuf[2][16*256];    // swizzled (16B slot ^= row&7)
  __shared__ float W3s[3*1024];
  __shared__ float dpart[25][16][3]; // per-step delta accumulators
  const int tid = threadIdx.x, l = tid & 63, w = tid >> 6;
  const int li = l & 15, hi = l >> 4;
  const int bblk = blockIdx.x, rb = bblk*16;

  for (int i=tid;i<3072;i+=512) W3s[i]=W3d[i];
  for (int i=tid; i<25*16*3; i+=512) ((float*)dpart)[i] = 0.f;

  float c_st[2][4];
#pragma unroll
  for (int j=0;j<2;++j)
#pragma unroll
    for (int i=0;i<4;++i) c_st[j][i]=0.f;

#define WLOAD(dst, WP, kfb)                                                   \
  _Pragma("unroll") for (int kk=0;kk<2;++kk)                                  \
  _Pragma("unroll") for (int q=0;q<4;++q)                                     \
  _Pragma("unroll") for (int j=0;j<2;++j)                                     \
    dst[kk][q][j] = *(const f16x8*)((WP) + ((size_t)(((kfb)+kk)*64 + q*16 + w*2 + j)*64 + l)*8);

#define AH2(dst, hB, kfb)                                                     \
  _Pragma("unroll") for (int kk=0;kk<2;++kk)                                  \
    dst[kk] = *(f16x8*)&(hB)[li*256 + (((((kfb)+kk)*4)+hi) ^ (li&7))*8];

#define MFMA_B2(WSET, AHS)                                                    \
  _Pragma("unroll") for (int kk=0;kk<2;++kk)                                  \
  _Pragma("unroll") for (int q=0;q<4;++q)                                     \
  _Pragma("unroll") for (int j=0;j<2;++j)                                     \
    acc[q][j] = MFMA16(AHS[kk], WSET[kk][q][j], acc[q][j]);

#define MFMA_STEP(hB, WP) {                                                   \
  f16x8 wa[2][4][2], wb[2][4][2];                                             \
  f16x8 aha[2], ahb[2];                                                       \
  WLOAD(wa, WP, 0) WLOAD(wb, WP, 2)                                           \
  AH2(aha, hB, 0) AH2(ahb, hB, 2)                                             \
  MFMA_B2(wa, aha)                                                            \
  WLOAD(wa, WP, 4) AH2(aha, hB, 4)                                            \
  MFMA_B2(wb, ahb)                                                            \
  WLOAD(wb, WP, 6) AH2(ahb, hB, 6)                                            \
  MFMA_B2(wa, aha)                                                            \
  MFMA_B2(wb, ahb) }

#define LOADPV(dst, base, t_)                                                 \
  _Pragma("unroll")                                                           \
  for (int q=0;q<4;++q)                                                       \
    _Pragma("unroll")                                                         \
    for (int j=0;j<2;++j)                                                     \
      dst[q][j] = *(const f16x4*)((base) + ((size_t)(t_)*16384 + (size_t)(q*16 + w*2 + j)*256 + l*4));

#define COPYPV()                                                              \
  _Pragma("unroll")                                                           \
  for (int q=0;q<4;++q)                                                       \
    _Pragma("unroll")                                                         \
    for (int j=0;j<2;++j) pvA[q][j] = pvB[q][j];

#define ACCINIT()                                                             \
  f32x4 acc[4][2];                                                            \
  _Pragma("unroll")                                                           \
  for (int q=0;q<4;++q)                                                       \
    _Pragma("unroll")                                                         \
    for (int j=0;j<2;++j)                                                     \
      acc[q][j] = (f32x4){(float)pvA[q][j][0],(float)pvA[q][j][1],(float)pvA[q][j][2],(float)pvA[q][j][3]};

  // ---------------- encoder (gate = acc only: bias+pos pre-folded) ---------
  const f16* prE = pregE + (size_t)bblk*5*16384;
  f16x4 pvA[4][2], pvB[4][2];
  LOADPV(pvA, prE, 0)
  __syncthreads();                 // W3s + dpart init visible (once)
  for (int t=0;t<5;++t) {
    if (t+1 < 5) LOADPV(pvB, prE, t+1)
    ACCINIT()
    if (t > 0) MFMA_STEP(hBuf[(t-1)&1], Whh_e_p)
#pragma unroll
    for (int i=0;i<4;++i) {
      int r = hi*4 + i;
#pragma unroll
      for (int j=0;j<2;++j) {
        int hc = w*32 + j*16 + li;
        float cn = sigm(acc[1][j][i])*c_st[j][i] + sigm(acc[0][j][i])*tanh_(acc[2][j][i]);
        c_st[j][i] = cn;
        float h = sigm(acc[3][j][i])*tanh_(cn);
        hBuf[t&1][r*256 + (((hc>>3) ^ (r&7))<<3) + (hc&7)] = (f16)h;
      }
    }
    if (t+1 < 5) { COPYPV() }
    bar_lgkm();                    // h[t] visible; pvB loads stay in flight
  }

  // ---------------- decoder constants ----------------
  float w2r[2][3];
#pragma unroll
  for (int j=0;j<2;++j) {
    int hc = w*32 + j*16 + li;
    w2r[j][0]=W2Wo[hc*3+0]; w2r[j][1]=W2Wo[hc*3+1]; w2r[j][2]=W2Wo[hc*3+2];
  }
  const float b2w0 = b2Wo[0], b2w1 = b2Wo[1], b2w2 = b2Wo[2];
  float pp[4][3];
#pragma unroll
  for (int i=0;i<4;++i) {
    int r = rb + hi*4 + i;
    pp[i][0]=dec_pos[r*3+0]; pp[i][1]=dec_pos[r*3+1]; pp[i][2]=dec_pos[r*3+2];
  }

  // ---------------- decoder (1 lgkm-barrier/step) ----------------
  // enc t=4 wrote hBuf[0]; dec step t reads hBuf[t&1], writes hBuf[(t+1)&1].
  const f16* prD = pregD + (size_t)bblk*25*16384;
  LOADPV(pvA, prD, 0)
  for (int t=0;t<25;++t) {
    if (t+1 < 25) LOADPV(pvB, prD, t+1)
    ACCINIT()
    MFMA_STEP(hBuf[t&1], Whh_d_p)
    float dpar[4][3];
#pragma unroll
    for (int i=0;i<4;++i){ dpar[i][0]=0.f; dpar[i][1]=0.f; dpar[i][2]=0.f; }
#pragma unroll
    for (int i=0;i<4;++i) {
      int r = hi*4 + i;
#pragma unroll
      for (int j=0;j<2;++j) {
        int hc = w*32 + j*16 + li;
        float gq[4];
#pragma unroll
        for (int q=0;q<4;++q) {
          int gc = q*256 + hc;
          gq[q] = acc[q][j][i] + pp[i][0]*W3s[gc] + pp[i][1]*W3s[1024+gc] + pp[i][2]*W3s[2048+gc];
        }
        float cn = sigm(gq[1])*c_st[j][i] + sigm(gq[0])*tanh_(gq[2]);
        c_st[j][i] = cn;
        float h = sigm(gq[3])*tanh_(cn);
        hBuf[(t+1)&1][r*256 + (((hc>>3) ^ (r&7))<<3) + (hc&7)] = (f16)h;
        dpar[i][0] += h*w2r[j][0];
        dpar[i][1] += h*w2r[j][1];
        dpar[i][2] += h*w2r[j][2];
      }
    }
#pragma unroll
    for (int m=1;m<16;m<<=1)
#pragma unroll
      for (int i=0;i<4;++i) {
        dpar[i][0] += __shfl_xor(dpar[i][0], m);
        dpar[i][1] += __shfl_xor(dpar[i][1], m);
        dpar[i][2] += __shfl_xor(dpar[i][2], m);
      }
    if (li==0) {
#pragma unroll
      for (int i=0;i<4;++i) {
        int r = hi*4 + i;
        atomicAdd(&dpart[t][r][0], dpar[i][0]);
        atomicAdd(&dpart[t][r][1], dpar[i][1]);
        atomicAdd(&dpart[t][r][2], dpar[i][2]);
      }
    }
    if (t+1 < 25) { COPYPV() }
    bar_lgkm();                    // h[t+1] + dpart[t] visible; pvB stays in flight
    // pos update (redundant per 16-lane group, identical FP ops -> identical)
#pragma unroll
    for (int i=0;i<4;++i) {
      int r = hi*4 + i;
      float p0 = pp[i][0] + b2w0 + dpart[t][r][0];
      float p1 = pp[i][1] + b2w1 + dpart[t][r][1];
      float p2 = pp[i][2] + b2w2 + dpart[t][r][2];
      float inv = 1.0f/sqrtf(p0*p0+p1*p1+p2*p2);
      pp[i][0]=p0*inv; pp[i][1]=p1*inv; pp[i][2]=p2*inv;
      if (w==0 && li==0) {
        float* o = out + (size_t)(rb+r)*75 + t*3;
        o[0]=pp[i][0]; o[1]=pp[i][1]; o[2]=pp[i][2];
      }
    }
  }
#undef WLOAD
#undef AH2
#undef MFMA_B2
#undef MFMA_STEP
#undef LOADPV
#undef COPYPV
#undef ACCINIT
}

// ================= launch =================
extern "C" void kernel_launch(void* const* d_in, const int* in_sizes, int n_in,
                              void* d_out, int out_size, void* d_ws, size_t ws_size,
                              hipStream_t stream)
{
  const float* enc_pos = (const float*)d_in[0];
  const float* enc_sal = (const float*)d_in[1];
  const float* dec_pos = (const float*)d_in[2];
  const float* dec_sal = (const float*)d_in[3];
  const float* Wpe  = (const float*)d_in[4];
  const float* bpe  = (const float*)d_in[5];
  const float* Wse  = (const float*)d_in[6];
  const float* bse  = (const float*)d_in[7];
  const float* Wih_e= (const float*)d_in[8];
  const float* Whh_e= (const float*)d_in[9];
  const float* bih_e= (const float*)d_in[10];
  const float* bhh_e= (const float*)d_in[11];
  const float* Wih_d= (const float*)d_in[12];
  const float* Whh_d= (const float*)d_in[13];
  const float* bih_d= (const float*)d_in[14];
  const float* bhh_d= (const float*)d_in[15];
  const float* Wpd  = (const float*)d_in[16];
  const float* bpd  = (const float*)d_in[17];
  const float* Wsd  = (const float*)d_in[18];
  const float* bsd  = (const float*)d_in[19];
  const float* W2   = (const float*)d_in[20];
  const float* b2   = (const float*)d_in[21];
  const float* Wo   = (const float*)d_in[22];
  const float* bo   = (const float*)d_in[23];

  char* ws = (char*)d_ws;
  f16* pWse   = (f16*)(ws + OFF_WSE_P);
  f16* pWsd   = (f16*)(ws + OFF_WSD_P);
  f16* pWih_e = (f16*)(ws + OFF_WIHE_P);
  f16* pWih_d = (f16*)(ws + OFF_WIHD_P);
  f16* pWhh_e = (f16*)(ws + OFF_WHHE_P);
  f16* pWhh_d = (f16*)(ws + OFF_WHHD_P);
  float* W3e  = (float*)(ws + OFF_W3E);
  float* W3d  = (float*)(ws + OFF_W3D);
  float* W2WoP= (float*)(ws + OFF_W2WO);
  float* biasE= (float*)(ws + OFF_BIASE);
  float* biasD= (float*)(ws + OFF_BIASD);
  float* b2WoP= (float*)(ws + OFF_B2WO);
  f16* pregE  = (f16*)(ws + OFF_PREGE);
  f16* pregD  = (f16*)(ws + OFF_PREGD);
  float* out  = (float*)d_out;

  hipLaunchKernelGGL(k_prep, dim3(2570), dim3(256), 0, stream,
                     Wse, Wsd, Wih_e, Wih_d, Whh_e, Whh_d,
                     pWse, pWsd, pWih_e, pWih_d, pWhh_e, pWhh_d,
                     Wpe, bpe, bih_e, bhh_e, Wpd, bpd, bih_d, bhh_d,
                     W2, b2, Wo, bo,
                     W3e, W3d, biasE, biasD, W2WoP, b2WoP);
  // fused sal-projection + pre-gate GEMM: enc tiles [0,80) (pos folded), dec [80,480)
  hipLaunchKernelGGL(k_gemm_fused, dim3(480), dim3(256), 0, stream,
                     enc_sal, pWse, bse, pWih_e, biasE, pregE, 80, 5, enc_pos, W3e,
                     dec_sal, pWsd, bsd, pWih_d, biasD, pregD, 25);
  // fused encoder+decoder recurrence
  hipLaunchKernelGGL(k_rnn, dim3(64), dim3(512), 0, stream,
                     pregE, pregD, pWhh_e, pWhh_d,
                     W3d, dec_pos, W2WoP, b2WoP, out);
}

// Round 10
// 682.632 us; speedup vs baseline: 1.3313x; 1.1855x over previous
//
#include <hip/hip_runtime.h>

typedef _Float16 f16;
typedef _Float16 f16x4 __attribute__((ext_vector_type(4)));
typedef _Float16 f16x8 __attribute__((ext_vector_type(8)));
typedef float    f32x4 __attribute__((ext_vector_type(4)));
typedef unsigned int u32;

#define MFMA16(a,b,c) __builtin_amdgcn_mfma_f32_16x16x32_f16((a),(b),(c),0,0,0)

typedef __attribute__((address_space(1))) const u32 gu32;
typedef __attribute__((address_space(3))) u32 lu32;

static __device__ __forceinline__ float frcp(float x){ float r; asm("v_rcp_f32 %0, %1" : "=v"(r) : "v"(x)); return r; }
static __device__ __forceinline__ float sigm(float x){ return frcp(1.0f + __expf(-x)); }
static __device__ __forceinline__ float tanh_(float x){ return 1.0f - 2.0f*frcp(1.0f + __expf(2.0f*x)); }

// barrier with LDS-visibility only: ds ops drained, global/gload_lds stay in flight
static __device__ __forceinline__ void bar_lgkm(){
  asm volatile("s_waitcnt lgkmcnt(0)" ::: "memory");
  __builtin_amdgcn_s_barrier();
  asm volatile("" ::: "memory");
}
static __device__ __forceinline__ void bar_plain(){
  asm volatile("" ::: "memory");
  __builtin_amdgcn_s_barrier();
  asm volatile("" ::: "memory");
}

// ---------------- workspace layout (bytes) ----------------
static constexpr size_t OFF_WSE_P  = 0;                                  // 4 MB
static constexpr size_t OFF_WSD_P  = OFF_WSE_P  + (size_t)8192*256*2;    // 4 MB
static constexpr size_t OFF_WIHE_P = OFF_WSD_P  + (size_t)8192*256*2;    // 512 KB
static constexpr size_t OFF_WIHD_P = OFF_WIHE_P + (size_t)256*1024*2;
static constexpr size_t OFF_WHHE_P = OFF_WIHD_P + (size_t)256*1024*2;
static constexpr size_t OFF_WHHD_P = OFF_WHHE_P + (size_t)256*1024*2;
static constexpr size_t OFF_W3E    = OFF_WHHD_P + (size_t)256*1024*2;
static constexpr size_t OFF_W3D    = OFF_W3E   + (size_t)3*1024*4;
static constexpr size_t OFF_W2WO   = OFF_W3D   + (size_t)3*1024*4;
static constexpr size_t OFF_BIASE  = OFF_W2WO  + (size_t)256*3*4;
static constexpr size_t OFF_BIASD  = OFF_BIASE + (size_t)1024*4;
static constexpr size_t OFF_B2WO   = OFF_BIASD + (size_t)1024*4;
static constexpr size_t OFF_PREGE  = OFF_B2WO  + 256;                    // 10.5 MB
static constexpr size_t OFF_PREGD  = OFF_PREGE + (size_t)5120*1024*2;    // 52.4 MB
static constexpr size_t OFF_END    = OFF_PREGD + (size_t)25600*1024*2;

// ================= prep: pack weights (blocks 0-2559) + small folds (2560-2569)
// pack layout [kfg][ctg][lane][8]; element (k,n): k = kfg*32+(l>>4)*8+i, n = ctg*16+(l&15)
__global__ __launch_bounds__(256) void k_prep(
    const float* __restrict__ Wse, const float* __restrict__ Wsd,
    const float* __restrict__ Wih_e, const float* __restrict__ Wih_d,
    const float* __restrict__ Whh_e, const float* __restrict__ Whh_d,
    f16* pWse, f16* pWsd, f16* pWih_e, f16* pWih_d, f16* pWhh_e, f16* pWhh_d,
    const float* __restrict__ Wpe, const float* __restrict__ bpe,
    const float* __restrict__ bih_e, const float* __restrict__ bhh_e,
    const float* __restrict__ Wpd, const float* __restrict__ bpd,
    const float* __restrict__ bih_d, const float* __restrict__ bhh_d,
    const float* __restrict__ W2, const float* __restrict__ b2,
    const float* __restrict__ Wo, const float* __restrict__ bo,
    float* W3e, float* W3d, float* biasE, float* biasD, float* W2Wo, float* b2Wo)
{
  int blk = blockIdx.x;
  if (blk < 2560) {
    const float* W; f16* o; int N, base;
    if      (blk < 1024) { W=Wse;   o=pWse;   N=256;  base=0; }
    else if (blk < 2048) { W=Wsd;   o=pWsd;   N=256;  base=1024; }
    else if (blk < 2176) { W=Wih_e; o=pWih_e; N=1024; base=2048; }  // k rows 0..255 (sal part)
    else if (blk < 2304) { W=Wih_d; o=pWih_d; N=1024; base=2176; }
    else if (blk < 2432) { W=Whh_e; o=pWhh_e; N=1024; base=2304; }
    else                 { W=Whh_d; o=pWhh_d; N=1024; base=2432; }
    int tid = (blk - base)*256 + threadIdx.x;
    int l = tid & 63;
    int nct = N >> 4;
    int ctg = (tid >> 6) % nct;
    int kfg = (tid >> 6) / nct;
    int k0  = kfg*32 + ((l>>4)<<3);
    int col = ctg*16 + (l&15);
    f16x8 v;
#pragma unroll
    for (int i=0;i<8;++i) v[i] = (f16)W[(size_t)(k0+i)*N + col];
    *(f16x8*)(o + (size_t)tid*8) = v;
    return;
  }
  int bid = blk - 2560, tid = threadIdx.x;
  if (bid < 4) {
    int j = bid*256 + tid;
    float s0=0,s1=0,s2=0,sb=0;
    for (int m=0;m<256;++m) {
      float wv = Wih_e[(size_t)(256+m)*1024 + j];
      s0 += Wpe[m]*wv; s1 += Wpe[256+m]*wv; s2 += Wpe[512+m]*wv; sb += bpe[m]*wv;
    }
    W3e[j]=s0; W3e[1024+j]=s1; W3e[2048+j]=s2;
    biasE[j] = bih_e[j] + bhh_e[j] + sb;
  } else if (bid < 8) {
    int j = (bid-4)*256 + tid;
    float s0=0,s1=0,s2=0,sb=0;
    for (int m=0;m<256;++m) {
      float wv = Wih_d[(size_t)(256+m)*1024 + j];
      s0 += Wpd[m]*wv; s1 += Wpd[256+m]*wv; s2 += Wpd[512+m]*wv; sb += bpd[m]*wv;
    }
    W3d[j]=s0; W3d[1024+j]=s1; W3d[2048+j]=s2;
    biasD[j] = bih_d[j] + bhh_d[j] + sb;
  } else if (bid == 8) {
    int c = tid;
    float s0=0,s1=0,s2=0;
    for (int m=0;m<256;++m) {
      float wv = W2[(size_t)c*256+m];
      s0 += wv*Wo[m*3+0]; s1 += wv*Wo[m*3+1]; s2 += wv*Wo[m*3+2];
    }
    W2Wo[c*3+0]=s0; W2Wo[c*3+1]=s1; W2Wo[c*3+2]=s2;
  } else {
    if (tid < 192) {
      int j = tid >> 6, lane = tid & 63;
      float s = 0.f;
      for (int m=lane;m<256;m+=64) s += b2[m]*Wo[m*3+j];
#pragma unroll
      for (int msk=1;msk<64;msk<<=1) s += __shfl_xor(s, msk);
      if (lane==0) b2Wo[j] = s + bo[j];
    }
  }
}

// ======== fused GEMM: preg = (A(f32,K=8192)@Ws + bs) @ Wih + bias [+ pos@W3] =
__global__ __launch_bounds__(256) void k_gemm_fused(
    const float* __restrict__ A0, const f16* __restrict__ W0,
    const float* __restrict__ bs0, const f16* __restrict__ Wih0,
    const float* __restrict__ bias0, f16* __restrict__ P0, int nb0, int T0,
    const float* __restrict__ pos0, const float* __restrict__ W3f0,
    const float* __restrict__ A1, const f16* __restrict__ W1,
    const float* __restrict__ bs1, const f16* __restrict__ Wih1,
    const float* __restrict__ bias1, f16* __restrict__ P1, int T1)
{
  __shared__ f16 aLDS[2][64*64];   // 16 KB: stage-1 A tiles, 16B-slot ^= row&7
  __shared__ f16 sLDS[64*256];     // 32 KB: sal tile, 16B-slot ^= row&7
  const int tid = threadIdx.x, l = tid & 63, w = tid >> 6;
  const int li = l & 15, hi = l >> 4;
  const int bx = blockIdx.x;
  const float *Ap, *bs, *bias, *posf, *W3f; const f16 *Wp, *Wih; f16* P; int rblk, T;
  if (bx < nb0) { Ap=A0; Wp=W0; bs=bs0; Wih=Wih0; bias=bias0; P=P0; rblk=bx*64;       T=T0; posf=pos0; W3f=W3f0; }
  else          { Ap=A1; Wp=W1; bs=bs1; Wih=Wih1; bias=bias1; P=P1; rblk=(bx-nb0)*64; T=T1; posf=nullptr; W3f=nullptr; }
  const int t = rblk >> 10, b0 = rblk & 1023;

  f32x4 acc[4][4];
#pragma unroll
  for (int a=0;a<4;++a)
#pragma unroll
    for (int b=0;b<4;++b) acc[a][b] = (f32x4){0.f,0.f,0.f,0.f};

  const int srow = tid >> 2, kseg = tid & 3;   // 64 rows x 4 k-segs
  const float* Arow = Ap + ((size_t)(b0 + srow)*T + t)*8192 + kseg*16;

  float4 fA0,fA1,fA2,fA3, fB0,fB1,fB2,fB3;
#define LOADA_A(ti_) { const float* Aq = Arow + (ti_)*64;                      \
    fA0 = *(const float4*)Aq;     fA1 = *(const float4*)(Aq+4);                \
    fA2 = *(const float4*)(Aq+8); fA3 = *(const float4*)(Aq+12); }
#define LOADA_B(ti_) { const float* Aq = Arow + (ti_)*64;                      \
    fB0 = *(const float4*)Aq;     fB1 = *(const float4*)(Aq+4);                \
    fB2 = *(const float4*)(Aq+8); fB3 = *(const float4*)(Aq+12); }
#define MFMA_TILE(buf_, kfg0_)                                                 \
  _Pragma("unroll")                                                            \
  for (int kf = 0; kf < 2; ++kf) {                                             \
    f16x8 afr[4], bfr[4];                                                      \
    _Pragma("unroll")                                                          \
    for (int rt=0; rt<4; ++rt) {                                               \
      int row = rt*16 + li;                                                    \
      afr[rt] = *(f16x8*)&aLDS[buf_][row*64 + (((kf*4) + hi) ^ (row&7))*8];    \
    }                                                                          \
    _Pragma("unroll")                                                          \
    for (int ct=0; ct<4; ++ct) {                                               \
      int ctg = w*4 + ct;                                                      \
      bfr[ct] = *(const f16x8*)(Wp + ((size_t)(((kfg0_)+kf)*16 + ctg)*64 + l)*8); \
    }                                                                          \
    _Pragma("unroll")                                                          \
    for (int rt=0; rt<4; ++rt)                                                 \
      _Pragma("unroll")                                                        \
      for (int ct=0; ct<4; ++ct)                                               \
        acc[rt][ct] = MFMA16(afr[rt], bfr[ct], acc[rt][ct]);                   \
  }
#define STAGE1_STEP(F0,F1,F2,F3, RELOAD, buf_, ti_) {                          \
    f16x8 w0, w1;  /* consume: load was issued 2 iterations ago */             \
    w0[0]=(f16)F0.x; w0[1]=(f16)F0.y; w0[2]=(f16)F0.z; w0[3]=(f16)F0.w;        \
    w0[4]=(f16)F1.x; w0[5]=(f16)F1.y; w0[6]=(f16)F1.z; w0[7]=(f16)F1.w;        \
    w1[0]=(f16)F2.x; w1[1]=(f16)F2.y; w1[2]=(f16)F2.z; w1[3]=(f16)F2.w;        \
    w1[4]=(f16)F3.x; w1[5]=(f16)F3.y; w1[6]=(f16)F3.z; w1[7]=(f16)F3.w;        \
    bar_plain();          /* readers of this buf (iter ti-2) done */           \
    *(f16x8*)&aLDS[buf_][srow*64 + ((kseg*2    ) ^ (srow&7))*8] = w0;          \
    *(f16x8*)&aLDS[buf_][srow*64 + ((kseg*2 + 1) ^ (srow&7))*8] = w1;          \
    { int tn = ((ti_)+2 < 128) ? (ti_)+2 : 127; RELOAD(tn); }                  \
    bar_lgkm();           /* LDS visible; A-loads stay in flight */            \
    MFMA_TILE(buf_, (ti_)*2)                                                   \
  }

  LOADA_A(0); LOADA_B(1);
  for (int ti = 0; ti < 128; ti += 2) {
    STAGE1_STEP(fA0,fA1,fA2,fA3, LOADA_A, 0, ti)
    STAGE1_STEP(fB0,fB1,fB2,fB3, LOADA_B, 1, ti+1)
  }
#undef LOADA_A
#undef LOADA_B
#undef MFMA_TILE
#undef STAGE1_STEP
  // stage-1 epilogue: sal tile (+bs) -> LDS, swizzled row-major [64][256]
  bar_plain();
#pragma unroll
  for (int ct=0; ct<4; ++ct) {
    int col = (w*4 + ct)*16 + li;
    float bv = bs[col];
    int slot = col >> 3;
#pragma unroll
    for (int rt=0; rt<4; ++rt)
#pragma unroll
      for (int i=0;i<4;++i) {
        int row = rt*16 + hi*4 + i;
        sLDS[row*256 + ((slot ^ (row&7))<<3) + (col&7)] = (f16)(acc[rt][ct][i] + bv);
      }
  }
  // enc job: load per-row pos once (reused across all output cols)
  float pe[4][4][3];
  if (posf) {
#pragma unroll
    for (int rt=0; rt<4; ++rt)
#pragma unroll
      for (int i=0;i<4;++i) {
        int brow = b0 + rt*16 + hi*4 + i;
        const float* pq = posf + ((size_t)brow*T + t)*3;
        pe[rt][i][0]=pq[0]; pe[rt][i][1]=pq[1]; pe[rt][i][2]=pq[2];
      }
  }
  __syncthreads();
  // stage-2: sal(64x256) @ Wih(256x1024), 4 col-chunks of 256
  const int bblk0 = b0 >> 4;
#pragma unroll
  for (int cg=0; cg<4; ++cg) {
    f32x4 a2[4][4];
#pragma unroll
    for (int a=0;a<4;++a)
#pragma unroll
      for (int b=0;b<4;++b) a2[a][b] = (f32x4){0.f,0.f,0.f,0.f};
#pragma unroll
    for (int kfg=0; kfg<8; ++kfg) {
      f16x8 afr[4], bfr[4];
#pragma unroll
      for (int rt=0; rt<4; ++rt) {
        int row = rt*16 + li;
        afr[rt] = *(f16x8*)&sLDS[row*256 + (((kfg*4 + hi) ^ (row&7))<<3)];
      }
#pragma unroll
      for (int ct=0; ct<4; ++ct) {
        int ctg2 = cg*16 + w*4 + ct;
        bfr[ct] = *(const f16x8*)(Wih + ((size_t)(kfg*64 + ctg2)*64 + l)*8);
      }
#pragma unroll
      for (int rt=0; rt<4; ++rt)
#pragma unroll
        for (int ct=0; ct<4; ++ct)
          a2[rt][ct] = MFMA16(afr[rt], bfr[ct], a2[rt][ct]);
    }
    // fragment-order store (identity with k_rnn's C-init loads); bias (+pos@W3) folded
#pragma unroll
    for (int ct=0; ct<4; ++ct) {
      const int ctg2 = cg*16 + w*4 + ct;
      const float bv = bias[ctg2*16 + li];
      float w30=0.f, w31=0.f, w32=0.f;
      if (posf) { int gc = ctg2*16 + li; w30=W3f[gc]; w31=W3f[1024+gc]; w32=W3f[2048+gc]; }
#pragma unroll
      for (int rt=0; rt<4; ++rt) {
        f16x4 o;
#pragma unroll
        for (int i=0;i<4;++i) {
          float v = a2[rt][ct][i] + bv;
          if (posf) v += pe[rt][i][0]*w30 + pe[rt][i][1]*w31 + pe[rt][i][2]*w32;
          o[i] = (f16)v;
        }
        *(f16x4*)(P + ((size_t)((bblk0 + rt)*T + t)*64 + ctg2)*256 + l*4) = o;
      }
    }
  }
}

// ================= fused recurrent kernel: encoder(5) then decoder(25) ======
// 64 blocks x 16 rows, 512 threads (8 waves), launch_bounds(512,1) -> 256 VGPR.
// wave w owns h-cols [w*32,+32): ctg = q*16 + w*2 + j (gate quads lane-local).
// Whh kf0-1 held in regs; kf2-7 streamed through WAVE-PRIVATE LDS slots via
// global_load_lds with COUNTED vmcnt (no extra barriers). Next step's first
// two stages issue before the step-end bar_lgkm -> fly through the barrier.
__global__ __launch_bounds__(512, 1) void k_rnn(
    const f16* __restrict__ pregE,   // [b_blk][5][64][64][4]  (pos+bias folded)
    const f16* __restrict__ pregD,   // [b_blk][25][64][64][4] (bias folded)
    const f16* __restrict__ Whh_e_p, const f16* __restrict__ Whh_d_p,
    const float* __restrict__ W3d, const float* __restrict__ dec_pos,
    const float* __restrict__ W2Wo, const float* __restrict__ b2Wo,
    float* __restrict__ out)         // (B,25,3)
{
  __shared__ f16 wLDS[8][2][8][512]; // 128 KB: [wave][slot][frag][lane*8]
  __shared__ f16 hBuf[2][16*256];    // 16 KB, swizzled (16B slot ^= row&7)
  __shared__ float dpart[25][16][3]; // 4.7 KB per-step delta accumulators
  const int tid = threadIdx.x, l = tid & 63, w = tid >> 6;
  const int li = l & 15, hi = l >> 4;
  const int bblk = blockIdx.x, rb = bblk*16;

  for (int i=tid; i<25*16*3; i+=512) ((float*)dpart)[i] = 0.f;

  float c_st[2][4];
#pragma unroll
  for (int j=0;j<2;++j)
#pragma unroll
    for (int i=0;i<4;++i) c_st[j][i]=0.f;

  // ---- macros ----
#define VMW(n) { asm volatile("s_waitcnt vmcnt(" #n ")" ::: "memory");        \
                 __builtin_amdgcn_sched_barrier(0); }
#define STAGE(WP, kf, s)                                                      \
  _Pragma("unroll") for (int f=0; f<8; ++f) {                                 \
    int ctg = (f>>1)*16 + w*2 + (f&1);                                        \
    const f16* g = (WP) + ((size_t)((kf)*64 + ctg)*64 + l)*8;                 \
    __builtin_amdgcn_global_load_lds((gu32*)g, (lu32*)&wLDS[w][s][f][0], 16, 0, 0); \
  }
#define MFMA_SLOT(s, kf, hB) {                                                \
  f16x8 ah = *(f16x8*)&(hB)[li*256 + ((((kf)*4)+hi) ^ (li&7))*8];             \
  _Pragma("unroll") for (int f=0; f<8; ++f) {                                 \
    f16x8 b = *(f16x8*)&wLDS[w][s][f][l*8];                                   \
    acc[f>>1][f&1] = MFMA16(ah, b, acc[f>>1][f&1]); } }
#define LOAD_HELD(WP)                                                         \
  _Pragma("unroll") for (int kk=0;kk<2;++kk)                                  \
    _Pragma("unroll") for (int q=0;q<4;++q)                                   \
      _Pragma("unroll") for (int j=0;j<2;++j)                                 \
        bhh[kk][q][j] = *(const f16x8*)((WP) + ((size_t)(kk*64 + q*16+w*2+j)*64 + l)*8);
#define MFMA_HELD(hB)                                                         \
  _Pragma("unroll") for (int kk=0;kk<2;++kk) {                                \
    f16x8 ah = *(f16x8*)&(hB)[li*256 + (((kk*4)+hi) ^ (li&7))*8];             \
    _Pragma("unroll") for (int q=0;q<4;++q)                                   \
      _Pragma("unroll") for (int j=0;j<2;++j)                                 \
        acc[q][j] = MFMA16(ah, bhh[kk][q][j], acc[q][j]); }
// full streamed MFMA phase: held kf0-1 + slots kf2-7 with counted vmcnt.
// entering queue: [S2(8), S3(8)]; pvB(8) issued after them this step.
#define KFSTREAM(hB, WP)                                                      \
  MFMA_HELD(hB)                                                               \
  VMW(16) MFMA_SLOT(0, 2, hB) STAGE(WP, 4, 0)                                 \
  VMW(16) MFMA_SLOT(1, 3, hB) STAGE(WP, 5, 1)                                 \
  VMW(8)  MFMA_SLOT(0, 4, hB) STAGE(WP, 6, 0)                                 \
  VMW(8)  MFMA_SLOT(1, 5, hB) STAGE(WP, 7, 1)                                 \
  VMW(8)  MFMA_SLOT(0, 6, hB)                                                 \
  VMW(0)  MFMA_SLOT(1, 7, hB)
#define LOADPV(dst, base, t_)                                                 \
  _Pragma("unroll")                                                           \
  for (int q=0;q<4;++q)                                                       \
    _Pragma("unroll")                                                         \
    for (int j=0;j<2;++j)                                                     \
      dst[q][j] = *(const f16x4*)((base) + ((size_t)(t_)*16384 + (size_t)(q*16 + w*2 + j)*256 + l*4));
#define COPYPV()                                                              \
  _Pragma("unroll")                                                           \
  for (int q=0;q<4;++q)                                                       \
    _Pragma("unroll")                                                         \
    for (int j=0;j<2;++j) pvA[q][j] = pvB[q][j];
#define ACCINIT()                                                             \
  f32x4 acc[4][2];                                                            \
  _Pragma("unroll")                                                           \
  for (int q=0;q<4;++q)                                                       \
    _Pragma("unroll")                                                         \
    for (int j=0;j<2;++j)                                                     \
      acc[q][j] = (f32x4){(float)pvA[q][j][0],(float)pvA[q][j][1],(float)pvA[q][j][2],(float)pvA[q][j][3]};

  f16x8 bhh[2][4][2];
  LOAD_HELD(Whh_e_p)

  // ---------------- encoder (gate = acc only: bias+pos pre-folded) ---------
  const f16* prE = pregE + (size_t)bblk*5*16384;
  f16x4 pvA[4][2], pvB[4][2];
  LOADPV(pvA, prE, 0)
  __syncthreads();                 // dpart zero-init visible (once)
  for (int t=0;t<5;++t) {
    if (t+1 < 5) LOADPV(pvB, prE, t+1)
    ACCINIT()
    if (t > 0) { KFSTREAM(hBuf[(t-1)&1], Whh_e_p) }
    if (t+1 < 5) { STAGE(Whh_e_p, 2, 0) STAGE(Whh_e_p, 3, 1) }  // for step t+1
#pragma unroll
    for (int i=0;i<4;++i) {
      int r = hi*4 + i;
#pragma unroll
      for (int j=0;j<2;++j) {
        int hc = w*32 + j*16 + li;
        float cn = sigm(acc[1][j][i])*c_st[j][i] + sigm(acc[0][j][i])*tanh_(acc[2][j][i]);
        c_st[j][i] = cn;
        float h = sigm(acc[3][j][i])*tanh_(cn);
        hBuf[t&1][r*256 + (((hc>>3) ^ (r&7))<<3) + (hc&7)] = (f16)h;
      }
    }
    if (t+1 < 5) { COPYPV() }
    bar_lgkm();                    // h[t] visible; stages + pvB stay in flight
  }

  // ---------------- decoder constants ----------------
  LOAD_HELD(Whh_d_p)
  STAGE(Whh_d_p, 2, 0) STAGE(Whh_d_p, 3, 1)   // for dec t=0
  float w3r[2][4][3];
#pragma unroll
  for (int j=0;j<2;++j)
#pragma unroll
    for (int q=0;q<4;++q) {
      int gc = q*256 + w*32 + j*16 + li;
      w3r[j][q][0]=W3d[gc]; w3r[j][q][1]=W3d[1024+gc]; w3r[j][q][2]=W3d[2048+gc];
    }
  float w2r[2][3];
#pragma unroll
  for (int j=0;j<2;++j) {
    int hc = w*32 + j*16 + li;
    w2r[j][0]=W2Wo[hc*3+0]; w2r[j][1]=W2Wo[hc*3+1]; w2r[j][2]=W2Wo[hc*3+2];
  }
  const float b2w0 = b2Wo[0], b2w1 = b2Wo[1], b2w2 = b2Wo[2];
  float pp[4][3];
#pragma unroll
  for (int i=0;i<4;++i) {
    int r = rb + hi*4 + i;
    pp[i][0]=dec_pos[r*3+0]; pp[i][1]=dec_pos[r*3+1]; pp[i][2]=dec_pos[r*3+2];
  }

  // ---------------- decoder (1 lgkm-barrier/step) ----------------
  // enc t=4 wrote hBuf[0]; dec step t reads hBuf[t&1], writes hBuf[(t+1)&1].
  const f16* prD = pregD + (size_t)bblk*25*16384;
  LOADPV(pvA, prD, 0)
  for (int t=0;t<25;++t) {
    if (t+1 < 25) LOADPV(pvB, prD, t+1)
    ACCINIT()
    KFSTREAM(hBuf[t&1], Whh_d_p)
    STAGE(Whh_d_p, 2, 0) STAGE(Whh_d_p, 3, 1)   // for step t+1 (t=24: dead, harmless)
    float dpar[4][3];
#pragma unroll
    for (int i=0;i<4;++i){ dpar[i][0]=0.f; dpar[i][1]=0.f; dpar[i][2]=0.f; }
#pragma unroll
    for (int i=0;i<4;++i) {
      int r = hi*4 + i;
#pragma unroll
      for (int j=0;j<2;++j) {
        int hc = w*32 + j*16 + li;
        float gq[4];
#pragma unroll
        for (int q=0;q<4;++q)
          gq[q] = acc[q][j][i] + pp[i][0]*w3r[j][q][0] + pp[i][1]*w3r[j][q][1] + pp[i][2]*w3r[j][q][2];
        float cn = sigm(gq[1])*c_st[j][i] + sigm(gq[0])*tanh_(gq[2]);
        c_st[j][i] = cn;
        float h = sigm(gq[3])*tanh_(cn);
        hBuf[(t+1)&1][r*256 + (((hc>>3) ^ (r&7))<<3) + (hc&7)] = (f16)h;
        dpar[i][0] += h*w2r[j][0];
        dpar[i][1] += h*w2r[j][1];
        dpar[i][2] += h*w2r[j][2];
      }
    }
#pragma unroll
    for (int m=1;m<16;m<<=1)
#pragma unroll
      for (int i=0;i<4;++i) {
        dpar[i][0] += __shfl_xor(dpar[i][0], m);
        dpar[i][1] += __shfl_xor(dpar[i][1], m);
        dpar[i][2] += __shfl_xor(dpar[i][2], m);
      }
    if (li==0) {
#pragma unroll
      for (int i=0;i<4;++i) {
        int r = hi*4 + i;
        atomicAdd(&dpart[t][r][0], dpar[i][0]);
        atomicAdd(&dpart[t][r][1], dpar[i][1]);
        atomicAdd(&dpart[t][r][2], dpar[i][2]);
      }
    }
    if (t+1 < 25) { COPYPV() }
    bar_lgkm();                    // h[t+1] + dpart[t] visible; stages/pvB alive
    // pos update (redundant per 16-lane group, identical FP ops -> identical)
#pragma unroll
    for (int i=0;i<4;++i) {
      int r = hi*4 + i;
      float p0 = pp[i][0] + b2w0 + dpart[t][r][0];
      float p1 = pp[i][1] + b2w1 + dpart[t][r][1];
      float p2 = pp[i][2] + b2w2 + dpart[t][r][2];
      float inv = 1.0f/sqrtf(p0*p0+p1*p1+p2*p2);
      pp[i][0]=p0*inv; pp[i][1]=p1*inv; pp[i][2]=p2*inv;
      if (w==0 && li==0) {
        float* o = out + (size_t)(rb+r)*75 + t*3;
        o[0]=pp[i][0]; o[1]=pp[i][1]; o[2]=pp[i][2];
      }
    }
  }
#undef VMW
#undef STAGE
#undef MFMA_SLOT
#undef LOAD_HELD
#undef MFMA_HELD
#undef KFSTREAM
#undef LOADPV
#undef COPYPV
#undef ACCINIT
}

// ================= launch =================
extern "C" void kernel_launch(void* const* d_in, const int* in_sizes, int n_in,
                              void* d_out, int out_size, void* d_ws, size_t ws_size,
                              hipStream_t stream)
{
  const float* enc_pos = (const float*)d_in[0];
  const float* enc_sal = (const float*)d_in[1];
  const float* dec_pos = (const float*)d_in[2];
  const float* dec_sal = (const float*)d_in[3];
  const float* Wpe  = (const float*)d_in[4];
  const float* bpe  = (const float*)d_in[5];
  const float* Wse  = (const float*)d_in[6];
  const float* bse  = (const float*)d_in[7];
  const float* Wih_e= (const float*)d_in[8];
  const float* Whh_e= (const float*)d_in[9];
  const float* bih_e= (const float*)d_in[10];
  const float* bhh_e= (const float*)d_in[11];
  const float* Wih_d= (const float*)d_in[12];
  const float* Whh_d= (const float*)d_in[13];
  const float* bih_d= (const float*)d_in[14];
  const float* bhh_d= (const float*)d_in[15];
  const float* Wpd  = (const float*)d_in[16];
  const float* bpd  = (const float*)d_in[17];
  const float* Wsd  = (const float*)d_in[18];
  const float* bsd  = (const float*)d_in[19];
  const float* W2   = (const float*)d_in[20];
  const float* b2   = (const float*)d_in[21];
  const float* Wo   = (const float*)d_in[22];
  const float* bo   = (const float*)d_in[23];

  char* ws = (char*)d_ws;
  f16* pWse   = (f16*)(ws + OFF_WSE_P);
  f16* pWsd   = (f16*)(ws + OFF_WSD_P);
  f16* pWih_e = (f16*)(ws + OFF_WIHE_P);
  f16* pWih_d = (f16*)(ws + OFF_WIHD_P);
  f16* pWhh_e = (f16*)(ws + OFF_WHHE_P);
  f16* pWhh_d = (f16*)(ws + OFF_WHHD_P);
  float* W3e  = (float*)(ws + OFF_W3E);
  float* W3d  = (float*)(ws + OFF_W3D);
  float* W2WoP= (float*)(ws + OFF_W2WO);
  float* biasE= (float*)(ws + OFF_BIASE);
  float* biasD= (float*)(ws + OFF_BIASD);
  float* b2WoP= (float*)(ws + OFF_B2WO);
  f16* pregE  = (f16*)(ws + OFF_PREGE);
  f16* pregD  = (f16*)(ws + OFF_PREGD);
  float* out  = (float*)d_out;

  hipLaunchKernelGGL(k_prep, dim3(2570), dim3(256), 0, stream,
                     Wse, Wsd, Wih_e, Wih_d, Whh_e, Whh_d,
                     pWse, pWsd, pWih_e, pWih_d, pWhh_e, pWhh_d,
                     Wpe, bpe, bih_e, bhh_e, Wpd, bpd, bih_d, bhh_d,
                     W2, b2, Wo, bo,
                     W3e, W3d, biasE, biasD, W2WoP, b2WoP);
  // fused sal-projection + pre-gate GEMM: enc tiles [0,80) (pos folded), dec [80,480)
  hipLaunchKernelGGL(k_gemm_fused, dim3(480), dim3(256), 0, stream,
                     enc_sal, pWse, bse, pWih_e, biasE, pregE, 80, 5, enc_pos, W3e,
                     dec_sal, pWsd, bsd, pWih_d, biasD, pregD, 25);
  // fused encoder+decoder recurrence
  hipLaunchKernelGGL(k_rnn, dim3(64), dim3(512), 0, stream,
                     pregE, pregD, pWhh_e, pWhh_d,
                     W3d, dec_pos, W2WoP, b2WoP, out);
}

// Round 11
// 656.178 us; speedup vs baseline: 1.3850x; 1.0403x over previous
//
#include <hip/hip_runtime.h>

typedef _Float16 f16;
typedef _Float16 f16x4 __attribute__((ext_vector_type(4)));
typedef _Float16 f16x8 __attribute__((ext_vector_type(8)));
typedef float    f32x4 __attribute__((ext_vector_type(4)));
typedef unsigned int u32;

#define MFMA16(a,b,c) __builtin_amdgcn_mfma_f32_16x16x32_f16((a),(b),(c),0,0,0)

typedef __attribute__((address_space(1))) const u32 gu32;
typedef __attribute__((address_space(3))) u32 lu32;

static __device__ __forceinline__ float frcp(float x){ float r; asm("v_rcp_f32 %0, %1" : "=v"(r) : "v"(x)); return r; }
static __device__ __forceinline__ float frsq(float x){ float r; asm("v_rsq_f32 %0, %1" : "=v"(r) : "v"(x)); return r; }
static __device__ __forceinline__ float sigm(float x){ return frcp(1.0f + __expf(-x)); }
static __device__ __forceinline__ float tanh_(float x){ return 1.0f - 2.0f*frcp(1.0f + __expf(2.0f*x)); }

// barrier with LDS-visibility only: ds ops drained, global/gload_lds stay in flight
static __device__ __forceinline__ void bar_lgkm(){
  asm volatile("s_waitcnt lgkmcnt(0)" ::: "memory");
  __builtin_amdgcn_s_barrier();
  asm volatile("" ::: "memory");
}
static __device__ __forceinline__ void bar_plain(){
  asm volatile("" ::: "memory");
  __builtin_amdgcn_s_barrier();
  asm volatile("" ::: "memory");
}

// ---------------- workspace layout (bytes) ----------------
static constexpr size_t OFF_WSE_P  = 0;                                  // 4 MB
static constexpr size_t OFF_WSD_P  = OFF_WSE_P  + (size_t)8192*256*2;    // 4 MB
static constexpr size_t OFF_WIHE_P = OFF_WSD_P  + (size_t)8192*256*2;    // 512 KB
static constexpr size_t OFF_WIHD_P = OFF_WIHE_P + (size_t)256*1024*2;
static constexpr size_t OFF_WHHE_P = OFF_WIHD_P + (size_t)256*1024*2;
static constexpr size_t OFF_WHHD_P = OFF_WHHE_P + (size_t)256*1024*2;
static constexpr size_t OFF_W3E    = OFF_WHHD_P + (size_t)256*1024*2;
static constexpr size_t OFF_W3D    = OFF_W3E   + (size_t)3*1024*4;
static constexpr size_t OFF_W2WO   = OFF_W3D   + (size_t)3*1024*4;
static constexpr size_t OFF_BIASE  = OFF_W2WO  + (size_t)256*3*4;
static constexpr size_t OFF_BIASD  = OFF_BIASE + (size_t)1024*4;
static constexpr size_t OFF_B2WO   = OFF_BIASD + (size_t)1024*4;
static constexpr size_t OFF_PREGE  = OFF_B2WO  + 256;                    // 10.5 MB
static constexpr size_t OFF_PREGD  = OFF_PREGE + (size_t)5120*1024*2;    // 52.4 MB
static constexpr size_t OFF_END    = OFF_PREGD + (size_t)25600*1024*2;

// ================= prep: pack weights (blocks 0-2559) + small folds (2560-2569)
// pack layout [kfg][ctg][lane][8]; element (k,n): k = kfg*32+(l>>4)*8+i, n = ctg*16+(l&15)
__global__ __launch_bounds__(256) void k_prep(
    const float* __restrict__ Wse, const float* __restrict__ Wsd,
    const float* __restrict__ Wih_e, const float* __restrict__ Wih_d,
    const float* __restrict__ Whh_e, const float* __restrict__ Whh_d,
    f16* pWse, f16* pWsd, f16* pWih_e, f16* pWih_d, f16* pWhh_e, f16* pWhh_d,
    const float* __restrict__ Wpe, const float* __restrict__ bpe,
    const float* __restrict__ bih_e, const float* __restrict__ bhh_e,
    const float* __restrict__ Wpd, const float* __restrict__ bpd,
    const float* __restrict__ bih_d, const float* __restrict__ bhh_d,
    const float* __restrict__ W2, const float* __restrict__ b2,
    const float* __restrict__ Wo, const float* __restrict__ bo,
    float* W3e, float* W3d, float* biasE, float* biasD, float* W2Wo, float* b2Wo)
{
  int blk = blockIdx.x;
  if (blk < 2560) {
    const float* W; f16* o; int N, base;
    if      (blk < 1024) { W=Wse;   o=pWse;   N=256;  base=0; }
    else if (blk < 2048) { W=Wsd;   o=pWsd;   N=256;  base=1024; }
    else if (blk < 2176) { W=Wih_e; o=pWih_e; N=1024; base=2048; }  // k rows 0..255 (sal part)
    else if (blk < 2304) { W=Wih_d; o=pWih_d; N=1024; base=2176; }
    else if (blk < 2432) { W=Whh_e; o=pWhh_e; N=1024; base=2304; }
    else                 { W=Whh_d; o=pWhh_d; N=1024; base=2432; }
    int tid = (blk - base)*256 + threadIdx.x;
    int l = tid & 63;
    int nct = N >> 4;
    int ctg = (tid >> 6) % nct;
    int kfg = (tid >> 6) / nct;
    int k0  = kfg*32 + ((l>>4)<<3);
    int col = ctg*16 + (l&15);
    f16x8 v;
#pragma unroll
    for (int i=0;i<8;++i) v[i] = (f16)W[(size_t)(k0+i)*N + col];
    *(f16x8*)(o + (size_t)tid*8) = v;
    return;
  }
  int bid = blk - 2560, tid = threadIdx.x;
  if (bid < 4) {
    int j = bid*256 + tid;
    float s0=0,s1=0,s2=0,sb=0;
    for (int m=0;m<256;++m) {
      float wv = Wih_e[(size_t)(256+m)*1024 + j];
      s0 += Wpe[m]*wv; s1 += Wpe[256+m]*wv; s2 += Wpe[512+m]*wv; sb += bpe[m]*wv;
    }
    W3e[j]=s0; W3e[1024+j]=s1; W3e[2048+j]=s2;
    biasE[j] = bih_e[j] + bhh_e[j] + sb;
  } else if (bid < 8) {
    int j = (bid-4)*256 + tid;
    float s0=0,s1=0,s2=0,sb=0;
    for (int m=0;m<256;++m) {
      float wv = Wih_d[(size_t)(256+m)*1024 + j];
      s0 += Wpd[m]*wv; s1 += Wpd[256+m]*wv; s2 += Wpd[512+m]*wv; sb += bpd[m]*wv;
    }
    W3d[j]=s0; W3d[1024+j]=s1; W3d[2048+j]=s2;
    biasD[j] = bih_d[j] + bhh_d[j] + sb;
  } else if (bid == 8) {
    int c = tid;
    float s0=0,s1=0,s2=0;
    for (int m=0;m<256;++m) {
      float wv = W2[(size_t)c*256+m];
      s0 += wv*Wo[m*3+0]; s1 += wv*Wo[m*3+1]; s2 += wv*Wo[m*3+2];
    }
    W2Wo[c*3+0]=s0; W2Wo[c*3+1]=s1; W2Wo[c*3+2]=s2;
  } else {
    if (tid < 192) {
      int j = tid >> 6, lane = tid & 63;
      float s = 0.f;
      for (int m=lane;m<256;m+=64) s += b2[m]*Wo[m*3+j];
#pragma unroll
      for (int msk=1;msk<64;msk<<=1) s += __shfl_xor(s, msk);
      if (lane==0) b2Wo[j] = s + bo[j];
    }
  }
}

// ======== fused GEMM: preg = (A(f32,K=8192)@Ws + bs) @ Wih + bias [+ pos@W3] =
__global__ __launch_bounds__(256) void k_gemm_fused(
    const float* __restrict__ A0, const f16* __restrict__ W0,
    const float* __restrict__ bs0, const f16* __restrict__ Wih0,
    const float* __restrict__ bias0, f16* __restrict__ P0, int nb0, int T0,
    const float* __restrict__ pos0, const float* __restrict__ W3f0,
    const float* __restrict__ A1, const f16* __restrict__ W1,
    const float* __restrict__ bs1, const f16* __restrict__ Wih1,
    const float* __restrict__ bias1, f16* __restrict__ P1, int T1)
{
  __shared__ f16 aLDS[2][64*64];   // 16 KB: stage-1 A tiles, 16B-slot ^= row&7
  __shared__ f16 sLDS[64*256];     // 32 KB: sal tile, 16B-slot ^= row&7
  const int tid = threadIdx.x, l = tid & 63, w = tid >> 6;
  const int li = l & 15, hi = l >> 4;
  const int bx = blockIdx.x;
  const float *Ap, *bs, *bias, *posf, *W3f; const f16 *Wp, *Wih; f16* P; int rblk, T;
  if (bx < nb0) { Ap=A0; Wp=W0; bs=bs0; Wih=Wih0; bias=bias0; P=P0; rblk=bx*64;       T=T0; posf=pos0; W3f=W3f0; }
  else          { Ap=A1; Wp=W1; bs=bs1; Wih=Wih1; bias=bias1; P=P1; rblk=(bx-nb0)*64; T=T1; posf=nullptr; W3f=nullptr; }
  const int t = rblk >> 10, b0 = rblk & 1023;

  f32x4 acc[4][4];
#pragma unroll
  for (int a=0;a<4;++a)
#pragma unroll
    for (int b=0;b<4;++b) acc[a][b] = (f32x4){0.f,0.f,0.f,0.f};

  const int srow = tid >> 2, kseg = tid & 3;   // 64 rows x 4 k-segs
  const float* Arow = Ap + ((size_t)(b0 + srow)*T + t)*8192 + kseg*16;

  float4 fA0,fA1,fA2,fA3, fB0,fB1,fB2,fB3;
#define LOADA_A(ti_) { const float* Aq = Arow + (ti_)*64;                      \
    fA0 = *(const float4*)Aq;     fA1 = *(const float4*)(Aq+4);                \
    fA2 = *(const float4*)(Aq+8); fA3 = *(const float4*)(Aq+12); }
#define LOADA_B(ti_) { const float* Aq = Arow + (ti_)*64;                      \
    fB0 = *(const float4*)Aq;     fB1 = *(const float4*)(Aq+4);                \
    fB2 = *(const float4*)(Aq+8); fB3 = *(const float4*)(Aq+12); }
#define MFMA_TILE(buf_, kfg0_)                                                 \
  _Pragma("unroll")                                                            \
  for (int kf = 0; kf < 2; ++kf) {                                             \
    f16x8 afr[4], bfr[4];                                                      \
    _Pragma("unroll")                                                          \
    for (int rt=0; rt<4; ++rt) {                                               \
      int row = rt*16 + li;                                                    \
      afr[rt] = *(f16x8*)&aLDS[buf_][row*64 + (((kf*4) + hi) ^ (row&7))*8];    \
    }                                                                          \
    _Pragma("unroll")                                                          \
    for (int ct=0; ct<4; ++ct) {                                               \
      int ctg = w*4 + ct;                                                      \
      bfr[ct] = *(const f16x8*)(Wp + ((size_t)(((kfg0_)+kf)*16 + ctg)*64 + l)*8); \
    }                                                                          \
    _Pragma("unroll")                                                          \
    for (int rt=0; rt<4; ++rt)                                                 \
      _Pragma("unroll")                                                        \
      for (int ct=0; ct<4; ++ct)                                               \
        acc[rt][ct] = MFMA16(afr[rt], bfr[ct], acc[rt][ct]);                   \
  }
#define STAGE1_STEP(F0,F1,F2,F3, RELOAD, buf_, ti_) {                          \
    f16x8 w0, w1;  /* consume: load was issued 2 iterations ago */             \
    w0[0]=(f16)F0.x; w0[1]=(f16)F0.y; w0[2]=(f16)F0.z; w0[3]=(f16)F0.w;        \
    w0[4]=(f16)F1.x; w0[5]=(f16)F1.y; w0[6]=(f16)F1.z; w0[7]=(f16)F1.w;        \
    w1[0]=(f16)F2.x; w1[1]=(f16)F2.y; w1[2]=(f16)F2.z; w1[3]=(f16)F2.w;        \
    w1[4]=(f16)F3.x; w1[5]=(f16)F3.y; w1[6]=(f16)F3.z; w1[7]=(f16)F3.w;        \
    bar_plain();          /* readers of this buf (iter ti-2) done */           \
    *(f16x8*)&aLDS[buf_][srow*64 + ((kseg*2    ) ^ (srow&7))*8] = w0;          \
    *(f16x8*)&aLDS[buf_][srow*64 + ((kseg*2 + 1) ^ (srow&7))*8] = w1;          \
    { int tn = ((ti_)+2 < 128) ? (ti_)+2 : 127; RELOAD(tn); }                  \
    bar_lgkm();           /* LDS visible; A-loads stay in flight */            \
    MFMA_TILE(buf_, (ti_)*2)                                                   \
  }

  LOADA_A(0); LOADA_B(1);
  for (int ti = 0; ti < 128; ti += 2) {
    STAGE1_STEP(fA0,fA1,fA2,fA3, LOADA_A, 0, ti)
    STAGE1_STEP(fB0,fB1,fB2,fB3, LOADA_B, 1, ti+1)
  }
#undef LOADA_A
#undef LOADA_B
#undef MFMA_TILE
#undef STAGE1_STEP
  // stage-1 epilogue: sal tile (+bs) -> LDS, swizzled row-major [64][256]
  bar_plain();
#pragma unroll
  for (int ct=0; ct<4; ++ct) {
    int col = (w*4 + ct)*16 + li;
    float bv = bs[col];
    int slot = col >> 3;
#pragma unroll
    for (int rt=0; rt<4; ++rt)
#pragma unroll
      for (int i=0;i<4;++i) {
        int row = rt*16 + hi*4 + i;
        sLDS[row*256 + ((slot ^ (row&7))<<3) + (col&7)] = (f16)(acc[rt][ct][i] + bv);
      }
  }
  // enc job: load per-row pos once (reused across all output cols)
  float pe[4][4][3];
  if (posf) {
#pragma unroll
    for (int rt=0; rt<4; ++rt)
#pragma unroll
      for (int i=0;i<4;++i) {
        int brow = b0 + rt*16 + hi*4 + i;
        const float* pq = posf + ((size_t)brow*T + t)*3;
        pe[rt][i][0]=pq[0]; pe[rt][i][1]=pq[1]; pe[rt][i][2]=pq[2];
      }
  }
  __syncthreads();
  // stage-2: sal(64x256) @ Wih(256x1024), 4 col-chunks of 256
  const int bblk0 = b0 >> 4;
#pragma unroll
  for (int cg=0; cg<4; ++cg) {
    f32x4 a2[4][4];
#pragma unroll
    for (int a=0;a<4;++a)
#pragma unroll
      for (int b=0;b<4;++b) a2[a][b] = (f32x4){0.f,0.f,0.f,0.f};
#pragma unroll
    for (int kfg=0; kfg<8; ++kfg) {
      f16x8 afr[4], bfr[4];
#pragma unroll
      for (int rt=0; rt<4; ++rt) {
        int row = rt*16 + li;
        afr[rt] = *(f16x8*)&sLDS[row*256 + (((kfg*4 + hi) ^ (row&7))<<3)];
      }
#pragma unroll
      for (int ct=0; ct<4; ++ct) {
        int ctg2 = cg*16 + w*4 + ct;
        bfr[ct] = *(const f16x8*)(Wih + ((size_t)(kfg*64 + ctg2)*64 + l)*8);
      }
#pragma unroll
      for (int rt=0; rt<4; ++rt)
#pragma unroll
        for (int ct=0; ct<4; ++ct)
          a2[rt][ct] = MFMA16(afr[rt], bfr[ct], a2[rt][ct]);
    }
    // fragment-order store (identity with k_rnn's C-init loads); bias (+pos@W3) folded
#pragma unroll
    for (int ct=0; ct<4; ++ct) {
      const int ctg2 = cg*16 + w*4 + ct;
      const float bv = bias[ctg2*16 + li];
      float w30=0.f, w31=0.f, w32=0.f;
      if (posf) { int gc = ctg2*16 + li; w30=W3f[gc]; w31=W3f[1024+gc]; w32=W3f[2048+gc]; }
#pragma unroll
      for (int rt=0; rt<4; ++rt) {
        f16x4 o;
#pragma unroll
        for (int i=0;i<4;++i) {
          float v = a2[rt][ct][i] + bv;
          if (posf) v += pe[rt][i][0]*w30 + pe[rt][i][1]*w31 + pe[rt][i][2]*w32;
          o[i] = (f16)v;
        }
        *(f16x4*)(P + ((size_t)((bblk0 + rt)*T + t)*64 + ctg2)*256 + l*4) = o;
      }
    }
  }
}

// ================= fused recurrent kernel: encoder(5) then decoder(25) ======
// 64 blocks x 16 rows, 512 threads (8 waves). wave w owns h-cols [w*32,+32):
// ctg = q*16 + w*2 + j (gate quads lane-local).
// ALL 8 kf of Whh streamed per step through 2 wave-private LDS slots via
// global_load_lds + counted vmcnt(8) (stages 2-ahead; next step's kf0/kf1
// staged at the end of this step's stream). NO weights or W3 held in VGPRs
// -> true usage ~110 regs, below the observed 128 allocator cap (R9 showed
// VGPR=128 + 88MB scratch writes = hot-loop spilling; this removes it).
// pvB preg prefetch issued AFTER the stream so no VMW waits on HBM.
__global__ __launch_bounds__(512) void k_rnn(
    const f16* __restrict__ pregE,   // [b_blk][5][64][64][4]  (pos+bias folded)
    const f16* __restrict__ pregD,   // [b_blk][25][64][64][4] (bias folded)
    const f16* __restrict__ Whh_e_p, const f16* __restrict__ Whh_d_p,
    const float* __restrict__ W3d, const float* __restrict__ dec_pos,
    const float* __restrict__ W2Wo, const float* __restrict__ b2Wo,
    float* __restrict__ out)         // (B,25,3)
{
  __shared__ f16 wLDS[8][2][8][512]; // 128 KB: [wave][slot][frag][lane*8]
  __shared__ f16 hBuf[2][16*256];    // 16 KB, swizzled (16B slot ^= row&7)
  __shared__ f16 W3h[3*1024];        // 6 KB (f16 fold of W3d)
  __shared__ float dpart[25][16][3]; // 4.7 KB per-step delta accumulators
  const int tid = threadIdx.x, l = tid & 63, w = tid >> 6;
  const int li = l & 15, hi = l >> 4;
  const int bblk = blockIdx.x, rb = bblk*16;

  for (int i=tid;i<3072;i+=512) W3h[i] = (f16)W3d[i];
  for (int i=tid; i<25*16*3; i+=512) ((float*)dpart)[i] = 0.f;

  float c_st[2][4];
#pragma unroll
  for (int j=0;j<2;++j)
#pragma unroll
    for (int i=0;i<4;++i) c_st[j][i]=0.f;

  // ---- macros ----
#define VMW(n) { asm volatile("s_waitcnt vmcnt(" #n ")" ::: "memory");        \
                 __builtin_amdgcn_sched_barrier(0); }
#define STAGE(WP, kf, s)                                                      \
  _Pragma("unroll") for (int f=0; f<8; ++f) {                                 \
    int ctg = (f>>1)*16 + w*2 + (f&1);                                        \
    const f16* g = (WP) + ((size_t)((kf)*64 + ctg)*64 + l)*8;                 \
    __builtin_amdgcn_global_load_lds((gu32*)g, (lu32*)&wLDS[w][s][f][0], 16, 0, 0); \
  }
#define MFMA_SLOT(s, kf, hB) {                                                \
  f16x8 ah = *(f16x8*)&(hB)[li*256 + ((((kf)*4)+hi) ^ (li&7))*8];             \
  _Pragma("unroll") for (int f=0; f<8; ++f) {                                 \
    f16x8 b = *(f16x8*)&wLDS[w][s][f][l*8];                                   \
    acc[f>>1][f&1] = MFMA16(ah, b, acc[f>>1][f&1]); } }
// stream all 8 kf; entering queue must be EMPTY (ACCINIT's implicit wait
// drains it) with slots s0=kf0, s1=kf1 pre-staged. Stages run 2 ahead; the
// last two stage NEXT step's kf0/kf1 (WPn) so every VMW(8) has exactly 8
// younger ops in flight. Exits with queue = [kf0', kf1'].
#define KFSTREAM(hB, WP, WPn)                                                 \
  MFMA_SLOT(0, 0, hB) STAGE(WP, 2, 0)                                         \
  MFMA_SLOT(1, 1, hB) STAGE(WP, 3, 1)                                         \
  VMW(8) MFMA_SLOT(0, 2, hB) STAGE(WP, 4, 0)                                  \
  VMW(8) MFMA_SLOT(1, 3, hB) STAGE(WP, 5, 1)                                  \
  VMW(8) MFMA_SLOT(0, 4, hB) STAGE(WP, 6, 0)                                  \
  VMW(8) MFMA_SLOT(1, 5, hB) STAGE(WP, 7, 1)                                  \
  VMW(8) MFMA_SLOT(0, 6, hB) STAGE(WPn, 0, 0)                                 \
  VMW(8) MFMA_SLOT(1, 7, hB) STAGE(WPn, 1, 1)
#define LOADPV(dst, base, t_)                                                 \
  _Pragma("unroll")                                                           \
  for (int q=0;q<4;++q)                                                       \
    _Pragma("unroll")                                                         \
    for (int j=0;j<2;++j)                                                     \
      dst[q][j] = *(const f16x4*)((base) + ((size_t)(t_)*16384 + (size_t)(q*16 + w*2 + j)*256 + l*4));
#define COPYPV()                                                              \
  _Pragma("unroll")                                                           \
  for (int q=0;q<4;++q)                                                       \
    _Pragma("unroll")                                                         \
    for (int j=0;j<2;++j) pvA[q][j] = pvB[q][j];
#define ACCINIT()                                                             \
  f32x4 acc[4][2];                                                            \
  _Pragma("unroll")                                                           \
  for (int q=0;q<4;++q)                                                       \
    _Pragma("unroll")                                                         \
    for (int j=0;j<2;++j)                                                     \
      acc[q][j] = (f32x4){(float)pvA[q][j][0],(float)pvA[q][j][1],(float)pvA[q][j][2],(float)pvA[q][j][3]};

  // ---------------- encoder (gate = acc only: bias+pos pre-folded) ---------
  const f16* prE = pregE + (size_t)bblk*5*16384;
  f16x4 pvA[4][2], pvB[4][2];
  LOADPV(pvA, prE, 0)
  __syncthreads();                 // W3h + dpart init visible (once)
  for (int t=0;t<5;++t) {
    ACCINIT()                      // implicit vmcnt wait drains prior queue
    if (t == 0) { STAGE(Whh_e_p, 0, 0) STAGE(Whh_e_p, 1, 1) }   // for t=1
    else if (t < 4) { KFSTREAM(hBuf[(t-1)&1], Whh_e_p, Whh_e_p) }
    else            { KFSTREAM(hBuf[(t-1)&1], Whh_e_p, Whh_d_p) }  // stage dec kf0/1
    if (t+1 < 5) LOADPV(pvB, prE, t+1)   // youngest in queue: no VMW touches it
#pragma unroll
    for (int i=0;i<4;++i) {
      int r = hi*4 + i;
#pragma unroll
      for (int j=0;j<2;++j) {
        int hc = w*32 + j*16 + li;
        float cn = sigm(acc[1][j][i])*c_st[j][i] + sigm(acc[0][j][i])*tanh_(acc[2][j][i]);
        c_st[j][i] = cn;
        float h = sigm(acc[3][j][i])*tanh_(cn);
        hBuf[t&1][r*256 + (((hc>>3) ^ (r&7))<<3) + (hc&7)] = (f16)h;
      }
    }
    if (t+1 < 5) { COPYPV() }
    bar_lgkm();                    // h[t] visible; stages + pvB stay in flight
  }

  // ---------------- decoder constants ----------------
  float w2r[2][3];
#pragma unroll
  for (int j=0;j<2;++j) {
    int hc = w*32 + j*16 + li;
    w2r[j][0]=W2Wo[hc*3+0]; w2r[j][1]=W2Wo[hc*3+1]; w2r[j][2]=W2Wo[hc*3+2];
  }
  const float b2w0 = b2Wo[0], b2w1 = b2Wo[1], b2w2 = b2Wo[2];
  float pp[4][3];
#pragma unroll
  for (int i=0;i<4;++i) {
    int r = rb + hi*4 + i;
    pp[i][0]=dec_pos[r*3+0]; pp[i][1]=dec_pos[r*3+1]; pp[i][2]=dec_pos[r*3+2];
  }

  // ---------------- decoder (1 lgkm-barrier/step) ----------------
  // enc t=4 wrote hBuf[0] and staged dec kf0/kf1; dec step t reads hBuf[t&1].
  const f16* prD = pregD + (size_t)bblk*25*16384;
  LOADPV(pvA, prD, 0)
  for (int t=0;t<25;++t) {
    ACCINIT()                      // implicit wait drains [kf0,kf1,pv]
    KFSTREAM(hBuf[t&1], Whh_d_p, Whh_d_p)   // t=24 trailing stages wasted, harmless
    if (t+1 < 25) LOADPV(pvB, prD, t+1)
    // per-step W3 gather from LDS (f16) — CSE'd across i, transient regs only
    float w3v[2][4][3];
#pragma unroll
    for (int j=0;j<2;++j)
#pragma unroll
      for (int q=0;q<4;++q) {
        int gc = q*256 + w*32 + j*16 + li;
        w3v[j][q][0] = (float)W3h[gc];
        w3v[j][q][1] = (float)W3h[1024+gc];
        w3v[j][q][2] = (float)W3h[2048+gc];
      }
    float dpar[4][3];
#pragma unroll
    for (int i=0;i<4;++i){ dpar[i][0]=0.f; dpar[i][1]=0.f; dpar[i][2]=0.f; }
#pragma unroll
    for (int i=0;i<4;++i) {
      int r = hi*4 + i;
#pragma unroll
      for (int j=0;j<2;++j) {
        int hc = w*32 + j*16 + li;
        float gq[4];
#pragma unroll
        for (int q=0;q<4;++q)
          gq[q] = acc[q][j][i] + pp[i][0]*w3v[j][q][0] + pp[i][1]*w3v[j][q][1] + pp[i][2]*w3v[j][q][2];
        float cn = sigm(gq[1])*c_st[j][i] + sigm(gq[0])*tanh_(gq[2]);
        c_st[j][i] = cn;
        float h = sigm(gq[3])*tanh_(cn);
        hBuf[(t+1)&1][r*256 + (((hc>>3) ^ (r&7))<<3) + (hc&7)] = (f16)h;
        dpar[i][0] += h*w2r[j][0];
        dpar[i][1] += h*w2r[j][1];
        dpar[i][2] += h*w2r[j][2];
      }
    }
#pragma unroll
    for (int m=1;m<16;m<<=1)
#pragma unroll
      for (int i=0;i<4;++i) {
        dpar[i][0] += __shfl_xor(dpar[i][0], m);
        dpar[i][1] += __shfl_xor(dpar[i][1], m);
        dpar[i][2] += __shfl_xor(dpar[i][2], m);
      }
    if (li==0) {
#pragma unroll
      for (int i=0;i<4;++i) {
        int r = hi*4 + i;
        atomicAdd(&dpart[t][r][0], dpar[i][0]);
        atomicAdd(&dpart[t][r][1], dpar[i][1]);
        atomicAdd(&dpart[t][r][2], dpar[i][2]);
      }
    }
    if (t+1 < 25) { COPYPV() }
    bar_lgkm();                    // h[t+1] + dpart[t] visible; stages/pvB alive
    // pos update (redundant per 16-lane group, identical FP ops -> identical)
#pragma unroll
    for (int i=0;i<4;++i) {
      int r = hi*4 + i;
      float p0 = pp[i][0] + b2w0 + dpart[t][r][0];
      float p1 = pp[i][1] + b2w1 + dpart[t][r][1];
      float p2 = pp[i][2] + b2w2 + dpart[t][r][2];
      float inv = frsq(p0*p0+p1*p1+p2*p2);
      pp[i][0]=p0*inv; pp[i][1]=p1*inv; pp[i][2]=p2*inv;
      if (w==0 && li==0) {
        float* o = out + (size_t)(rb+r)*75 + t*3;
        o[0]=pp[i][0]; o[1]=pp[i][1]; o[2]=pp[i][2];
      }
    }
  }
#undef VMW
#undef STAGE
#undef MFMA_SLOT
#undef KFSTREAM
#undef LOADPV
#undef COPYPV
#undef ACCINIT
}

// ================= launch =================
extern "C" void kernel_launch(void* const* d_in, const int* in_sizes, int n_in,
                              void* d_out, int out_size, void* d_ws, size_t ws_size,
                              hipStream_t stream)
{
  const float* enc_pos = (const float*)d_in[0];
  const float* enc_sal = (const float*)d_in[1];
  const float* dec_pos = (const float*)d_in[2];
  const float* dec_sal = (const float*)d_in[3];
  const float* Wpe  = (const float*)d_in[4];
  const float* bpe  = (const float*)d_in[5];
  const float* Wse  = (const float*)d_in[6];
  const float* bse  = (const float*)d_in[7];
  const float* Wih_e= (const float*)d_in[8];
  const float* Whh_e= (const float*)d_in[9];
  const float* bih_e= (const float*)d_in[10];
  const float* bhh_e= (const float*)d_in[11];
  const float* Wih_d= (const float*)d_in[12];
  const float* Whh_d= (const float*)d_in[13];
  const float* bih_d= (const float*)d_in[14];
  const float* bhh_d= (const float*)d_in[15];
  const float* Wpd  = (const float*)d_in[16];
  const float* bpd  = (const float*)d_in[17];
  const float* Wsd  = (const float*)d_in[18];
  const float* bsd  = (const float*)d_in[19];
  const float* W2   = (const float*)d_in[20];
  const float* b2   = (const float*)d_in[21];
  const float* Wo   = (const float*)d_in[22];
  const float* bo   = (const float*)d_in[23];

  char* ws = (char*)d_ws;
  f16* pWse   = (f16*)(ws + OFF_WSE_P);
  f16* pWsd   = (f16*)(ws + OFF_WSD_P);
  f16* pWih_e = (f16*)(ws + OFF_WIHE_P);
  f16* pWih_d = (f16*)(ws + OFF_WIHD_P);
  f16* pWhh_e = (f16*)(ws + OFF_WHHE_P);
  f16* pWhh_d = (f16*)(ws + OFF_WHHD_P);
  float* W3e  = (float*)(ws + OFF_W3E);
  float* W3d  = (float*)(ws + OFF_W3D);
  float* W2WoP= (float*)(ws + OFF_W2WO);
  float* biasE= (float*)(ws + OFF_BIASE);
  float* biasD= (float*)(ws + OFF_BIASD);
  float* b2WoP= (float*)(ws + OFF_B2WO);
  f16* pregE  = (f16*)(ws + OFF_PREGE);
  f16* pregD  = (f16*)(ws + OFF_PREGD);
  float* out  = (float*)d_out;

  hipLaunchKernelGGL(k_prep, dim3(2570), dim3(256), 0, stream,
                     Wse, Wsd, Wih_e, Wih_d, Whh_e, Whh_d,
                     pWse, pWsd, pWih_e, pWih_d, pWhh_e, pWhh_d,
                     Wpe, bpe, bih_e, bhh_e, Wpd, bpd, bih_d, bhh_d,
                     W2, b2, Wo, bo,
                     W3e, W3d, biasE, biasD, W2WoP, b2WoP);
  // fused sal-projection + pre-gate GEMM: enc tiles [0,80) (pos folded), dec [80,480)
  hipLaunchKernelGGL(k_gemm_fused, dim3(480), dim3(256), 0, stream,
                     enc_sal, pWse, bse, pWih_e, biasE, pregE, 80, 5, enc_pos, W3e,
                     dec_sal, pWsd, bsd, pWih_d, biasD, pregD, 25);
  // fused encoder+decoder recurrence
  hipLaunchKernelGGL(k_rnn, dim3(64), dim3(512), 0, stream,
                     pregE, pregD, pWhh_e, pWhh_d,
                     W3d, dec_pos, W2WoP, b2WoP, out);
}

// Round 12
// 623.897 us; speedup vs baseline: 1.4566x; 1.0517x over previous
//
#include <hip/hip_runtime.h>

typedef _Float16 f16;
typedef _Float16 f16x4 __attribute__((ext_vector_type(4)));
typedef _Float16 f16x8 __attribute__((ext_vector_type(8)));
typedef float    f32x4 __attribute__((ext_vector_type(4)));
typedef unsigned int u32;

#define MFMA16(a,b,c) __builtin_amdgcn_mfma_f32_16x16x32_f16((a),(b),(c),0,0,0)

typedef __attribute__((address_space(1))) const u32 gu32;
typedef __attribute__((address_space(3))) u32 lu32;

static __device__ __forceinline__ float frcp(float x){ float r; asm("v_rcp_f32 %0, %1" : "=v"(r) : "v"(x)); return r; }
static __device__ __forceinline__ float frsq(float x){ float r; asm("v_rsq_f32 %0, %1" : "=v"(r) : "v"(x)); return r; }
static __device__ __forceinline__ float sigm(float x){ return frcp(1.0f + __expf(-x)); }
static __device__ __forceinline__ float tanh_(float x){ return 1.0f - 2.0f*frcp(1.0f + __expf(2.0f*x)); }

// barrier with LDS-visibility only: ds ops drained, global/gload_lds stay in flight
static __device__ __forceinline__ void bar_lgkm(){
  asm volatile("s_waitcnt lgkmcnt(0)" ::: "memory");
  __builtin_amdgcn_s_barrier();
  asm volatile("" ::: "memory");
}
static __device__ __forceinline__ void bar_plain(){
  asm volatile("" ::: "memory");
  __builtin_amdgcn_s_barrier();
  asm volatile("" ::: "memory");
}

// ---------------- workspace layout (bytes) ----------------
static constexpr size_t OFF_WSE_P  = 0;                                  // 4 MB
static constexpr size_t OFF_WSD_P  = OFF_WSE_P  + (size_t)8192*256*2;    // 4 MB
static constexpr size_t OFF_WIHE_P = OFF_WSD_P  + (size_t)8192*256*2;    // 512 KB
static constexpr size_t OFF_WIHD_P = OFF_WIHE_P + (size_t)256*1024*2;
static constexpr size_t OFF_WHHE_P = OFF_WIHD_P + (size_t)256*1024*2;
static constexpr size_t OFF_WHHD_P = OFF_WHHE_P + (size_t)256*1024*2;
static constexpr size_t OFF_W3E    = OFF_WHHD_P + (size_t)256*1024*2;
static constexpr size_t OFF_W3D    = OFF_W3E   + (size_t)3*1024*4;
static constexpr size_t OFF_W2WO   = OFF_W3D   + (size_t)3*1024*4;
static constexpr size_t OFF_BIASE  = OFF_W2WO  + (size_t)256*3*4;
static constexpr size_t OFF_BIASD  = OFF_BIASE + (size_t)1024*4;
static constexpr size_t OFF_B2WO   = OFF_BIASD + (size_t)1024*4;
static constexpr size_t OFF_PREGE  = OFF_B2WO  + 256;                    // 10.5 MB
static constexpr size_t OFF_PREGD  = OFF_PREGE + (size_t)5120*1024*2;    // 52.4 MB
static constexpr size_t OFF_END    = OFF_PREGD + (size_t)25600*1024*2;

// ================= prep: pack weights (blocks 0-2559) + small folds (2560-2569)
// pack layout [kfg][ctg][lane][8]; element (k,n): k = kfg*32+(l>>4)*8+i, n = ctg*16+(l&15)
__global__ __launch_bounds__(256) void k_prep(
    const float* __restrict__ Wse, const float* __restrict__ Wsd,
    const float* __restrict__ Wih_e, const float* __restrict__ Wih_d,
    const float* __restrict__ Whh_e, const float* __restrict__ Whh_d,
    f16* pWse, f16* pWsd, f16* pWih_e, f16* pWih_d, f16* pWhh_e, f16* pWhh_d,
    const float* __restrict__ Wpe, const float* __restrict__ bpe,
    const float* __restrict__ bih_e, const float* __restrict__ bhh_e,
    const float* __restrict__ Wpd, const float* __restrict__ bpd,
    const float* __restrict__ bih_d, const float* __restrict__ bhh_d,
    const float* __restrict__ W2, const float* __restrict__ b2,
    const float* __restrict__ Wo, const float* __restrict__ bo,
    float* W3e, float* W3d, float* biasE, float* biasD, float* W2Wo, float* b2Wo)
{
  int blk = blockIdx.x;
  if (blk < 2560) {
    const float* W; f16* o; int N, base;
    if      (blk < 1024) { W=Wse;   o=pWse;   N=256;  base=0; }
    else if (blk < 2048) { W=Wsd;   o=pWsd;   N=256;  base=1024; }
    else if (blk < 2176) { W=Wih_e; o=pWih_e; N=1024; base=2048; }  // k rows 0..255 (sal part)
    else if (blk < 2304) { W=Wih_d; o=pWih_d; N=1024; base=2176; }
    else if (blk < 2432) { W=Whh_e; o=pWhh_e; N=1024; base=2304; }
    else                 { W=Whh_d; o=pWhh_d; N=1024; base=2432; }
    int tid = (blk - base)*256 + threadIdx.x;
    int l = tid & 63;
    int nct = N >> 4;
    int ctg = (tid >> 6) % nct;
    int kfg = (tid >> 6) / nct;
    int k0  = kfg*32 + ((l>>4)<<3);
    int col = ctg*16 + (l&15);
    f16x8 v;
#pragma unroll
    for (int i=0;i<8;++i) v[i] = (f16)W[(size_t)(k0+i)*N + col];
    *(f16x8*)(o + (size_t)tid*8) = v;
    return;
  }
  int bid = blk - 2560, tid = threadIdx.x;
  if (bid < 4) {
    int j = bid*256 + tid;
    float s0=0,s1=0,s2=0,sb=0;
    for (int m=0;m<256;++m) {
      float wv = Wih_e[(size_t)(256+m)*1024 + j];
      s0 += Wpe[m]*wv; s1 += Wpe[256+m]*wv; s2 += Wpe[512+m]*wv; sb += bpe[m]*wv;
    }
    W3e[j]=s0; W3e[1024+j]=s1; W3e[2048+j]=s2;
    biasE[j] = bih_e[j] + bhh_e[j] + sb;
  } else if (bid < 8) {
    int j = (bid-4)*256 + tid;
    float s0=0,s1=0,s2=0,sb=0;
    for (int m=0;m<256;++m) {
      float wv = Wih_d[(size_t)(256+m)*1024 + j];
      s0 += Wpd[m]*wv; s1 += Wpd[256+m]*wv; s2 += Wpd[512+m]*wv; sb += bpd[m]*wv;
    }
    W3d[j]=s0; W3d[1024+j]=s1; W3d[2048+j]=s2;
    biasD[j] = bih_d[j] + bhh_d[j] + sb;
  } else if (bid == 8) {
    int c = tid;
    float s0=0,s1=0,s2=0;
    for (int m=0;m<256;++m) {
      float wv = W2[(size_t)c*256+m];
      s0 += wv*Wo[m*3+0]; s1 += wv*Wo[m*3+1]; s2 += wv*Wo[m*3+2];
    }
    W2Wo[c*3+0]=s0; W2Wo[c*3+1]=s1; W2Wo[c*3+2]=s2;
  } else {
    if (tid < 192) {
      int j = tid >> 6, lane = tid & 63;
      float s = 0.f;
      for (int m=lane;m<256;m+=64) s += b2[m]*Wo[m*3+j];
#pragma unroll
      for (int msk=1;msk<64;msk<<=1) s += __shfl_xor(s, msk);
      if (lane==0) b2Wo[j] = s + bo[j];
    }
  }
}

// ======== fused GEMM: preg = (A(f32,K=8192)@Ws + bs) @ Wih + bias [+ pos@W3] =
__global__ __launch_bounds__(256) void k_gemm_fused(
    const float* __restrict__ A0, const f16* __restrict__ W0,
    const float* __restrict__ bs0, const f16* __restrict__ Wih0,
    const float* __restrict__ bias0, f16* __restrict__ P0, int nb0, int T0,
    const float* __restrict__ pos0, const float* __restrict__ W3f0,
    const float* __restrict__ A1, const f16* __restrict__ W1,
    const float* __restrict__ bs1, const f16* __restrict__ Wih1,
    const float* __restrict__ bias1, f16* __restrict__ P1, int T1)
{
  __shared__ f16 aLDS[2][64*64];   // 16 KB: stage-1 A tiles, 16B-slot ^= row&7
  __shared__ f16 sLDS[64*256];     // 32 KB: sal tile, 16B-slot ^= row&7
  const int tid = threadIdx.x, l = tid & 63, w = tid >> 6;
  const int li = l & 15, hi = l >> 4;
  const int bx = blockIdx.x;
  const float *Ap, *bs, *bias, *posf, *W3f; const f16 *Wp, *Wih; f16* P; int rblk, T;
  if (bx < nb0) { Ap=A0; Wp=W0; bs=bs0; Wih=Wih0; bias=bias0; P=P0; rblk=bx*64;       T=T0; posf=pos0; W3f=W3f0; }
  else          { Ap=A1; Wp=W1; bs=bs1; Wih=Wih1; bias=bias1; P=P1; rblk=(bx-nb0)*64; T=T1; posf=nullptr; W3f=nullptr; }
  const int t = rblk >> 10, b0 = rblk & 1023;

  f32x4 acc[4][4];
#pragma unroll
  for (int a=0;a<4;++a)
#pragma unroll
    for (int b=0;b<4;++b) acc[a][b] = (f32x4){0.f,0.f,0.f,0.f};

  const int srow = tid >> 2, kseg = tid & 3;   // 64 rows x 4 k-segs
  const float* Arow = Ap + ((size_t)(b0 + srow)*T + t)*8192 + kseg*16;

  float4 fA0,fA1,fA2,fA3, fB0,fB1,fB2,fB3;
#define LOADA_A(ti_) { const float* Aq = Arow + (ti_)*64;                      \
    fA0 = *(const float4*)Aq;     fA1 = *(const float4*)(Aq+4);                \
    fA2 = *(const float4*)(Aq+8); fA3 = *(const float4*)(Aq+12); }
#define LOADA_B(ti_) { const float* Aq = Arow + (ti_)*64;                      \
    fB0 = *(const float4*)Aq;     fB1 = *(const float4*)(Aq+4);                \
    fB2 = *(const float4*)(Aq+8); fB3 = *(const float4*)(Aq+12); }
#define MFMA_TILE(buf_, kfg0_)                                                 \
  _Pragma("unroll")                                                            \
  for (int kf = 0; kf < 2; ++kf) {                                             \
    f16x8 afr[4], bfr[4];                                                      \
    _Pragma("unroll")                                                          \
    for (int rt=0; rt<4; ++rt) {                                               \
      int row = rt*16 + li;                                                    \
      afr[rt] = *(f16x8*)&aLDS[buf_][row*64 + (((kf*4) + hi) ^ (row&7))*8];    \
    }                                                                          \
    _Pragma("unroll")                                                          \
    for (int ct=0; ct<4; ++ct) {                                               \
      int ctg = w*4 + ct;                                                      \
      bfr[ct] = *(const f16x8*)(Wp + ((size_t)(((kfg0_)+kf)*16 + ctg)*64 + l)*8); \
    }                                                                          \
    _Pragma("unroll")                                                          \
    for (int rt=0; rt<4; ++rt)                                                 \
      _Pragma("unroll")                                                        \
      for (int ct=0; ct<4; ++ct)                                               \
        acc[rt][ct] = MFMA16(afr[rt], bfr[ct], acc[rt][ct]);                   \
  }
#define STAGE1_STEP(F0,F1,F2,F3, RELOAD, buf_, ti_) {                          \
    f16x8 w0, w1;  /* consume: load was issued 2 iterations ago */             \
    w0[0]=(f16)F0.x; w0[1]=(f16)F0.y; w0[2]=(f16)F0.z; w0[3]=(f16)F0.w;        \
    w0[4]=(f16)F1.x; w0[5]=(f16)F1.y; w0[6]=(f16)F1.z; w0[7]=(f16)F1.w;        \
    w1[0]=(f16)F2.x; w1[1]=(f16)F2.y; w1[2]=(f16)F2.z; w1[3]=(f16)F2.w;        \
    w1[4]=(f16)F3.x; w1[5]=(f16)F3.y; w1[6]=(f16)F3.z; w1[7]=(f16)F3.w;        \
    bar_plain();          /* readers of this buf (iter ti-2) done */           \
    *(f16x8*)&aLDS[buf_][srow*64 + ((kseg*2    ) ^ (srow&7))*8] = w0;          \
    *(f16x8*)&aLDS[buf_][srow*64 + ((kseg*2 + 1) ^ (srow&7))*8] = w1;          \
    { int tn = ((ti_)+2 < 128) ? (ti_)+2 : 127; RELOAD(tn); }                  \
    bar_lgkm();           /* LDS visible; A-loads stay in flight */            \
    MFMA_TILE(buf_, (ti_)*2)                                                   \
  }

  LOADA_A(0); LOADA_B(1);
  for (int ti = 0; ti < 128; ti += 2) {
    STAGE1_STEP(fA0,fA1,fA2,fA3, LOADA_A, 0, ti)
    STAGE1_STEP(fB0,fB1,fB2,fB3, LOADA_B, 1, ti+1)
  }
#undef LOADA_A
#undef LOADA_B
#undef MFMA_TILE
#undef STAGE1_STEP
  // stage-1 epilogue: sal tile (+bs) -> LDS, swizzled row-major [64][256]
  bar_plain();
#pragma unroll
  for (int ct=0; ct<4; ++ct) {
    int col = (w*4 + ct)*16 + li;
    float bv = bs[col];
    int slot = col >> 3;
#pragma unroll
    for (int rt=0; rt<4; ++rt)
#pragma unroll
      for (int i=0;i<4;++i) {
        int row = rt*16 + hi*4 + i;
        sLDS[row*256 + ((slot ^ (row&7))<<3) + (col&7)] = (f16)(acc[rt][ct][i] + bv);
      }
  }
  // enc job: load per-row pos once (reused across all output cols)
  float pe[4][4][3];
  if (posf) {
#pragma unroll
    for (int rt=0; rt<4; ++rt)
#pragma unroll
      for (int i=0;i<4;++i) {
        int brow = b0 + rt*16 + hi*4 + i;
        const float* pq = posf + ((size_t)brow*T + t)*3;
        pe[rt][i][0]=pq[0]; pe[rt][i][1]=pq[1]; pe[rt][i][2]=pq[2];
      }
  }
  __syncthreads();
  // stage-2: sal(64x256) @ Wih(256x1024), 4 col-chunks of 256
  const int bblk0 = b0 >> 4;
#pragma unroll
  for (int cg=0; cg<4; ++cg) {
    f32x4 a2[4][4];
#pragma unroll
    for (int a=0;a<4;++a)
#pragma unroll
      for (int b=0;b<4;++b) a2[a][b] = (f32x4){0.f,0.f,0.f,0.f};
#pragma unroll
    for (int kfg=0; kfg<8; ++kfg) {
      f16x8 afr[4], bfr[4];
#pragma unroll
      for (int rt=0; rt<4; ++rt) {
        int row = rt*16 + li;
        afr[rt] = *(f16x8*)&sLDS[row*256 + (((kfg*4 + hi) ^ (row&7))<<3)];
      }
#pragma unroll
      for (int ct=0; ct<4; ++ct) {
        int ctg2 = cg*16 + w*4 + ct;
        bfr[ct] = *(const f16x8*)(Wih + ((size_t)(kfg*64 + ctg2)*64 + l)*8);
      }
#pragma unroll
      for (int rt=0; rt<4; ++rt)
#pragma unroll
        for (int ct=0; ct<4; ++ct)
          a2[rt][ct] = MFMA16(afr[rt], bfr[ct], a2[rt][ct]);
    }
    // fragment-order store (identity with k_rnn's C-init loads); bias (+pos@W3) folded
#pragma unroll
    for (int ct=0; ct<4; ++ct) {
      const int ctg2 = cg*16 + w*4 + ct;
      const float bv = bias[ctg2*16 + li];
      float w30=0.f, w31=0.f, w32=0.f;
      if (posf) { int gc = ctg2*16 + li; w30=W3f[gc]; w31=W3f[1024+gc]; w32=W3f[2048+gc]; }
#pragma unroll
      for (int rt=0; rt<4; ++rt) {
        f16x4 o;
#pragma unroll
        for (int i=0;i<4;++i) {
          float v = a2[rt][ct][i] + bv;
          if (posf) v += pe[rt][i][0]*w30 + pe[rt][i][1]*w31 + pe[rt][i][2]*w32;
          o[i] = (f16)v;
        }
        *(f16x4*)(P + ((size_t)((bblk0 + rt)*T + t)*64 + ctg2)*256 + l*4) = o;
      }
    }
  }
}

// ================= fused recurrent kernel: encoder(5) then decoder(25) ======
// 64 blocks x 16 rows, 512 threads (8 waves). wave w owns h-cols [w*32,+32):
// ctg = q*16 + w*2 + j (gate quads lane-local).
// Whh streamed per step through 4 wave-private 4KB LDS slots (16 stages of
// 4 frags each) with counted vmcnt: 3 stages (12KB) always in flight ->
// saturates the ~64B/cy per-CU L2 path (needs ~13KB to cover ~200cy latency).
// pv preg prefetch issued at step top: retires during the first VMW(12), so
// COPYPV never drains. Next step's first 4 stages issue at stream tail.
__global__ __launch_bounds__(512) void k_rnn(
    const f16* __restrict__ pregE,   // [b_blk][5][64][64][4]  (pos+bias folded)
    const f16* __restrict__ pregD,   // [b_blk][25][64][64][4] (bias folded)
    const f16* __restrict__ Whh_e_p, const f16* __restrict__ Whh_d_p,
    const float* __restrict__ W3d, const float* __restrict__ dec_pos,
    const float* __restrict__ W2Wo, const float* __restrict__ b2Wo,
    float* __restrict__ out)         // (B,25,3)
{
  __shared__ f16 wLDS[8][4][4][512]; // 128 KB: [wave][slot][frag][lane*8]
  __shared__ f16 hBuf[2][16*256];    // 16 KB, swizzled (16B slot ^= row&7)
  __shared__ f16 W3h[3*1024];        // 6 KB (f16 fold of W3d)
  __shared__ float dpart[25][16][3]; // 4.7 KB per-step delta accumulators
  const int tid = threadIdx.x, l = tid & 63, w = tid >> 6;
  const int li = l & 15, hi = l >> 4;
  const int bblk = blockIdx.x, rb = bblk*16;

  for (int i=tid;i<3072;i+=512) W3h[i] = (f16)W3d[i];
  for (int i=tid; i<25*16*3; i+=512) ((float*)dpart)[i] = 0.f;

  float c_st[2][4];
#pragma unroll
  for (int j=0;j<2;++j)
#pragma unroll
    for (int i=0;i<4;++i) c_st[j][i]=0.f;

  // ---- macros ----
#define VMW(n) { asm volatile("s_waitcnt vmcnt(" #n ")" ::: "memory");        \
                 __builtin_amdgcn_sched_barrier(0); }
// stage 4 frags (one kf-half h: qs {h*2, h*2+1}) into slot s  — 4 instrs, 4KB
#define STAGE4(WP, kf, h, s)                                                  \
  _Pragma("unroll") for (int f=0; f<4; ++f) {                                 \
    int ctg = ((h)*2 + (f>>1))*16 + w*2 + (f&1);                              \
    const f16* g = (WP) + ((size_t)((kf)*64 + ctg)*64 + l)*8;                 \
    __builtin_amdgcn_global_load_lds((gu32*)g, (lu32*)&wLDS[w][s][f][0], 16, 0, 0); \
  }
#define AH(ah, hB, kf) ah = *(f16x8*)&(hB)[li*256 + ((((kf)*4)+hi) ^ (li&7))*8];
#define MFMA4(s, h, ah)                                                       \
  _Pragma("unroll") for (int f=0; f<4; ++f) {                                 \
    f16x8 b = *(f16x8*)&wLDS[w][s][f][l*8];                                   \
    acc[(h)*2 + (f>>1)][f&1] = MFMA16(ah, b, acc[(h)*2 + (f>>1)][f&1]); }
// 16-stage stream; entry queue = [S0..S3]=16 (+pv issued at step top).
// Consume 1 stage per wait; 3 stages always in flight; tail stages next step's
// kf0/kf1 from WPn. Exit queue = [S0'..S3'] = 16.
#define KFSTREAM16(hB, WP, WPn) {                                             \
  f16x8 ah;                                                                   \
  VMW(20) AH(ah, hB, 0) MFMA4(0,0,ah) STAGE4(WP,2,0,0)                        \
  VMW(20)               MFMA4(1,1,ah) STAGE4(WP,2,1,1)                        \
  VMW(20) AH(ah, hB, 1) MFMA4(2,0,ah) STAGE4(WP,3,0,2)                        \
  VMW(20)               MFMA4(3,1,ah) STAGE4(WP,3,1,3)                        \
  VMW(12) AH(ah, hB, 2) MFMA4(0,0,ah) STAGE4(WP,4,0,0)                        \
  VMW(12)               MFMA4(1,1,ah) STAGE4(WP,4,1,1)                        \
  VMW(12) AH(ah, hB, 3) MFMA4(2,0,ah) STAGE4(WP,5,0,2)                        \
  VMW(12)               MFMA4(3,1,ah) STAGE4(WP,5,1,3)                        \
  VMW(12) AH(ah, hB, 4) MFMA4(0,0,ah) STAGE4(WP,6,0,0)                        \
  VMW(12)               MFMA4(1,1,ah) STAGE4(WP,6,1,1)                        \
  VMW(12) AH(ah, hB, 5) MFMA4(2,0,ah) STAGE4(WP,7,0,2)                        \
  VMW(12)               MFMA4(3,1,ah) STAGE4(WP,7,1,3)                        \
  VMW(12) AH(ah, hB, 6) MFMA4(0,0,ah) STAGE4(WPn,0,0,0)                       \
  VMW(12)               MFMA4(1,1,ah) STAGE4(WPn,0,1,1)                       \
  VMW(12) AH(ah, hB, 7) MFMA4(2,0,ah) STAGE4(WPn,1,0,2)                       \
  VMW(12)               MFMA4(3,1,ah) STAGE4(WPn,1,1,3)                       \
  }
#define LOADPV(dst, base, t_)                                                 \
  _Pragma("unroll")                                                           \
  for (int q=0;q<4;++q)                                                       \
    _Pragma("unroll")                                                         \
    for (int j=0;j<2;++j)                                                     \
      dst[q][j] = *(const f16x4*)((base) + ((size_t)(t_)*16384 + (size_t)(q*16 + w*2 + j)*256 + l*4));
#define COPYPV()                                                              \
  _Pragma("unroll")                                                           \
  for (int q=0;q<4;++q)                                                       \
    _Pragma("unroll")                                                         \
    for (int j=0;j<2;++j) pvA[q][j] = pvB[q][j];
#define ACCINIT()                                                             \
  f32x4 acc[4][2];                                                            \
  _Pragma("unroll")                                                           \
  for (int q=0;q<4;++q)                                                       \
    _Pragma("unroll")                                                         \
    for (int j=0;j<2;++j)                                                     \
      acc[q][j] = (f32x4){(float)pvA[q][j][0],(float)pvA[q][j][1],(float)pvA[q][j][2],(float)pvA[q][j][3]};

  const f16* prE = pregE + (size_t)bblk*5*16384;
  const f16* prD = pregD + (size_t)bblk*25*16384;
  f16x4 pvA[4][2], pvB[4][2];

  __syncthreads();                 // W3h + dpart init visible (before any stream)
  LOADPV(pvA, prE, 0)
  STAGE4(Whh_e_p,0,0,0) STAGE4(Whh_e_p,0,1,1) STAGE4(Whh_e_p,1,0,2) STAGE4(Whh_e_p,1,1,3)

  // ---------------- encoder (gate = acc only: bias+pos pre-folded) ---------
  for (int t=0;t<5;++t) {
    if (t < 4) LOADPV(pvB, prE, t+1)
    else       LOADPV(pvB, prD, 0)       // decoder t=0 preg
    ACCINIT()
    if (t > 0) KFSTREAM16(hBuf[(t-1)&1], Whh_e_p, ((t<4)?Whh_e_p:Whh_d_p))
#pragma unroll
    for (int i=0;i<4;++i) {
      int r = hi*4 + i;
#pragma unroll
      for (int j=0;j<2;++j) {
        int hc = w*32 + j*16 + li;
        float cn = sigm(acc[1][j][i])*c_st[j][i] + sigm(acc[0][j][i])*tanh_(acc[2][j][i]);
        c_st[j][i] = cn;
        float h = sigm(acc[3][j][i])*tanh_(cn);
        hBuf[t&1][r*256 + (((hc>>3) ^ (r&7))<<3) + (hc&7)] = (f16)h;
      }
    }
    COPYPV()
    bar_lgkm();                    // h[t] visible; stages + pv stay in flight
  }

  // ---------------- decoder constants ----------------
  float w2r[2][3];
#pragma unroll
  for (int j=0;j<2;++j) {
    int hc = w*32 + j*16 + li;
    w2r[j][0]=W2Wo[hc*3+0]; w2r[j][1]=W2Wo[hc*3+1]; w2r[j][2]=W2Wo[hc*3+2];
  }
  const float b2w0 = b2Wo[0], b2w1 = b2Wo[1], b2w2 = b2Wo[2];
  float pp[4][3];
#pragma unroll
  for (int i=0;i<4;++i) {
    int r = rb + hi*4 + i;
    pp[i][0]=dec_pos[r*3+0]; pp[i][1]=dec_pos[r*3+1]; pp[i][2]=dec_pos[r*3+2];
  }

  // ---------------- decoder (1 lgkm-barrier/step) ----------------
  // enc t=4 wrote hBuf[0] and staged dec kf0/kf1; dec step t reads hBuf[t&1].
  for (int t=0;t<25;++t) {
    if (t+1 < 25) LOADPV(pvB, prD, t+1)
    ACCINIT()
    KFSTREAM16(hBuf[t&1], Whh_d_p, Whh_d_p)   // t=24 trailing stages dead, harmless
    // per-step W3 gather from LDS (f16)
    float w3v[2][4][3];
#pragma unroll
    for (int j=0;j<2;++j)
#pragma unroll
      for (int q=0;q<4;++q) {
        int gc = q*256 + w*32 + j*16 + li;
        w3v[j][q][0] = (float)W3h[gc];
        w3v[j][q][1] = (float)W3h[1024+gc];
        w3v[j][q][2] = (float)W3h[2048+gc];
      }
    float dpar[4][3];
#pragma unroll
    for (int i=0;i<4;++i){ dpar[i][0]=0.f; dpar[i][1]=0.f; dpar[i][2]=0.f; }
#pragma unroll
    for (int i=0;i<4;++i) {
      int r = hi*4 + i;
#pragma unroll
      for (int j=0;j<2;++j) {
        int hc = w*32 + j*16 + li;
        float gq[4];
#pragma unroll
        for (int q=0;q<4;++q)
          gq[q] = acc[q][j][i] + pp[i][0]*w3v[j][q][0] + pp[i][1]*w3v[j][q][1] + pp[i][2]*w3v[j][q][2];
        float cn = sigm(gq[1])*c_st[j][i] + sigm(gq[0])*tanh_(gq[2]);
        c_st[j][i] = cn;
        float h = sigm(gq[3])*tanh_(cn);
        hBuf[(t+1)&1][r*256 + (((hc>>3) ^ (r&7))<<3) + (hc&7)] = (f16)h;
        dpar[i][0] += h*w2r[j][0];
        dpar[i][1] += h*w2r[j][1];
        dpar[i][2] += h*w2r[j][2];
      }
    }
#pragma unroll
    for (int m=1;m<16;m<<=1)
#pragma unroll
      for (int i=0;i<4;++i) {
        dpar[i][0] += __shfl_xor(dpar[i][0], m);
        dpar[i][1] += __shfl_xor(dpar[i][1], m);
        dpar[i][2] += __shfl_xor(dpar[i][2], m);
      }
    if (li==0) {
#pragma unroll
      for (int i=0;i<4;++i) {
        int r = hi*4 + i;
        atomicAdd(&dpart[t][r][0], dpar[i][0]);
        atomicAdd(&dpart[t][r][1], dpar[i][1]);
        atomicAdd(&dpart[t][r][2], dpar[i][2]);
      }
    }
    if (t+1 < 25) { COPYPV() }
    bar_lgkm();                    // h[t+1] + dpart[t] visible; stages/pv alive
    // pos update (redundant per 16-lane group, identical FP ops -> identical)
#pragma unroll
    for (int i=0;i<4;++i) {
      int r = hi*4 + i;
      float p0 = pp[i][0] + b2w0 + dpart[t][r][0];
      float p1 = pp[i][1] + b2w1 + dpart[t][r][1];
      float p2 = pp[i][2] + b2w2 + dpart[t][r][2];
      float inv = frsq(p0*p0+p1*p1+p2*p2);
      pp[i][0]=p0*inv; pp[i][1]=p1*inv; pp[i][2]=p2*inv;
      if (w==0 && li==0) {
        float* o = out + (size_t)(rb+r)*75 + t*3;
        o[0]=pp[i][0]; o[1]=pp[i][1]; o[2]=pp[i][2];
      }
    }
  }
#undef VMW
#undef STAGE4
#undef AH
#undef MFMA4
#undef KFSTREAM16
#undef LOADPV
#undef COPYPV
#undef ACCINIT
}

// ================= launch =================
extern "C" void kernel_launch(void* const* d_in, const int* in_sizes, int n_in,
                              void* d_out, int out_size, void* d_ws, size_t ws_size,
                              hipStream_t stream)
{
  const float* enc_pos = (const float*)d_in[0];
  const float* enc_sal = (const float*)d_in[1];
  const float* dec_pos = (const float*)d_in[2];
  const float* dec_sal = (const float*)d_in[3];
  const float* Wpe  = (const float*)d_in[4];
  const float* bpe  = (const float*)d_in[5];
  const float* Wse  = (const float*)d_in[6];
  const float* bse  = (const float*)d_in[7];
  const float* Wih_e= (const float*)d_in[8];
  const float* Whh_e= (const float*)d_in[9];
  const float* bih_e= (const float*)d_in[10];
  const float* bhh_e= (const float*)d_in[11];
  const float* Wih_d= (const float*)d_in[12];
  const float* Whh_d= (const float*)d_in[13];
  const float* bih_d= (const float*)d_in[14];
  const float* bhh_d= (const float*)d_in[15];
  const float* Wpd  = (const float*)d_in[16];
  const float* bpd  = (const float*)d_in[17];
  const float* Wsd  = (const float*)d_in[18];
  const float* bsd  = (const float*)d_in[19];
  const float* W2   = (const float*)d_in[20];
  const float* b2   = (const float*)d_in[21];
  const float* Wo   = (const float*)d_in[22];
  const float* bo   = (const float*)d_in[23];

  char* ws = (char*)d_ws;
  f16* pWse   = (f16*)(ws + OFF_WSE_P);
  f16* pWsd   = (f16*)(ws + OFF_WSD_P);
  f16* pWih_e = (f16*)(ws + OFF_WIHE_P);
  f16* pWih_d = (f16*)(ws + OFF_WIHD_P);
  f16* pWhh_e = (f16*)(ws + OFF_WHHE_P);
  f16* pWhh_d = (f16*)(ws + OFF_WHHD_P);
  float* W3e  = (float*)(ws + OFF_W3E);
  float* W3d  = (float*)(ws + OFF_W3D);
  float* W2WoP= (float*)(ws + OFF_W2WO);
  float* biasE= (float*)(ws + OFF_BIASE);
  float* biasD= (float*)(ws + OFF_BIASD);
  float* b2WoP= (float*)(ws + OFF_B2WO);
  f16* pregE  = (f16*)(ws + OFF_PREGE);
  f16* pregD  = (f16*)(ws + OFF_PREGD);
  float* out  = (float*)d_out;

  hipLaunchKernelGGL(k_prep, dim3(2570), dim3(256), 0, stream,
                     Wse, Wsd, Wih_e, Wih_d, Whh_e, Whh_d,
                     pWse, pWsd, pWih_e, pWih_d, pWhh_e, pWhh_d,
                     Wpe, bpe, bih_e, bhh_e, Wpd, bpd, bih_d, bhh_d,
                     W2, b2, Wo, bo,
                     W3e, W3d, biasE, biasD, W2WoP, b2WoP);
  // fused sal-projection + pre-gate GEMM: enc tiles [0,80) (pos folded), dec [80,480)
  hipLaunchKernelGGL(k_gemm_fused, dim3(480), dim3(256), 0, stream,
                     enc_sal, pWse, bse, pWih_e, biasE, pregE, 80, 5, enc_pos, W3e,
                     dec_sal, pWsd, bsd, pWih_d, biasD, pregD, 25);
  // fused encoder+decoder recurrence
  hipLaunchKernelGGL(k_rnn, dim3(64), dim3(512), 0, stream,
                     pregE, pregD, pWhh_e, pWhh_d,
                     W3d, dec_pos, W2WoP, b2WoP, out);
}

// Round 13
// 505.522 us; speedup vs baseline: 1.7977x; 1.2342x over previous
//
#include <hip/hip_runtime.h>

typedef _Float16 f16;
typedef _Float16 f16x4 __attribute__((ext_vector_type(4)));
typedef _Float16 f16x8 __attribute__((ext_vector_type(8)));
typedef float    f32x4 __attribute__((ext_vector_type(4)));
typedef int      i32x4 __attribute__((ext_vector_type(4)));
typedef unsigned int u32;

#define MFMA16(a,b,c) __builtin_amdgcn_mfma_f32_16x16x32_f16((a),(b),(c),0,0,0)
#define MFMAI8(a,b,c) __builtin_amdgcn_mfma_i32_16x16x64_i8((a),(b),(c),0,0,0)

typedef __attribute__((address_space(1))) const u32 gu32;
typedef __attribute__((address_space(3))) u32 lu32;

static __device__ __forceinline__ float frcp(float x){ float r; asm("v_rcp_f32 %0, %1" : "=v"(r) : "v"(x)); return r; }
static __device__ __forceinline__ float frsq(float x){ float r; asm("v_rsq_f32 %0, %1" : "=v"(r) : "v"(x)); return r; }
static __device__ __forceinline__ float sigm(float x){ return frcp(1.0f + __expf(-x)); }
static __device__ __forceinline__ float tanh_(float x){ return 1.0f - 2.0f*frcp(1.0f + __expf(2.0f*x)); }

// barrier with LDS-visibility only: ds ops drained, global/gload_lds stay in flight
static __device__ __forceinline__ void bar_lgkm(){
  asm volatile("s_waitcnt lgkmcnt(0)" ::: "memory");
  __builtin_amdgcn_s_barrier();
  asm volatile("" ::: "memory");
}
static __device__ __forceinline__ void bar_plain(){
  asm volatile("" ::: "memory");
  __builtin_amdgcn_s_barrier();
  asm volatile("" ::: "memory");
}

// ---------------- workspace layout (bytes) ----------------
static constexpr size_t OFF_WSE_P  = 0;                                  // 4 MB
static constexpr size_t OFF_WSD_P  = OFF_WSE_P  + (size_t)8192*256*2;    // 4 MB
static constexpr size_t OFF_WIHE_P = OFF_WSD_P  + (size_t)8192*256*2;    // 512 KB
static constexpr size_t OFF_WIHD_P = OFF_WIHE_P + (size_t)256*1024*2;
static constexpr size_t OFF_WHHE_P = OFF_WIHD_P + (size_t)256*1024*2;    // 256 KB (i8)
static constexpr size_t OFF_WHHD_P = OFF_WHHE_P + (size_t)256*1024;      // 256 KB (i8)
static constexpr size_t OFF_W3E    = OFF_WHHD_P + (size_t)256*1024;
static constexpr size_t OFF_W3D    = OFF_W3E   + (size_t)3*1024*4;
static constexpr size_t OFF_W2WO   = OFF_W3D   + (size_t)3*1024*4;
static constexpr size_t OFF_BIASE  = OFF_W2WO  + (size_t)256*3*4;
static constexpr size_t OFF_BIASD  = OFF_BIASE + (size_t)1024*4;
static constexpr size_t OFF_B2WO   = OFF_BIASD + (size_t)1024*4;
static constexpr size_t OFF_PREGE  = OFF_B2WO  + 256;                    // 10.5 MB
static constexpr size_t OFF_PREGD  = OFF_PREGE + (size_t)5120*1024*2;    // 52.4 MB
static constexpr size_t OFF_END    = OFF_PREGD + (size_t)25600*1024*2;

// ================= prep: pack weights + small folds ==========================
// f16 pack layout [kfg][ctg][lane][8]: k = kfg*32+(l>>4)*8+i, n = ctg*16+(l&15)
// i8  pack layout [kfg][ctg][lane][16]: k = kfg*64+(l>>4)*16+e (K=64 MFMA)
// blocks: [0,1024) Wse | [1024,2048) Wsd | [2048,2176) Wih_e | [2176,2304) Wih_d
//         [2304,2368) Whh_e(i8) | [2368,2432) Whh_d(i8) | [2432,2442) folds
__global__ __launch_bounds__(256) void k_prep(
    const float* __restrict__ Wse, const float* __restrict__ Wsd,
    const float* __restrict__ Wih_e, const float* __restrict__ Wih_d,
    const float* __restrict__ Whh_e, const float* __restrict__ Whh_d,
    f16* pWse, f16* pWsd, f16* pWih_e, f16* pWih_d,
    signed char* pWhh_e, signed char* pWhh_d,
    const float* __restrict__ Wpe, const float* __restrict__ bpe,
    const float* __restrict__ bih_e, const float* __restrict__ bhh_e,
    const float* __restrict__ Wpd, const float* __restrict__ bpd,
    const float* __restrict__ bih_d, const float* __restrict__ bhh_d,
    const float* __restrict__ W2, const float* __restrict__ b2,
    const float* __restrict__ Wo, const float* __restrict__ bo,
    float* W3e, float* W3d, float* biasE, float* biasD, float* W2Wo, float* b2Wo)
{
  int blk = blockIdx.x;
  if (blk < 2304) {
    const float* W; f16* o; int N, base;
    if      (blk < 1024) { W=Wse;   o=pWse;   N=256;  base=0; }
    else if (blk < 2048) { W=Wsd;   o=pWsd;   N=256;  base=1024; }
    else if (blk < 2176) { W=Wih_e; o=pWih_e; N=1024; base=2048; }
    else                 { W=Wih_d; o=pWih_d; N=1024; base=2176; }
    int tid = (blk - base)*256 + threadIdx.x;
    int l = tid & 63;
    int nct = N >> 4;
    int ctg = (tid >> 6) % nct;
    int kfg = (tid >> 6) / nct;
    int k0  = kfg*32 + ((l>>4)<<3);
    int col = ctg*16 + (l&15);
    f16x8 v;
#pragma unroll
    for (int i=0;i<8;++i) v[i] = (f16)W[(size_t)(k0+i)*N + col];
    *(f16x8*)(o + (size_t)tid*8) = v;
    return;
  }
  if (blk < 2432) {
    const float* W; signed char* o; int base;
    if (blk < 2368) { W=Whh_e; o=pWhh_e; base=2304; }
    else            { W=Whh_d; o=pWhh_d; base=2368; }
    int tid = (blk - base)*256 + threadIdx.x;   // 16384 threads
    int l = tid & 63;
    int unit = tid >> 6;                        // 0..255 = [kfg(4)][ctg(64)]
    int kfg = unit >> 6, ctg = unit & 63;
    int k0  = kfg*64 + ((l>>4)<<4);
    int col = ctg*16 + (l&15);
    signed char* dst = o + ((size_t)unit*64 + l)*16;
#pragma unroll
    for (int e=0;e<16;++e) {
      int q = __float2int_rn(W[(size_t)(k0+e)*1024 + col] * 1024.0f);
      q = q > 127 ? 127 : (q < -127 ? -127 : q);
      dst[e] = (signed char)q;
    }
    return;
  }
  int bid = blk - 2432, tid = threadIdx.x;
  if (bid < 4) {
    int j = bid*256 + tid;
    float s0=0,s1=0,s2=0,sb=0;
    for (int m=0;m<256;++m) {
      float wv = Wih_e[(size_t)(256+m)*1024 + j];
      s0 += Wpe[m]*wv; s1 += Wpe[256+m]*wv; s2 += Wpe[512+m]*wv; sb += bpe[m]*wv;
    }
    W3e[j]=s0; W3e[1024+j]=s1; W3e[2048+j]=s2;
    biasE[j] = bih_e[j] + bhh_e[j] + sb;
  } else if (bid < 8) {
    int j = (bid-4)*256 + tid;
    float s0=0,s1=0,s2=0,sb=0;
    for (int m=0;m<256;++m) {
      float wv = Wih_d[(size_t)(256+m)*1024 + j];
      s0 += Wpd[m]*wv; s1 += Wpd[256+m]*wv; s2 += Wpd[512+m]*wv; sb += bpd[m]*wv;
    }
    W3d[j]=s0; W3d[1024+j]=s1; W3d[2048+j]=s2;
    biasD[j] = bih_d[j] + bhh_d[j] + sb;
  } else if (bid == 8) {
    int c = tid;
    float s0=0,s1=0,s2=0;
    for (int m=0;m<256;++m) {
      float wv = W2[(size_t)c*256+m];
      s0 += wv*Wo[m*3+0]; s1 += wv*Wo[m*3+1]; s2 += wv*Wo[m*3+2];
    }
    W2Wo[c*3+0]=s0; W2Wo[c*3+1]=s1; W2Wo[c*3+2]=s2;
  } else {
    if (tid < 192) {
      int j = tid >> 6, lane = tid & 63;
      float s = 0.f;
      for (int m=lane;m<256;m+=64) s += b2[m]*Wo[m*3+j];
#pragma unroll
      for (int msk=1;msk<64;msk<<=1) s += __shfl_xor(s, msk);
      if (lane==0) b2Wo[j] = s + bo[j];
    }
  }
}

// ======== fused GEMM: preg = (A(f32,K=8192)@Ws + bs) @ Wih + bias [+ pos@W3] =
__global__ __launch_bounds__(256) void k_gemm_fused(
    const float* __restrict__ A0, const f16* __restrict__ W0,
    const float* __restrict__ bs0, const f16* __restrict__ Wih0,
    const float* __restrict__ bias0, f16* __restrict__ P0, int nb0, int T0,
    const float* __restrict__ pos0, const float* __restrict__ W3f0,
    const float* __restrict__ A1, const f16* __restrict__ W1,
    const float* __restrict__ bs1, const f16* __restrict__ Wih1,
    const float* __restrict__ bias1, f16* __restrict__ P1, int T1)
{
  __shared__ f16 aLDS[2][64*64];   // 16 KB: stage-1 A tiles, 16B-slot ^= row&7
  __shared__ f16 sLDS[64*256];     // 32 KB: sal tile, 16B-slot ^= row&7
  const int tid = threadIdx.x, l = tid & 63, w = tid >> 6;
  const int li = l & 15, hi = l >> 4;
  const int bx = blockIdx.x;
  const float *Ap, *bs, *bias, *posf, *W3f; const f16 *Wp, *Wih; f16* P; int rblk, T;
  if (bx < nb0) { Ap=A0; Wp=W0; bs=bs0; Wih=Wih0; bias=bias0; P=P0; rblk=bx*64;       T=T0; posf=pos0; W3f=W3f0; }
  else          { Ap=A1; Wp=W1; bs=bs1; Wih=Wih1; bias=bias1; P=P1; rblk=(bx-nb0)*64; T=T1; posf=nullptr; W3f=nullptr; }
  const int t = rblk >> 10, b0 = rblk & 1023;

  f32x4 acc[4][4];
#pragma unroll
  for (int a=0;a<4;++a)
#pragma unroll
    for (int b=0;b<4;++b) acc[a][b] = (f32x4){0.f,0.f,0.f,0.f};

  const int srow = tid >> 2, kseg = tid & 3;   // 64 rows x 4 k-segs
  const float* Arow = Ap + ((size_t)(b0 + srow)*T + t)*8192 + kseg*16;

  float4 fA0,fA1,fA2,fA3, fB0,fB1,fB2,fB3;
#define LOADA_A(ti_) { const float* Aq = Arow + (ti_)*64;                      \
    fA0 = *(const float4*)Aq;     fA1 = *(const float4*)(Aq+4);                \
    fA2 = *(const float4*)(Aq+8); fA3 = *(const float4*)(Aq+12); }
#define LOADA_B(ti_) { const float* Aq = Arow + (ti_)*64;                      \
    fB0 = *(const float4*)Aq;     fB1 = *(const float4*)(Aq+4);                \
    fB2 = *(const float4*)(Aq+8); fB3 = *(const float4*)(Aq+12); }
#define MFMA_TILE(buf_, kfg0_)                                                 \
  _Pragma("unroll")                                                            \
  for (int kf = 0; kf < 2; ++kf) {                                             \
    f16x8 afr[4], bfr[4];                                                      \
    _Pragma("unroll")                                                          \
    for (int rt=0; rt<4; ++rt) {                                               \
      int row = rt*16 + li;                                                    \
      afr[rt] = *(f16x8*)&aLDS[buf_][row*64 + (((kf*4) + hi) ^ (row&7))*8];    \
    }                                                                          \
    _Pragma("unroll")                                                          \
    for (int ct=0; ct<4; ++ct) {                                               \
      int ctg = w*4 + ct;                                                      \
      bfr[ct] = *(const f16x8*)(Wp + ((size_t)(((kfg0_)+kf)*16 + ctg)*64 + l)*8); \
    }                                                                          \
    _Pragma("unroll")                                                          \
    for (int rt=0; rt<4; ++rt)                                                 \
      _Pragma("unroll")                                                        \
      for (int ct=0; ct<4; ++ct)                                               \
        acc[rt][ct] = MFMA16(afr[rt], bfr[ct], acc[rt][ct]);                   \
  }
#define STAGE1_STEP(F0,F1,F2,F3, RELOAD, buf_, ti_) {                          \
    f16x8 w0, w1;  /* consume: load was issued 2 iterations ago */             \
    w0[0]=(f16)F0.x; w0[1]=(f16)F0.y; w0[2]=(f16)F0.z; w0[3]=(f16)F0.w;        \
    w0[4]=(f16)F1.x; w0[5]=(f16)F1.y; w0[6]=(f16)F1.z; w0[7]=(f16)F1.w;        \
    w1[0]=(f16)F2.x; w1[1]=(f16)F2.y; w1[2]=(f16)F2.z; w1[3]=(f16)F2.w;        \
    w1[4]=(f16)F3.x; w1[5]=(f16)F3.y; w1[6]=(f16)F3.z; w1[7]=(f16)F3.w;        \
    bar_plain();          /* readers of this buf (iter ti-2) done */           \
    *(f16x8*)&aLDS[buf_][srow*64 + ((kseg*2    ) ^ (srow&7))*8] = w0;          \
    *(f16x8*)&aLDS[buf_][srow*64 + ((kseg*2 + 1) ^ (srow&7))*8] = w1;          \
    { int tn = ((ti_)+2 < 128) ? (ti_)+2 : 127; RELOAD(tn); }                  \
    bar_lgkm();           /* LDS visible; A-loads stay in flight */            \
    MFMA_TILE(buf_, (ti_)*2)                                                   \
  }

  LOADA_A(0); LOADA_B(1);
  for (int ti = 0; ti < 128; ti += 2) {
    STAGE1_STEP(fA0,fA1,fA2,fA3, LOADA_A, 0, ti)
    STAGE1_STEP(fB0,fB1,fB2,fB3, LOADA_B, 1, ti+1)
  }
#undef LOADA_A
#undef LOADA_B
#undef MFMA_TILE
#undef STAGE1_STEP
  // stage-1 epilogue: sal tile (+bs) -> LDS, swizzled row-major [64][256]
  bar_plain();
#pragma unroll
  for (int ct=0; ct<4; ++ct) {
    int col = (w*4 + ct)*16 + li;
    float bv = bs[col];
    int slot = col >> 3;
#pragma unroll
    for (int rt=0; rt<4; ++rt)
#pragma unroll
      for (int i=0;i<4;++i) {
        int row = rt*16 + hi*4 + i;
        sLDS[row*256 + ((slot ^ (row&7))<<3) + (col&7)] = (f16)(acc[rt][ct][i] + bv);
      }
  }
  // enc job: load per-row pos once (reused across all output cols)
  float pe[4][4][3];
  if (posf) {
#pragma unroll
    for (int rt=0; rt<4; ++rt)
#pragma unroll
      for (int i=0;i<4;++i) {
        int brow = b0 + rt*16 + hi*4 + i;
        const float* pq = posf + ((size_t)brow*T + t)*3;
        pe[rt][i][0]=pq[0]; pe[rt][i][1]=pq[1]; pe[rt][i][2]=pq[2];
      }
  }
  __syncthreads();
  // stage-2: sal(64x256) @ Wih(256x1024), 4 col-chunks of 256
  const int bblk0 = b0 >> 4;
#pragma unroll
  for (int cg=0; cg<4; ++cg) {
    f32x4 a2[4][4];
#pragma unroll
    for (int a=0;a<4;++a)
#pragma unroll
      for (int b=0;b<4;++b) a2[a][b] = (f32x4){0.f,0.f,0.f,0.f};
#pragma unroll
    for (int kfg=0; kfg<8; ++kfg) {
      f16x8 afr[4], bfr[4];
#pragma unroll
      for (int rt=0; rt<4; ++rt) {
        int row = rt*16 + li;
        afr[rt] = *(f16x8*)&sLDS[row*256 + (((kfg*4 + hi) ^ (row&7))<<3)];
      }
#pragma unroll
      for (int ct=0; ct<4; ++ct) {
        int ctg2 = cg*16 + w*4 + ct;
        bfr[ct] = *(const f16x8*)(Wih + ((size_t)(kfg*64 + ctg2)*64 + l)*8);
      }
#pragma unroll
      for (int rt=0; rt<4; ++rt)
#pragma unroll
        for (int ct=0; ct<4; ++ct)
          a2[rt][ct] = MFMA16(afr[rt], bfr[ct], a2[rt][ct]);
    }
    // fragment-order store (identity with k_rnn's C-init loads); bias (+pos@W3) folded
#pragma unroll
    for (int ct=0; ct<4; ++ct) {
      const int ctg2 = cg*16 + w*4 + ct;
      const float bv = bias[ctg2*16 + li];
      float w30=0.f, w31=0.f, w32=0.f;
      if (posf) { int gc = ctg2*16 + li; w30=W3f[gc]; w31=W3f[1024+gc]; w32=W3f[2048+gc]; }
#pragma unroll
      for (int rt=0; rt<4; ++rt) {
        f16x4 o;
#pragma unroll
        for (int i=0;i<4;++i) {
          float v = a2[rt][ct][i] + bv;
          if (posf) v += pe[rt][i][0]*w30 + pe[rt][i][1]*w31 + pe[rt][i][2]*w32;
          o[i] = (f16)v;
        }
        *(f16x4*)(P + ((size_t)((bblk0 + rt)*T + t)*64 + ctg2)*256 + l*4) = o;
      }
    }
  }
}

// ================= fused recurrent kernel: encoder(5) then decoder(25) ======
// 64 blocks x 16 rows, 512 threads (8 waves). wave w owns h-cols [w*32,+32):
// ctg = q*16 + w*2 + j (gate quads lane-local).
// INT8 path: Whh packed i8 (x1024), h quantized i8 (x127),
// mfma_i32_16x16x64_i8 (K=64) -> per-step weight ingest 256 KB (was 512),
// 8 stream points (was 16). 4 rotating wave-private LDS slots, 3 stages
// (12 KB/wave) in flight, uniform vmcnt(8); pv preg prefetch issued at
// point 5 of the stream, drained only at COPYPV after the gate phase.
__global__ __launch_bounds__(512) void k_rnn(
    const f16* __restrict__ pregE,   // [b_blk][5][64][64][4]  f16 (pos+bias folded)
    const f16* __restrict__ pregD,   // [b_blk][25][64][64][4] f16 (bias folded)
    const signed char* __restrict__ Whh_e_p, const signed char* __restrict__ Whh_d_p,
    const float* __restrict__ W3d, const float* __restrict__ dec_pos,
    const float* __restrict__ W2Wo, const float* __restrict__ b2Wo,
    float* __restrict__ out)         // (B,25,3)
{
  __shared__ signed char wLDS[8][4][4][1024]; // 128 KB: [wave][slot][frag][lane*16]
  __shared__ signed char hBuf[2][16*256];     // 8 KB i8, 16B-slot ^= (row&7)
  __shared__ f16 W3h[3*1024];                 // 6 KB (f16 fold of W3d)
  __shared__ float dpart[25][16][3];          // 4.7 KB per-step delta accumulators
  const int tid = threadIdx.x, l = tid & 63, w = tid >> 6;
  const int li = l & 15, hi = l >> 4;
  const int bblk = blockIdx.x, rb = bblk*16;
  const float SC = 1.0f/130048.0f;            // 1/(1024*127)

  for (int i=tid;i<3072;i+=512) W3h[i] = (f16)W3d[i];
  for (int i=tid; i<25*16*3; i+=512) ((float*)dpart)[i] = 0.f;

  float c_st[2][4];
#pragma unroll
  for (int j=0;j<2;++j)
#pragma unroll
    for (int i=0;i<4;++i) c_st[j][i]=0.f;

  // ---- macros ----
#define VMW(n) { asm volatile("s_waitcnt vmcnt(" #n ")" ::: "memory");        \
                 __builtin_amdgcn_sched_barrier(0); }
// stage point (kf,h): 4 frags (q = h*2+(f>>1), j = f&1), 4x 1KB gload_lds
#define STAGE(WP, kf, h, s)                                                   \
  _Pragma("unroll") for (int f=0; f<4; ++f) {                                 \
    int ctg = ((h)*2 + (f>>1))*16 + w*2 + (f&1);                              \
    const signed char* g = (WP) + ((size_t)((kf)*64 + ctg)*64 + l)*16;        \
    __builtin_amdgcn_global_load_lds((gu32*)g, (lu32*)&wLDS[w][s][f][0], 16, 0, 0); \
  }
#define AH(ah, hB, kf) ah = *(i32x4*)&(hB)[li*256 + ((((kf)*4)+hi) ^ (li&7))*16];
#define MFMA4(s, h, ah)                                                       \
  _Pragma("unroll") for (int f=0; f<4; ++f) {                                 \
    i32x4 b = *(i32x4*)&wLDS[w][s][f][l*16];                                  \
    acc[(h)*2 + (f>>1)][f&1] = MFMAI8(ah, b, acc[(h)*2 + (f>>1)][f&1]); }
// 8-point stream (points p = kf*2+h, slot = p&3). Entry: p0,p1,p2 staged
// (12 ops, retired during prior gate+barrier). Stage at p covers p+3;
// p5 issues pv(next) first; tail points use VMW(24) (12 stage ops + 16 pv
// younger). Exit queue = pv(16) + next p0..p2 (12); COPYPV drains pv only.
#define KFSTREAM8(hB, WP, WPn, PVB, PVT) {                                    \
  i32x4 ah;                                                                   \
  VMW(8) AH(ah, hB, 0) MFMA4(0, 0, ah) STAGE(WP, 1, 1, 3)                     \
  VMW(8)               MFMA4(1, 1, ah) STAGE(WP, 2, 0, 0)                     \
  VMW(8) AH(ah, hB, 1) MFMA4(2, 0, ah) STAGE(WP, 2, 1, 1)                     \
  VMW(8)               MFMA4(3, 1, ah) STAGE(WP, 3, 0, 2)                     \
  VMW(8) AH(ah, hB, 2) MFMA4(0, 0, ah) STAGE(WP, 3, 1, 3)                     \
  VMW(8)               MFMA4(1, 1, ah) LOADPV(pvB, PVB, PVT) STAGE(WPn, 0, 0, 0) \
  VMW(24) AH(ah, hB, 3) MFMA4(2, 0, ah) STAGE(WPn, 0, 1, 1)                   \
  VMW(24)               MFMA4(3, 1, ah) STAGE(WPn, 1, 0, 2)                   \
  }
#define LOADPV(dst, base, t_)                                                 \
  _Pragma("unroll")                                                           \
  for (int q=0;q<4;++q)                                                       \
    _Pragma("unroll")                                                         \
    for (int j=0;j<2;++j)                                                     \
      dst[q][j] = *(const f16x4*)((base) + ((size_t)(t_)*16384 + (size_t)(q*16 + w*2 + j)*256 + l*4));
#define COPYPV()                                                              \
  _Pragma("unroll")                                                           \
  for (int q=0;q<4;++q)                                                       \
    _Pragma("unroll")                                                         \
    for (int j=0;j<2;++j) pvA[q][j] = pvB[q][j];
#define ACCZERO()                                                             \
  i32x4 acc[4][2];                                                            \
  _Pragma("unroll")                                                           \
  for (int q=0;q<4;++q)                                                       \
    _Pragma("unroll")                                                         \
    for (int j=0;j<2;++j) acc[q][j] = (i32x4){0,0,0,0};
// write h (i8) into hBuf with the read-matching swizzle
#define HWRITE(hB, r, hc, hval)                                               \
  (hB)[(r)*256 + ((((hc)>>4) ^ ((r)&7))<<4) + ((hc)&15)] =                    \
      (signed char)__float2int_rn((hval)*127.0f);

  const f16* prE = pregE + (size_t)bblk*5*16384;
  const f16* prD = pregD + (size_t)bblk*25*16384;
  f16x4 pvA[4][2], pvB[4][2];

  __syncthreads();                 // W3h + dpart init visible (once)
  LOADPV(pvA, prE, 0)
  STAGE(Whh_e_p,0,0,0) STAGE(Whh_e_p,0,1,1) STAGE(Whh_e_p,1,0,2)   // p0,p1,p2

  // ---------------- encoder (gate = pv + acc: bias+pos pre-folded) ---------
  for (int t=0;t<5;++t) {
    ACCZERO()
    if (t > 0) {
      if (t < 4) { KFSTREAM8(hBuf[(t-1)&1], Whh_e_p, Whh_e_p, prE, t+1) }
      else       { KFSTREAM8(hBuf[(t-1)&1], Whh_e_p, Whh_d_p, prD, 0)   }
    }
#pragma unroll
    for (int i=0;i<4;++i) {
      int r = hi*4 + i;
#pragma unroll
      for (int j=0;j<2;++j) {
        int hc = w*32 + j*16 + li;
        float gq[4];
#pragma unroll
        for (int q=0;q<4;++q)
          gq[q] = (float)pvA[q][j][i] + (float)acc[q][j][i]*SC;
        float cn = sigm(gq[1])*c_st[j][i] + sigm(gq[0])*tanh_(gq[2]);
        c_st[j][i] = cn;
        float h = sigm(gq[3])*tanh_(cn);
        HWRITE(hBuf[t&1], r, hc, h)
      }
    }
    if (t == 0) LOADPV(pvB, prE, 1)   // no stream at t=0: load next pv here
    COPYPV()                          // implicit wait: drains pv, stages survive
    bar_lgkm();                       // h[t] visible; stages stay in flight
  }

  // ---------------- decoder constants ----------------
  float w2r[2][3];
#pragma unroll
  for (int j=0;j<2;++j) {
    int hc = w*32 + j*16 + li;
    w2r[j][0]=W2Wo[hc*3+0]; w2r[j][1]=W2Wo[hc*3+1]; w2r[j][2]=W2Wo[hc*3+2];
  }
  const float b2w0 = b2Wo[0], b2w1 = b2Wo[1], b2w2 = b2Wo[2];
  float pp[4][3];
#pragma unroll
  for (int i=0;i<4;++i) {
    int r = rb + hi*4 + i;
    pp[i][0]=dec_pos[r*3+0]; pp[i][1]=dec_pos[r*3+1]; pp[i][2]=dec_pos[r*3+2];
  }

  // ---------------- decoder (1 lgkm-barrier/step) ----------------
  // enc t=4 wrote hBuf[0] and staged dec p0..p2; dec step t reads hBuf[t&1].
  for (int t=0;t<25;++t) {
    ACCZERO()
    if (t+1 < 25) { KFSTREAM8(hBuf[t&1], Whh_d_p, Whh_d_p, prD, t+1) }
    else          { KFSTREAM8(hBuf[t&1], Whh_d_p, Whh_d_p, prD, 24)  }  // dummy pv/stages keep queue uniform
    // per-step W3 gather from LDS (f16)
    float w3v[2][4][3];
#pragma unroll
    for (int j=0;j<2;++j)
#pragma unroll
      for (int q=0;q<4;++q) {
        int gc = q*256 + w*32 + j*16 + li;
        w3v[j][q][0] = (float)W3h[gc];
        w3v[j][q][1] = (float)W3h[1024+gc];
        w3v[j][q][2] = (float)W3h[2048+gc];
      }
    float dpar[4][3];
#pragma unroll
    for (int i=0;i<4;++i){ dpar[i][0]=0.f; dpar[i][1]=0.f; dpar[i][2]=0.f; }
#pragma unroll
    for (int i=0;i<4;++i) {
      int r = hi*4 + i;
#pragma unroll
      for (int j=0;j<2;++j) {
        int hc = w*32 + j*16 + li;
        float gq[4];
#pragma unroll
        for (int q=0;q<4;++q)
          gq[q] = (float)pvA[q][j][i] + (float)acc[q][j][i]*SC
                + pp[i][0]*w3v[j][q][0] + pp[i][1]*w3v[j][q][1] + pp[i][2]*w3v[j][q][2];
        float cn = sigm(gq[1])*c_st[j][i] + sigm(gq[0])*tanh_(gq[2]);
        c_st[j][i] = cn;
        float h = sigm(gq[3])*tanh_(cn);
        HWRITE(hBuf[(t+1)&1], r, hc, h)
        dpar[i][0] += h*w2r[j][0];
        dpar[i][1] += h*w2r[j][1];
        dpar[i][2] += h*w2r[j][2];
      }
    }
#pragma unroll
    for (int m=1;m<16;m<<=1)
#pragma unroll
      for (int i=0;i<4;++i) {
        dpar[i][0] += __shfl_xor(dpar[i][0], m);
        dpar[i][1] += __shfl_xor(dpar[i][1], m);
        dpar[i][2] += __shfl_xor(dpar[i][2], m);
      }
    if (li==0) {
#pragma unroll
      for (int i=0;i<4;++i) {
        int r = hi*4 + i;
        atomicAdd(&dpart[t][r][0], dpar[i][0]);
        atomicAdd(&dpart[t][r][1], dpar[i][1]);
        atomicAdd(&dpart[t][r][2], dpar[i][2]);
      }
    }
    COPYPV()                       // drains pv only (12 tail-stage ops younger)
    bar_lgkm();                    // h[t+1] + dpart[t] visible; stages alive
    // pos update (redundant per 16-lane group, identical FP ops -> identical)
#pragma unroll
    for (int i=0;i<4;++i) {
      int r = hi*4 + i;
      float p0 = pp[i][0] + b2w0 + dpart[t][r][0];
      float p1 = pp[i][1] + b2w1 + dpart[t][r][1];
      float p2 = pp[i][2] + b2w2 + dpart[t][r][2];
      float inv = frsq(p0*p0+p1*p1+p2*p2);
      pp[i][0]=p0*inv; pp[i][1]=p1*inv; pp[i][2]=p2*inv;
      if (w==0 && li==0) {
        float* o = out + (size_t)(rb+r)*75 + t*3;
        o[0]=pp[i][0]; o[1]=pp[i][1]; o[2]=pp[i][2];
      }
    }
  }
#undef VMW
#undef STAGE
#undef AH
#undef MFMA4
#undef KFSTREAM8
#undef LOADPV
#undef COPYPV
#undef ACCZERO
#undef HWRITE
}

// ================= launch =================
extern "C" void kernel_launch(void* const* d_in, const int* in_sizes, int n_in,
                              void* d_out, int out_size, void* d_ws, size_t ws_size,
                              hipStream_t stream)
{
  const float* enc_pos = (const float*)d_in[0];
  const float* enc_sal = (const float*)d_in[1];
  const float* dec_pos = (const float*)d_in[2];
  const float* dec_sal = (const float*)d_in[3];
  const float* Wpe  = (const float*)d_in[4];
  const float* bpe  = (const float*)d_in[5];
  const float* Wse  = (const float*)d_in[6];
  const float* bse  = (const float*)d_in[7];
  const float* Wih_e= (const float*)d_in[8];
  const float* Whh_e= (const float*)d_in[9];
  const float* bih_e= (const float*)d_in[10];
  const float* bhh_e= (const float*)d_in[11];
  const float* Wih_d= (const float*)d_in[12];
  const float* Whh_d= (const float*)d_in[13];
  const float* bih_d= (const float*)d_in[14];
  const float* bhh_d= (const float*)d_in[15];
  const float* Wpd  = (const float*)d_in[16];
  const float* bpd  = (const float*)d_in[17];
  const float* Wsd  = (const float*)d_in[18];
  const float* bsd  = (const float*)d_in[19];
  const float* W2   = (const float*)d_in[20];
  const float* b2   = (const float*)d_in[21];
  const float* Wo   = (const float*)d_in[22];
  const float* bo   = (const float*)d_in[23];

  char* ws = (char*)d_ws;
  f16* pWse   = (f16*)(ws + OFF_WSE_P);
  f16* pWsd   = (f16*)(ws + OFF_WSD_P);
  f16* pWih_e = (f16*)(ws + OFF_WIHE_P);
  f16* pWih_d = (f16*)(ws + OFF_WIHD_P);
  signed char* pWhh_e = (signed char*)(ws + OFF_WHHE_P);
  signed char* pWhh_d = (signed char*)(ws + OFF_WHHD_P);
  float* W3e  = (float*)(ws + OFF_W3E);
  float* W3d  = (float*)(ws + OFF_W3D);
  float* W2WoP= (float*)(ws + OFF_W2WO);
  float* biasE= (float*)(ws + OFF_BIASE);
  float* biasD= (float*)(ws + OFF_BIASD);
  float* b2WoP= (float*)(ws + OFF_B2WO);
  f16* pregE  = (f16*)(ws + OFF_PREGE);
  f16* pregD  = (f16*)(ws + OFF_PREGD);
  float* out  = (float*)d_out;

  hipLaunchKernelGGL(k_prep, dim3(2442), dim3(256), 0, stream,
                     Wse, Wsd, Wih_e, Wih_d, Whh_e, Whh_d,
                     pWse, pWsd, pWih_e, pWih_d, pWhh_e, pWhh_d,
                     Wpe, bpe, bih_e, bhh_e, Wpd, bpd, bih_d, bhh_d,
                     W2, b2, Wo, bo,
                     W3e, W3d, biasE, biasD, W2WoP, b2WoP);
  // fused sal-projection + pre-gate GEMM: enc tiles [0,80) (pos folded), dec [80,480)
  hipLaunchKernelGGL(k_gemm_fused, dim3(480), dim3(256), 0, stream,
                     enc_sal, pWse, bse, pWih_e, biasE, pregE, 80, 5, enc_pos, W3e,
                     dec_sal, pWsd, bsd, pWih_d, biasD, pregD, 25);
  // fused encoder+decoder recurrence (int8 weight stream)
  hipLaunchKernelGGL(k_rnn, dim3(64), dim3(512), 0, stream,
                     pregE, pregD, pWhh_e, pWhh_d,
                     W3d, dec_pos, W2WoP, b2WoP, out);
}